// Round 1
// baseline (9054.056 us; speedup 1.0000x reference)
//
#include <hip/hip_runtime.h>
#include <math.h>

// ---------------- problem constants ----------------
constexpr int kB = 4;
constexpr int kS = 5440;           // 64*64 + 32*32 + 16*16 + 8*8
constexpr int kH = 256;            // HIDDEN
constexpr int kNH = 8, kNL = 4, kNP = 4, kDH = 32;
constexpr int kM = kB * kS;        // 21760 rows
constexpr int kCHSUM = 1408;       // sum(CHS)

// level tables
__host__ __device__ inline int lvlW(int l){ const int w[4]={64,32,16,8}; return w[l]; }

// ---------------- kernels ----------------

// fused = sum_t feat_t * softmax_t(tfw[:, prior+ch])
__global__ void fuse_kernel(const float* __restrict__ f0, const float* __restrict__ f1,
                            const float* __restrict__ f2, const float* __restrict__ tfw,
                            float* __restrict__ fused, int c, int hw, int prior, int n)
{
    int idx = blockIdx.x * blockDim.x + threadIdx.x;
    if (idx >= n) return;
    int ch = (idx / hw) % c;
    float t0 = tfw[0*kCHSUM + prior + ch];
    float t1 = tfw[1*kCHSUM + prior + ch];
    float t2 = tfw[2*kCHSUM + prior + ch];
    float m = fmaxf(t0, fmaxf(t1, t2));
    float e0 = expf(t0-m), e1 = expf(t1-m), e2 = expf(t2-m);
    float inv = 1.0f / (e0+e1+e2);
    fused[idx] = f0[idx]*(e0*inv) + f1[idx]*(e1*inv) + f2[idx]*(e2*inv);
}

// 1x1 conv: xbuf[b,o,p] = sum_c fused[b,c,p]*pw[o,c] + pb[o]
__global__ void proj1x1_kernel(const float* __restrict__ fused, const float* __restrict__ pw,
                               const float* __restrict__ pb, float* __restrict__ xbuf,
                               int cin, int hw, int n)
{
    int idx = blockIdx.x * blockDim.x + threadIdx.x;
    if (idx >= n) return;
    int p = idx % hw;
    int o = (idx / hw) % kH;
    int b = idx / (hw * kH);
    const float* fp = fused + (size_t)b*cin*hw + p;
    const float* wp = pw + (size_t)o*cin;
    float acc = pb[o];
    for (int c = 0; c < cin; ++c) acc += fp[(size_t)c*hw] * wp[c];
    xbuf[idx] = acc;
}

// GroupNorm (32 groups of 8 ch) on xbuf (b,256,hw), write transposed into src[b, sbase+p, ch]
__global__ __launch_bounds__(256) void gn_kernel(const float* __restrict__ xbuf,
                          const float* __restrict__ gg, const float* __restrict__ gb,
                          float* __restrict__ src, int hw, int sbase)
{
    int b = blockIdx.x >> 5;
    int g = blockIdx.x & 31;
    int n = 8 * hw;
    const float* base = xbuf + ((size_t)b*kH + g*8) * hw;   // 8 contiguous channels
    float s = 0.f, s2 = 0.f;
    for (int e = threadIdx.x; e < n; e += 256) { float v = base[e]; s += v; s2 += v*v; }
    __shared__ float rs[256], rq[256];
    rs[threadIdx.x] = s; rq[threadIdx.x] = s2; __syncthreads();
    for (int off = 128; off; off >>= 1) {
        if (threadIdx.x < off) { rs[threadIdx.x] += rs[threadIdx.x+off]; rq[threadIdx.x] += rq[threadIdx.x+off]; }
        __syncthreads();
    }
    float mu  = rs[0] / n;
    float var = rq[0] / n - mu*mu;
    float inv = rsqrtf(var + 1e-5f);
    for (int e = threadIdx.x; e < n; e += 256) {
        int chl = e / hw, p = e % hw;
        int ch = g*8 + chl;
        float v = (base[e] - mu) * inv;
        src[((size_t)b*kS + sbase + p)*kH + ch] = v * gg[ch] + gb[ch];
    }
}

// sine position embedding + level embed, broadcast over batch
__global__ void pos_kernel(const float* __restrict__ lev, float* __restrict__ pos,
                           int h, int w, int sbase, int lvl, int n)
{
    int idx = blockIdx.x * blockDim.x + threadIdx.x;
    if (idx >= n) return;                 // n = h*w*256
    int ch = idx % kH;
    int p  = idx / kH;
    int py = p / w, px = p % w;
    int c2 = ch & 127;
    int i  = c2 >> 1;
    float dt = powf(10000.0f, (float)i / 64.0f);
    float t;
    if (ch < 128) t = (py + 1) / ((float)h + 1e-6f) * 6.2831853071795864f;
    else          t = (px + 1) / ((float)w + 1e-6f) * 6.2831853071795864f;
    float arg = t / dt;
    float val = (c2 & 1) ? cosf(arg) : sinf(arg);
    val += lev[lvl*kH + ch];
    for (int b = 0; b < kB; ++b)
        pos[((size_t)b*kS + sbase + p)*kH + ch] = val;
}

__global__ void add_kernel(const float* __restrict__ a, const float* __restrict__ b,
                           float* __restrict__ o, int n)
{
    int idx = blockIdx.x * blockDim.x + threadIdx.x;
    if (idx < n) o[idx] = a[idx] + b[idx];
}

// C[m,n] = sum_k A[m,k]*W[n,k] + bias[n]  (A: MxK row-major, W: NxK row-major)
// 64x64 tile, BK=16, 4x4 micro-tile, 256 threads.
__global__ __launch_bounds__(256) void gemm_nt_kernel(const float* __restrict__ A,
        const float* __restrict__ W, const float* __restrict__ bias,
        float* __restrict__ C, int M, int N, int K, int relu)
{
    __shared__ float As[64][17];
    __shared__ float Ws[64][17];
    int t  = threadIdx.x;
    int bm = blockIdx.x * 64;
    int bn = blockIdx.y * 64;
    int tx = t & 15;       // 0..15 (cols)
    int ty = t >> 4;       // 0..15 (rows)
    int lr = t >> 2;       // staging row 0..63
    int lc = (t & 3) * 4;  // staging col 0,4,8,12
    float acc[4][4] = {{0.f}};
    for (int k0 = 0; k0 < K; k0 += 16) {
        float4 av = *(const float4*)(A + (size_t)(bm + lr)*K + k0 + lc);
        float4 wv = *(const float4*)(W + (size_t)(bn + lr)*K + k0 + lc);
        __syncthreads();
        As[lr][lc+0]=av.x; As[lr][lc+1]=av.y; As[lr][lc+2]=av.z; As[lr][lc+3]=av.w;
        Ws[lr][lc+0]=wv.x; Ws[lr][lc+1]=wv.y; Ws[lr][lc+2]=wv.z; Ws[lr][lc+3]=wv.w;
        __syncthreads();
        #pragma unroll
        for (int kk = 0; kk < 16; ++kk) {
            float ar[4], br[4];
            #pragma unroll
            for (int i = 0; i < 4; ++i) ar[i] = As[ty*4+i][kk];
            #pragma unroll
            for (int j = 0; j < 4; ++j) br[j] = Ws[tx*4+j][kk];
            #pragma unroll
            for (int i = 0; i < 4; ++i)
                #pragma unroll
                for (int j = 0; j < 4; ++j)
                    acc[i][j] = fmaf(ar[i], br[j], acc[i][j]);
        }
    }
    #pragma unroll
    for (int i = 0; i < 4; ++i) {
        #pragma unroll
        for (int j = 0; j < 4; ++j) {
            float v = acc[i][j] + bias[bn + tx*4 + j];
            if (relu) v = fmaxf(v, 0.f);
            C[(size_t)(bm + ty*4 + i)*N + bn + tx*4 + j] = v;
        }
    }
}

// softmax over 16 (NL*NP) per (b,s,head), in place
__global__ void softmax16_kernel(float* __restrict__ aw, int n)
{
    int idx = blockIdx.x * blockDim.x + threadIdx.x;
    if (idx >= n) return;
    float* p = aw + (size_t)idx * 16;
    float m = p[0];
    #pragma unroll
    for (int k = 1; k < 16; ++k) m = fmaxf(m, p[k]);
    float s = 0.f;
    float e[16];
    #pragma unroll
    for (int k = 0; k < 16; ++k) { e[k] = expf(p[k]-m); s += e[k]; }
    float inv = 1.0f / s;
    #pragma unroll
    for (int k = 0; k < 16; ++k) p[k] = e[k]*inv;
}

// ms_deform: one block per (b,s), thread = (head, d)
__global__ __launch_bounds__(256) void msdeform_kernel(const float* __restrict__ val,
        const float* __restrict__ offb, const float* __restrict__ awb,
        float* __restrict__ msd)
{
    int bs = blockIdx.x;
    int s  = bs % kS;
    int b  = bs / kS;
    int head = threadIdx.x >> 5;
    int d    = threadIdx.x & 31;
    float refx, refy;
    if (s < 4096)      { int loc = s;        refy = ((loc>>6)+0.5f)/64.f; refx = ((loc&63)+0.5f)/64.f; }
    else if (s < 5120) { int loc = s - 4096; refy = ((loc>>5)+0.5f)/32.f; refx = ((loc&31)+0.5f)/32.f; }
    else if (s < 5376) { int loc = s - 5120; refy = ((loc>>4)+0.5f)/16.f; refx = ((loc&15)+0.5f)/16.f; }
    else               { int loc = s - 5376; refy = ((loc>>3)+0.5f)/8.f;  refx = ((loc&7)+0.5f)/8.f; }
    const float* op = offb + (size_t)bs*256 + head*32;
    const float* ap = awb  + (size_t)bs*128 + head*16;
    const float* vb = val  + (size_t)b*kS*256 + head*32 + d;
    const int WL[4] = {64,32,16,8};
    const int BASE[4] = {0,4096,5120,5376};
    float acc = 0.f;
    #pragma unroll
    for (int l = 0; l < 4; ++l) {
        int wl = WL[l], hl = WL[l], base = BASE[l];
        #pragma unroll
        for (int p = 0; p < 4; ++p) {
            float ox = op[l*8 + p*2 + 0];
            float oy = op[l*8 + p*2 + 1];
            float gx = (refx + ox/wl)*wl - 0.5f;
            float gy = (refy + oy/hl)*hl - 0.5f;
            float x0f = floorf(gx), y0f = floorf(gy);
            float wx1 = gx - x0f, wy1 = gy - y0f;
            int x0 = (int)x0f, y0 = (int)y0f;
            float a = ap[l*4 + p];
            #pragma unroll
            for (int dy = 0; dy < 2; ++dy) {
                int yi = y0 + dy;
                if (yi < 0 || yi >= hl) continue;
                float wy = dy ? wy1 : 1.f - wy1;
                #pragma unroll
                for (int dx = 0; dx < 2; ++dx) {
                    int xi = x0 + dx;
                    if (xi < 0 || xi >= wl) continue;
                    float wx = dx ? wx1 : 1.f - wx1;
                    acc += vb[((size_t)(base + yi*wl + xi))*256] * (wx*wy*a);
                }
            }
        }
    }
    msd[(size_t)bs*256 + head*32 + d] = acc;
}

// src = LayerNorm(src + delta) * g + b   (row = 256)
__global__ __launch_bounds__(256) void add_ln_kernel(float* __restrict__ src,
        const float* __restrict__ delta, const float* __restrict__ g,
        const float* __restrict__ bta)
{
    int row = blockIdx.x;
    int ch  = threadIdx.x;
    size_t idx = (size_t)row*256 + ch;
    float x = src[idx] + delta[idx];
    __shared__ float rs[256];
    rs[ch] = x; __syncthreads();
    for (int off = 128; off; off >>= 1) { if (ch < off) rs[ch] += rs[ch+off]; __syncthreads(); }
    float mu = rs[0] / 256.f;
    __syncthreads();
    float xc = x - mu;
    rs[ch] = xc*xc; __syncthreads();
    for (int off = 128; off; off >>= 1) { if (ch < off) rs[ch] += rs[ch+off]; __syncthreads(); }
    float inv = rsqrtf(rs[0]/256.f + 1e-5f);
    src[idx] = xc * inv * g[ch] + bta[ch];
}

// conv1: 3x3, 256->64, on src[:, :4096] viewed as (b,64,64,256), ReLU, out NCHW (b,64,64,64)
__global__ void conv1_kernel(const float* __restrict__ src, const float* __restrict__ w,
                             const float* __restrict__ bias, float* __restrict__ out)
{
    int idx = blockIdx.x * blockDim.x + threadIdx.x;   // B*64*64*64
    int x = idx & 63;
    int y = (idx >> 6) & 63;
    int o = (idx >> 12) & 63;
    int b = idx >> 18;
    float acc = bias[o];
    for (int dy = 0; dy < 3; ++dy) {
        int yy = y + dy - 1;
        if (yy < 0 || yy >= 64) continue;
        for (int dx = 0; dx < 3; ++dx) {
            int xx = x + dx - 1;
            if (xx < 0 || xx >= 64) continue;
            const float* sp = src + ((size_t)b*kS + yy*64 + xx)*256;
            const float* wp = w + (size_t)o*256*9 + dy*3 + dx;
            float a2 = 0.f;
            for (int c = 0; c < 256; ++c) a2 += sp[c] * wp[(size_t)c*9];
            acc += a2;
        }
    }
    out[idx] = fmaxf(acc, 0.f);
}

// conv2: 3x3, 64->2, NCHW in/out
__global__ void conv2_kernel(const float* __restrict__ c1, const float* __restrict__ w,
                             const float* __restrict__ bias, float* __restrict__ pred)
{
    int idx = blockIdx.x * blockDim.x + threadIdx.x;   // B*2*64*64
    int x = idx & 63;
    int y = (idx >> 6) & 63;
    int o = (idx >> 12) & 1;
    int b = idx >> 13;
    float acc = bias[o];
    for (int c = 0; c < 64; ++c) {
        const float* cp = c1 + ((size_t)(b*64 + c))*4096;
        const float* wp = w + ((size_t)(o*64 + c))*9;
        for (int dy = 0; dy < 3; ++dy) {
            int yy = y + dy - 1;
            if (yy < 0 || yy >= 64) continue;
            for (int dx = 0; dx < 3; ++dx) {
                int xx = x + dx - 1;
                if (xx < 0 || xx >= 64) continue;
                acc += cp[yy*64 + xx] * wp[dy*3 + dx];
            }
        }
    }
    pred[idx] = acc;
}

// bilinear resize 64x64 -> 256x256 (half-pixel, edge clamp == jax.image.resize bilinear)
__global__ void resize_kernel(const float* __restrict__ pred, float* __restrict__ out)
{
    int idx = blockIdx.x * blockDim.x + threadIdx.x;   // B*2*256*256
    int X = idx & 255;
    int Y = (idx >> 8) & 255;
    int c = (idx >> 16) & 1;
    int b = idx >> 17;
    float sx = (X + 0.5f)*0.25f - 0.5f;
    float sy = (Y + 0.5f)*0.25f - 0.5f;
    int x0 = (int)floorf(sx); float fx = sx - x0;
    int y0 = (int)floorf(sy); float fy = sy - y0;
    int x0c = min(max(x0, 0), 63), x1c = min(max(x0+1, 0), 63);
    int y0c = min(max(y0, 0), 63), y1c = min(max(y0+1, 0), 63);
    const float* p = pred + ((size_t)(b*2 + c))*4096;
    float v00 = p[y0c*64 + x0c], v01 = p[y0c*64 + x1c];
    float v10 = p[y1c*64 + x0c], v11 = p[y1c*64 + x1c];
    out[idx] = (1.f-fy)*((1.f-fx)*v00 + fx*v01) + fy*((1.f-fx)*v10 + fx*v11);
}

// ---------------- launch ----------------
extern "C" void kernel_launch(void* const* d_in, const int* in_sizes, int n_in,
                              void* d_out, int out_size, void* d_ws, size_t ws_size,
                              hipStream_t stream)
{
    const float* F[3][4];
    for (int t = 0; t < 3; ++t)
        for (int l = 0; l < 4; ++l)
            F[t][l] = (const float*)d_in[t*4 + l];
    const float* tfw = (const float*)d_in[12];
    const float *pw[4], *pb[4], *gg[4], *gb[4];
    for (int l = 0; l < 4; ++l) {
        pw[l] = (const float*)d_in[13 + 4*l];
        pb[l] = (const float*)d_in[14 + 4*l];
        gg[l] = (const float*)d_in[15 + 4*l];
        gb[l] = (const float*)d_in[16 + 4*l];
    }
    const float* lev   = (const float*)d_in[29];
    const float* off_w = (const float*)d_in[30];
    const float* off_b = (const float*)d_in[31];
    const float* aw_w  = (const float*)d_in[32];
    const float* aw_b  = (const float*)d_in[33];
    const float* val_w = (const float*)d_in[34];
    const float* val_b = (const float*)d_in[35];
    const float* out_w = (const float*)d_in[36];
    const float* out_b = (const float*)d_in[37];
    const float* ln1g  = (const float*)d_in[38];
    const float* ln1b  = (const float*)d_in[39];
    const float* ff1w  = (const float*)d_in[40];
    const float* ff1b  = (const float*)d_in[41];
    const float* ff2w  = (const float*)d_in[42];
    const float* ff2b  = (const float*)d_in[43];
    const float* ln2g  = (const float*)d_in[44];
    const float* ln2b  = (const float*)d_in[45];
    const float* c1w   = (const float*)d_in[46];
    const float* c1b   = (const float*)d_in[47];
    const float* c2w   = (const float*)d_in[48];
    const float* c2b   = (const float*)d_in[49];

    const size_t N256 = (size_t)kB * kS * 256;        // 5,570,560
    float* ws   = (float*)d_ws;
    float* src  = ws;
    float* pos  = src + N256;
    float* q    = pos + N256;
    float* offb = q + N256;
    float* awb  = offb + N256;                        // B*S*128
    float* val  = awb + (size_t)kB*kS*128;
    float* msd  = val + N256;
    float* tmp  = msd + N256;
    float* ffh  = tmp + N256;                         // B*S*1024
    // aliases into ffh (only live outside the encoder loop)
    float* fused = ffh;
    float* xbuf  = ffh + (size_t)kB*128*4096;         // max fused size
    float* c1o   = ffh;                               // B*64*64*64
    float* pred  = ffh + (size_t)kB*64*4096;

    const int LVL_HWS[4]  = {4096, 1024, 256, 64};
    const int LVL_BASE[4] = {0, 4096, 5120, 5376};
    const int LVL_C[4]    = {128, 256, 512, 512};
    const int LVL_PRIOR[4]= {0, 128, 256, 512};       // reference's literal (non-cumulative) priors
    const int LVL_DIM[4]  = {64, 32, 16, 8};

    // ---- stage 1: per-level fuse + proj + GN (+transpose into src) + pos ----
    for (int l = 0; l < 4; ++l) {
        int hw = LVL_HWS[l], c = LVL_C[l];
        int n1 = kB * c * hw;
        fuse_kernel<<<(n1+255)/256, 256, 0, stream>>>(F[0][l], F[1][l], F[2][l], tfw,
                                                      fused, c, hw, LVL_PRIOR[l], n1);
        int n2 = kB * kH * hw;
        proj1x1_kernel<<<(n2+255)/256, 256, 0, stream>>>(fused, pw[l], pb[l], xbuf, c, hw, n2);
        gn_kernel<<<kB*32, 256, 0, stream>>>(xbuf, gg[l], gb[l], src, hw, LVL_BASE[l]);
        int n3 = hw * kH;
        pos_kernel<<<(n3+255)/256, 256, 0, stream>>>(lev, pos, LVL_DIM[l], LVL_DIM[l],
                                                     LVL_BASE[l], l, n3);
    }

    // ---- stage 2: 6 encoder layers ----
    for (int i = 0; i < 6; ++i) {
        add_kernel<<<(int)((N256+255)/256), 256, 0, stream>>>(src, pos, q, (int)N256);

        dim3 g1(kM/64, 256/64);
        gemm_nt_kernel<<<g1, 256, 0, stream>>>(q, off_w + (size_t)i*256*256, off_b + i*256,
                                               offb, kM, 256, 256, 0);
        dim3 g2(kM/64, 128/64);
        gemm_nt_kernel<<<g2, 256, 0, stream>>>(q, aw_w + (size_t)i*128*256, aw_b + i*128,
                                               awb, kM, 128, 256, 0);
        int nsm = kM * kNH;
        softmax16_kernel<<<(nsm+255)/256, 256, 0, stream>>>(awb, nsm);

        gemm_nt_kernel<<<g1, 256, 0, stream>>>(src, val_w + (size_t)i*256*256, val_b + i*256,
                                               val, kM, 256, 256, 0);
        msdeform_kernel<<<kM, 256, 0, stream>>>(val, offb, awb, msd);
        gemm_nt_kernel<<<g1, 256, 0, stream>>>(msd, out_w + (size_t)i*256*256, out_b + i*256,
                                               tmp, kM, 256, 256, 0);
        add_ln_kernel<<<kM, 256, 0, stream>>>(src, tmp, ln1g + i*256, ln1b + i*256);

        dim3 g3(kM/64, 1024/64);
        gemm_nt_kernel<<<g3, 256, 0, stream>>>(src, ff1w + (size_t)i*1024*256, ff1b + i*1024,
                                               ffh, kM, 1024, 256, 1);
        gemm_nt_kernel<<<g1, 256, 0, stream>>>(ffh, ff2w + (size_t)i*256*1024, ff2b + i*256,
                                               tmp, kM, 256, 1024, 0);
        add_ln_kernel<<<kM, 256, 0, stream>>>(src, tmp, ln2g + i*256, ln2b + i*256);
    }

    // ---- stage 3: head ----
    conv1_kernel<<<(kB*64*64*64)/256, 256, 0, stream>>>(src, c1w, c1b, c1o);
    conv2_kernel<<<(kB*2*64*64)/256, 256, 0, stream>>>(c1o, c2w, c2b, pred);
    resize_kernel<<<(kB*2*256*256)/256, 256, 0, stream>>>(pred, (float*)d_out);
}

// Round 2
// 3888.821 us; speedup vs baseline: 2.3282x; 2.3282x over previous
//
#include <hip/hip_runtime.h>
#include <math.h>

// ---------------- problem constants ----------------
constexpr int kB = 4;
constexpr int kS = 5440;           // 64*64 + 32*32 + 16*16 + 8*8
constexpr int kH = 256;            // HIDDEN
constexpr int kNH = 8, kNL = 4, kNP = 4, kDH = 32;
constexpr int kM = kB * kS;        // 21760 rows
constexpr int kCHSUM = 1408;       // sum(CHS)

typedef __attribute__((ext_vector_type(8))) short short8v;   // 8 bf16 in 4 VGPRs
typedef __attribute__((ext_vector_type(4))) float f32x4;

__device__ inline short bf16rne(float f) {
    unsigned u = __float_as_uint(f);
    u += 0x7FFF + ((u >> 16) & 1);
    return (short)(u >> 16);
}

// ---------------- kernels ----------------

// fused = sum_t feat_t * softmax_t(tfw[:, prior+ch])
__global__ void fuse_kernel(const float* __restrict__ f0, const float* __restrict__ f1,
                            const float* __restrict__ f2, const float* __restrict__ tfw,
                            float* __restrict__ fused, int c, int hw, int prior, int n)
{
    int idx = blockIdx.x * blockDim.x + threadIdx.x;
    if (idx >= n) return;
    int ch = (idx / hw) % c;
    float t0 = tfw[0*kCHSUM + prior + ch];
    float t1 = tfw[1*kCHSUM + prior + ch];
    float t2 = tfw[2*kCHSUM + prior + ch];
    float m = fmaxf(t0, fmaxf(t1, t2));
    float e0 = expf(t0-m), e1 = expf(t1-m), e2 = expf(t2-m);
    float inv = 1.0f / (e0+e1+e2);
    fused[idx] = f0[idx]*(e0*inv) + f1[idx]*(e1*inv) + f2[idx]*(e2*inv);
}

// 1x1 conv: xbuf[b,o,p] = sum_c fused[b,c,p]*pw[o,c] + pb[o]
__global__ void proj1x1_kernel(const float* __restrict__ fused, const float* __restrict__ pw,
                               const float* __restrict__ pb, float* __restrict__ xbuf,
                               int cin, int hw, int n)
{
    int idx = blockIdx.x * blockDim.x + threadIdx.x;
    if (idx >= n) return;
    int p = idx % hw;
    int o = (idx / hw) % kH;
    int b = idx / (hw * kH);
    const float* fp = fused + (size_t)b*cin*hw + p;
    const float* wp = pw + (size_t)o*cin;
    float acc = pb[o];
    for (int c = 0; c < cin; ++c) acc += fp[(size_t)c*hw] * wp[c];
    xbuf[idx] = acc;
}

// GroupNorm (32 groups of 8 ch) on xbuf (b,256,hw), write transposed into src[b, sbase+p, ch]
__global__ __launch_bounds__(256) void gn_kernel(const float* __restrict__ xbuf,
                          const float* __restrict__ gg, const float* __restrict__ gb,
                          float* __restrict__ src, int hw, int sbase)
{
    int b = blockIdx.x >> 5;
    int g = blockIdx.x & 31;
    int n = 8 * hw;
    const float* base = xbuf + ((size_t)b*kH + g*8) * hw;   // 8 contiguous channels
    float s = 0.f, s2 = 0.f;
    for (int e = threadIdx.x; e < n; e += 256) { float v = base[e]; s += v; s2 += v*v; }
    __shared__ float rs[256], rq[256];
    rs[threadIdx.x] = s; rq[threadIdx.x] = s2; __syncthreads();
    for (int off = 128; off; off >>= 1) {
        if (threadIdx.x < off) { rs[threadIdx.x] += rs[threadIdx.x+off]; rq[threadIdx.x] += rq[threadIdx.x+off]; }
        __syncthreads();
    }
    float mu  = rs[0] / n;
    float var = rq[0] / n - mu*mu;
    float inv = rsqrtf(var + 1e-5f);
    for (int e = threadIdx.x; e < n; e += 256) {
        int chl = e / hw, p = e % hw;
        int ch = g*8 + chl;
        float v = (base[e] - mu) * inv;
        src[((size_t)b*kS + sbase + p)*kH + ch] = v * gg[ch] + gb[ch];
    }
}

// sine position embedding + level embed, broadcast over batch
__global__ void pos_kernel(const float* __restrict__ lev, float* __restrict__ pos,
                           int h, int w, int sbase, int lvl, int n)
{
    int idx = blockIdx.x * blockDim.x + threadIdx.x;
    if (idx >= n) return;                 // n = h*w*256
    int ch = idx % kH;
    int p  = idx / kH;
    int py = p / w, px = p % w;
    int c2 = ch & 127;
    int i  = c2 >> 1;
    float dt = powf(10000.0f, (float)i / 64.0f);
    float t;
    if (ch < 128) t = (py + 1) / ((float)h + 1e-6f) * 6.2831853071795864f;
    else          t = (px + 1) / ((float)w + 1e-6f) * 6.2831853071795864f;
    float arg = t / dt;
    float val = (c2 & 1) ? cosf(arg) : sinf(arg);
    val += lev[lvl*kH + ch];
    for (int b = 0; b < kB; ++b)
        pos[((size_t)b*kS + sbase + p)*kH + ch] = val;
}

__global__ void add_kernel(const float* __restrict__ a, const float* __restrict__ b,
                           float* __restrict__ o, int n)
{
    int idx = blockIdx.x * blockDim.x + threadIdx.x;
    if (idx < n) o[idx] = a[idx] + b[idx];
}

// ---------------- MFMA bf16 GEMM ----------------
// C[m,n] = sum_k A[m,k]*W[n,k] + bias[n]  (A: MxK fp32 row-major, W: NxK fp32 row-major)
// 128x128 tile, BK=32, 256 threads (4 waves, 2x2), 4x4 16x16 fragments per wave.
// fp32 staged -> bf16 RNE -> LDS (row stride 40 bf16 = 80B: 16-lane frag reads
// spread across all 32 banks, 2 lanes/bank = conflict-free).
// M, K must be multiples of 128/32; N arbitrary (guarded).
__global__ __launch_bounds__(256) void gemm_mfma_kernel(const float* __restrict__ A,
        const float* __restrict__ W, const float* __restrict__ bias,
        float* __restrict__ C, int M, int N, int K, int relu)
{
    __shared__ short Asm[128 * 40];
    __shared__ short Bsm[128 * 40];
    const int t    = threadIdx.x;
    const int bm   = blockIdx.x * 128;
    const int bn   = blockIdx.y * 128;
    const int lane = t & 63;
    const int wid  = t >> 6;
    const int wr   = wid >> 1;
    const int wc   = wid & 1;
    const int frow = lane & 15;
    const int g    = lane >> 4;

    // staging role: each thread loads 16 floats of A and 16 of W
    const int sr = t >> 1;             // row 0..127
    const int sc = (t & 1) * 16;       // col 0 or 16

    f32x4 acc[4][4];
    #pragma unroll
    for (int i = 0; i < 4; ++i)
        #pragma unroll
        for (int j = 0; j < 4; ++j)
            acc[i][j] = (f32x4){0.f, 0.f, 0.f, 0.f};

    const int wrow_ok = (bn + sr) < N;

    for (int k0 = 0; k0 < K; k0 += 32) {
        const float4* Ap = (const float4*)(A + (size_t)(bm + sr)*K + k0 + sc);
        float4 a0 = Ap[0], a1 = Ap[1], a2 = Ap[2], a3 = Ap[3];
        float4 w0 = {0,0,0,0}, w1 = {0,0,0,0}, w2 = {0,0,0,0}, w3 = {0,0,0,0};
        if (wrow_ok) {
            const float4* Wp = (const float4*)(W + (size_t)(bn + sr)*K + k0 + sc);
            w0 = Wp[0]; w1 = Wp[1]; w2 = Wp[2]; w3 = Wp[3];
        }
        __syncthreads();   // previous iteration's reads done before overwrite
        short8v av, av2, wv, wv2;
        av[0]=bf16rne(a0.x); av[1]=bf16rne(a0.y); av[2]=bf16rne(a0.z); av[3]=bf16rne(a0.w);
        av[4]=bf16rne(a1.x); av[5]=bf16rne(a1.y); av[6]=bf16rne(a1.z); av[7]=bf16rne(a1.w);
        av2[0]=bf16rne(a2.x); av2[1]=bf16rne(a2.y); av2[2]=bf16rne(a2.z); av2[3]=bf16rne(a2.w);
        av2[4]=bf16rne(a3.x); av2[5]=bf16rne(a3.y); av2[6]=bf16rne(a3.z); av2[7]=bf16rne(a3.w);
        wv[0]=bf16rne(w0.x); wv[1]=bf16rne(w0.y); wv[2]=bf16rne(w0.z); wv[3]=bf16rne(w0.w);
        wv[4]=bf16rne(w1.x); wv[5]=bf16rne(w1.y); wv[6]=bf16rne(w1.z); wv[7]=bf16rne(w1.w);
        wv2[0]=bf16rne(w2.x); wv2[1]=bf16rne(w2.y); wv2[2]=bf16rne(w2.z); wv2[3]=bf16rne(w2.w);
        wv2[4]=bf16rne(w3.x); wv2[5]=bf16rne(w3.y); wv2[6]=bf16rne(w3.z); wv2[7]=bf16rne(w3.w);
        *(short8v*)&Asm[sr*40 + sc]     = av;
        *(short8v*)&Asm[sr*40 + sc + 8] = av2;
        *(short8v*)&Bsm[sr*40 + sc]     = wv;
        *(short8v*)&Bsm[sr*40 + sc + 8] = wv2;
        __syncthreads();

        short8v af[4], bf[4];
        #pragma unroll
        for (int i = 0; i < 4; ++i)
            af[i] = *(const short8v*)&Asm[(wr*64 + i*16 + frow)*40 + g*8];
        #pragma unroll
        for (int j = 0; j < 4; ++j)
            bf[j] = *(const short8v*)&Bsm[(wc*64 + j*16 + frow)*40 + g*8];
        #pragma unroll
        for (int i = 0; i < 4; ++i)
            #pragma unroll
            for (int j = 0; j < 4; ++j)
                acc[i][j] = __builtin_amdgcn_mfma_f32_16x16x32_bf16(af[i], bf[j], acc[i][j], 0, 0, 0);
    }

    // epilogue: D row = (lane>>4)*4 + reg, col = lane&15  (m89-verified mapping)
    #pragma unroll
    for (int j = 0; j < 4; ++j) {
        int col = bn + wc*64 + j*16 + frow;
        if (col >= N) continue;
        float bz = bias[col];
        #pragma unroll
        for (int i = 0; i < 4; ++i) {
            int row = bm + wr*64 + i*16 + g*4;
            #pragma unroll
            for (int rr = 0; rr < 4; ++rr) {
                float v = acc[i][j][rr] + bz;
                if (relu) v = fmaxf(v, 0.f);
                C[(size_t)(row + rr)*N + col] = v;
            }
        }
    }
}

// softmax over 16 (NL*NP) per (b,s,head), in place
__global__ void softmax16_kernel(float* __restrict__ aw, int n)
{
    int idx = blockIdx.x * blockDim.x + threadIdx.x;
    if (idx >= n) return;
    float* p = aw + (size_t)idx * 16;
    float m = p[0];
    #pragma unroll
    for (int k = 1; k < 16; ++k) m = fmaxf(m, p[k]);
    float s = 0.f;
    float e[16];
    #pragma unroll
    for (int k = 0; k < 16; ++k) { e[k] = expf(p[k]-m); s += e[k]; }
    float inv = 1.0f / s;
    #pragma unroll
    for (int k = 0; k < 16; ++k) p[k] = e[k]*inv;
}

// ms_deform: one block per (b,s), thread = (head, d)
__global__ __launch_bounds__(256) void msdeform_kernel(const float* __restrict__ val,
        const float* __restrict__ offb, const float* __restrict__ awb,
        float* __restrict__ msd)
{
    int bs = blockIdx.x;
    int s  = bs % kS;
    int b  = bs / kS;
    int head = threadIdx.x >> 5;
    int d    = threadIdx.x & 31;
    float refx, refy;
    if (s < 4096)      { int loc = s;        refy = ((loc>>6)+0.5f)/64.f; refx = ((loc&63)+0.5f)/64.f; }
    else if (s < 5120) { int loc = s - 4096; refy = ((loc>>5)+0.5f)/32.f; refx = ((loc&31)+0.5f)/32.f; }
    else if (s < 5376) { int loc = s - 5120; refy = ((loc>>4)+0.5f)/16.f; refx = ((loc&15)+0.5f)/16.f; }
    else               { int loc = s - 5376; refy = ((loc>>3)+0.5f)/8.f;  refx = ((loc&7)+0.5f)/8.f; }
    const float* op = offb + (size_t)bs*256 + head*32;
    const float* ap = awb  + (size_t)bs*128 + head*16;
    const float* vb = val  + (size_t)b*kS*256 + head*32 + d;
    const int WL[4] = {64,32,16,8};
    const int BASE[4] = {0,4096,5120,5376};
    float acc = 0.f;
    #pragma unroll
    for (int l = 0; l < 4; ++l) {
        int wl = WL[l], hl = WL[l], base = BASE[l];
        #pragma unroll
        for (int p = 0; p < 4; ++p) {
            float ox = op[l*8 + p*2 + 0];
            float oy = op[l*8 + p*2 + 1];
            float gx = (refx + ox/wl)*wl - 0.5f;
            float gy = (refy + oy/hl)*hl - 0.5f;
            float x0f = floorf(gx), y0f = floorf(gy);
            float wx1 = gx - x0f, wy1 = gy - y0f;
            int x0 = (int)x0f, y0 = (int)y0f;
            float a = ap[l*4 + p];
            #pragma unroll
            for (int dy = 0; dy < 2; ++dy) {
                int yi = y0 + dy;
                if (yi < 0 || yi >= hl) continue;
                float wy = dy ? wy1 : 1.f - wy1;
                #pragma unroll
                for (int dx = 0; dx < 2; ++dx) {
                    int xi = x0 + dx;
                    if (xi < 0 || xi >= wl) continue;
                    float wx = dx ? wx1 : 1.f - wx1;
                    acc += vb[((size_t)(base + yi*wl + xi))*256] * (wx*wy*a);
                }
            }
        }
    }
    msd[(size_t)bs*256 + head*32 + d] = acc;
}

// src = LayerNorm(src + delta) * g + b   (row = 256)
__global__ __launch_bounds__(256) void add_ln_kernel(float* __restrict__ src,
        const float* __restrict__ delta, const float* __restrict__ g,
        const float* __restrict__ bta)
{
    int row = blockIdx.x;
    int ch  = threadIdx.x;
    size_t idx = (size_t)row*256 + ch;
    float x = src[idx] + delta[idx];
    __shared__ float rs[256];
    rs[ch] = x; __syncthreads();
    for (int off = 128; off; off >>= 1) { if (ch < off) rs[ch] += rs[ch+off]; __syncthreads(); }
    float mu = rs[0] / 256.f;
    __syncthreads();
    float xc = x - mu;
    rs[ch] = xc*xc; __syncthreads();
    for (int off = 128; off; off >>= 1) { if (ch < off) rs[ch] += rs[ch+off]; __syncthreads(); }
    float inv = rsqrtf(rs[0]/256.f + 1e-5f);
    src[idx] = xc * inv * g[ch] + bta[ch];
}

// im2col for conv1: A[m][k], m = b*4096 + y*64 + x, k = c*9 + dy*3 + dx
__global__ void im2col_kernel(const float* __restrict__ src, float* __restrict__ A, int n)
{
    int idx = blockIdx.x * blockDim.x + threadIdx.x;
    if (idx >= n) return;
    int k = idx % 2304;
    int m = idx / 2304;
    int c  = k / 9;
    int r9 = k - c*9;
    int dy = r9 / 3;
    int dx = r9 - dy*3;
    int x = m & 63, y = (m >> 6) & 63, b = m >> 12;
    int yy = y + dy - 1, xx = x + dx - 1;
    float v = 0.f;
    if (yy >= 0 && yy < 64 && xx >= 0 && xx < 64)
        v = src[((size_t)b*kS + yy*64 + xx)*256 + c];
    A[idx] = v;
}

// conv2: 3x3, 64->2; input c1 is NHWC (b, 64x64, 64) from the GEMM; output NCHW
__global__ void conv2_kernel(const float* __restrict__ c1, const float* __restrict__ w,
                             const float* __restrict__ bias, float* __restrict__ pred)
{
    int idx = blockIdx.x * blockDim.x + threadIdx.x;   // B*2*64*64
    int x = idx & 63;
    int y = (idx >> 6) & 63;
    int o = (idx >> 12) & 1;
    int b = idx >> 13;
    float acc = bias[o];
    for (int dy = 0; dy < 3; ++dy) {
        int yy = y + dy - 1;
        if (yy < 0 || yy >= 64) continue;
        for (int dx = 0; dx < 3; ++dx) {
            int xx = x + dx - 1;
            if (xx < 0 || xx >= 64) continue;
            const float* sp = c1 + ((size_t)(b*4096) + yy*64 + xx)*64;
            const float* wp = w + o*576 + dy*3 + dx;
            for (int c = 0; c < 64; ++c) acc += sp[c] * wp[c*9];
        }
    }
    pred[idx] = acc;
}

// bilinear resize 64x64 -> 256x256 (half-pixel, edge clamp == jax.image.resize bilinear)
__global__ void resize_kernel(const float* __restrict__ pred, float* __restrict__ out)
{
    int idx = blockIdx.x * blockDim.x + threadIdx.x;   // B*2*256*256
    int X = idx & 255;
    int Y = (idx >> 8) & 255;
    int c = (idx >> 16) & 1;
    int b = idx >> 17;
    float sx = (X + 0.5f)*0.25f - 0.5f;
    float sy = (Y + 0.5f)*0.25f - 0.5f;
    int x0 = (int)floorf(sx); float fx = sx - x0;
    int y0 = (int)floorf(sy); float fy = sy - y0;
    int x0c = min(max(x0, 0), 63), x1c = min(max(x0+1, 0), 63);
    int y0c = min(max(y0, 0), 63), y1c = min(max(y0+1, 0), 63);
    const float* p = pred + ((size_t)(b*2 + c))*4096;
    float v00 = p[y0c*64 + x0c], v01 = p[y0c*64 + x1c];
    float v10 = p[y1c*64 + x0c], v11 = p[y1c*64 + x1c];
    out[idx] = (1.f-fy)*((1.f-fx)*v00 + fx*v01) + fy*((1.f-fx)*v10 + fx*v11);
}

// ---------------- launch ----------------
extern "C" void kernel_launch(void* const* d_in, const int* in_sizes, int n_in,
                              void* d_out, int out_size, void* d_ws, size_t ws_size,
                              hipStream_t stream)
{
    const float* F[3][4];
    for (int t = 0; t < 3; ++t)
        for (int l = 0; l < 4; ++l)
            F[t][l] = (const float*)d_in[t*4 + l];
    const float* tfw = (const float*)d_in[12];
    const float *pw[4], *pb[4], *gg[4], *gb[4];
    for (int l = 0; l < 4; ++l) {
        pw[l] = (const float*)d_in[13 + 4*l];
        pb[l] = (const float*)d_in[14 + 4*l];
        gg[l] = (const float*)d_in[15 + 4*l];
        gb[l] = (const float*)d_in[16 + 4*l];
    }
    const float* lev   = (const float*)d_in[29];
    const float* off_w = (const float*)d_in[30];
    const float* off_b = (const float*)d_in[31];
    const float* aw_w  = (const float*)d_in[32];
    const float* aw_b  = (const float*)d_in[33];
    const float* val_w = (const float*)d_in[34];
    const float* val_b = (const float*)d_in[35];
    const float* out_w = (const float*)d_in[36];
    const float* out_b = (const float*)d_in[37];
    const float* ln1g  = (const float*)d_in[38];
    const float* ln1b  = (const float*)d_in[39];
    const float* ff1w  = (const float*)d_in[40];
    const float* ff1b  = (const float*)d_in[41];
    const float* ff2w  = (const float*)d_in[42];
    const float* ff2b  = (const float*)d_in[43];
    const float* ln2g  = (const float*)d_in[44];
    const float* ln2b  = (const float*)d_in[45];
    const float* c1w   = (const float*)d_in[46];
    const float* c1b   = (const float*)d_in[47];
    const float* c2w   = (const float*)d_in[48];
    const float* c2b   = (const float*)d_in[49];

    const size_t N256 = (size_t)kB * kS * 256;        // 5,570,560
    float* ws   = (float*)d_ws;
    float* src  = ws;
    float* pos  = src + N256;
    float* q    = pos + N256;
    float* offb = q + N256;
    float* awb  = offb + N256;                        // B*S*128
    float* val  = awb + (size_t)kB*kS*128;
    float* msd  = val + N256;
    float* tmp  = msd + N256;
    float* ffh  = tmp + N256;                         // B*S*1024 floats
    // stage-1 aliases inside ffh (dead during encoder loop)
    float* fused = ffh;
    float* xbuf  = ffh + (size_t)kB*128*4096;
    // head aliases: everything except src is dead after the encoder loop
    float* Acol  = pos;                               // im2col: 16384*2304 floats (fits: ends at 43.3M < 64M)
    float* c1o   = ws + (size_t)44*1024*1024;         // 16384*64 floats
    float* pred  = ws + (size_t)46*1024*1024;         // 32768 floats

    const int LVL_HWS[4]  = {4096, 1024, 256, 64};
    const int LVL_BASE[4] = {0, 4096, 5120, 5376};
    const int LVL_C[4]    = {128, 256, 512, 512};
    const int LVL_PRIOR[4]= {0, 128, 256, 512};       // reference's literal (non-cumulative) priors
    const int LVL_DIM[4]  = {64, 32, 16, 8};

    // ---- stage 1: per-level fuse + proj + GN (+transpose into src) + pos ----
    for (int l = 0; l < 4; ++l) {
        int hw = LVL_HWS[l], c = LVL_C[l];
        int n1 = kB * c * hw;
        fuse_kernel<<<(n1+255)/256, 256, 0, stream>>>(F[0][l], F[1][l], F[2][l], tfw,
                                                      fused, c, hw, LVL_PRIOR[l], n1);
        int n2 = kB * kH * hw;
        proj1x1_kernel<<<(n2+255)/256, 256, 0, stream>>>(fused, pw[l], pb[l], xbuf, c, hw, n2);
        gn_kernel<<<kB*32, 256, 0, stream>>>(xbuf, gg[l], gb[l], src, hw, LVL_BASE[l]);
        int n3 = hw * kH;
        pos_kernel<<<(n3+255)/256, 256, 0, stream>>>(lev, pos, LVL_DIM[l], LVL_DIM[l],
                                                     LVL_BASE[l], l, n3);
    }

    // ---- stage 2: 6 encoder layers ----
    for (int i = 0; i < 6; ++i) {
        add_kernel<<<(int)((N256+255)/256), 256, 0, stream>>>(src, pos, q, (int)N256);

        dim3 g1(kM/128, 2);   // N=256
        gemm_mfma_kernel<<<g1, 256, 0, stream>>>(q, off_w + (size_t)i*256*256, off_b + i*256,
                                                 offb, kM, 256, 256, 0);
        dim3 g2(kM/128, 1);   // N=128
        gemm_mfma_kernel<<<g2, 256, 0, stream>>>(q, aw_w + (size_t)i*128*256, aw_b + i*128,
                                                 awb, kM, 128, 256, 0);
        int nsm = kM * kNH;
        softmax16_kernel<<<(nsm+255)/256, 256, 0, stream>>>(awb, nsm);

        gemm_mfma_kernel<<<g1, 256, 0, stream>>>(src, val_w + (size_t)i*256*256, val_b + i*256,
                                                 val, kM, 256, 256, 0);
        msdeform_kernel<<<kM, 256, 0, stream>>>(val, offb, awb, msd);
        gemm_mfma_kernel<<<g1, 256, 0, stream>>>(msd, out_w + (size_t)i*256*256, out_b + i*256,
                                                 tmp, kM, 256, 256, 0);
        add_ln_kernel<<<kM, 256, 0, stream>>>(src, tmp, ln1g + i*256, ln1b + i*256);

        dim3 g3(kM/128, 8);   // N=1024
        gemm_mfma_kernel<<<g3, 256, 0, stream>>>(src, ff1w + (size_t)i*1024*256, ff1b + i*1024,
                                                 ffh, kM, 1024, 256, 1);
        gemm_mfma_kernel<<<g1, 256, 0, stream>>>(ffh, ff2w + (size_t)i*256*1024, ff2b + i*256,
                                                 tmp, kM, 256, 1024, 0);
        add_ln_kernel<<<kM, 256, 0, stream>>>(src, tmp, ln2g + i*256, ln2b + i*256);
    }

    // ---- stage 3: head (conv1 as im2col + MFMA GEMM, N=64, relu) ----
    {
        int nim = 16384 * 2304;
        im2col_kernel<<<(nim+255)/256, 256, 0, stream>>>(src, Acol, nim);
        dim3 gc(16384/128, 1);
        gemm_mfma_kernel<<<gc, 256, 0, stream>>>(Acol, c1w, c1b, c1o, 16384, 64, 2304, 1);
        conv2_kernel<<<(kB*2*64*64)/256, 256, 0, stream>>>(c1o, c2w, c2b, pred);
        resize_kernel<<<(kB*2*256*256)/256, 256, 0, stream>>>(pred, (float*)d_out);
    }
}

// Round 3
// 2212.420 us; speedup vs baseline: 4.0924x; 1.7577x over previous
//
#include <hip/hip_runtime.h>
#include <math.h>

// ---------------- problem constants ----------------
constexpr int kB = 4;
constexpr int kS = 5440;           // 64*64 + 32*32 + 16*16 + 8*8
constexpr int kH = 256;            // HIDDEN
constexpr int kNH = 8, kNL = 4, kNP = 4, kDH = 32;
constexpr int kM = kB * kS;        // 21760 rows
constexpr int kCHSUM = 1408;       // sum(CHS)

typedef __attribute__((ext_vector_type(8))) short short8v;   // 8 bf16 in 4 VGPRs
typedef __attribute__((ext_vector_type(4))) float f32x4;

__device__ inline short bf16rne(float f) {
    unsigned u = __float_as_uint(f);
    u += 0x7FFF + ((u >> 16) & 1);
    return (short)(u >> 16);
}

// ---------------- stage-1 kernels ----------------

// fused (transposed): out[(b*hw+p)*c + ch] = sum_t f_t[b,ch,p] * softmax_t(tfw[:,prior+ch])
// 32x32 LDS transpose tile so both global read and write are coalesced.
__global__ __launch_bounds__(256) void fuseT_kernel(const float* __restrict__ f0,
        const float* __restrict__ f1, const float* __restrict__ f2,
        const float* __restrict__ tfw, float* __restrict__ out,
        int c, int hw, int prior)
{
    __shared__ float tile[32][33];
    int p0 = blockIdx.x * 32;
    int c0 = blockIdx.y * 32;
    int b  = blockIdx.z;
    int tx  = threadIdx.x & 31;
    int ty8 = threadIdx.x >> 5;      // 0..7
    #pragma unroll
    for (int i = 0; i < 4; ++i) {
        int ch = c0 + ty8 + i*8;
        float t0 = tfw[0*kCHSUM + prior + ch];
        float t1 = tfw[1*kCHSUM + prior + ch];
        float t2 = tfw[2*kCHSUM + prior + ch];
        float m = fmaxf(t0, fmaxf(t1, t2));
        float e0 = expf(t0-m), e1 = expf(t1-m), e2 = expf(t2-m);
        float inv = 1.0f / (e0+e1+e2);
        size_t base = ((size_t)b*c + ch)*hw + p0 + tx;
        tile[ty8+i*8][tx] = f0[base]*(e0*inv) + f1[base]*(e1*inv) + f2[base]*(e2*inv);
    }
    __syncthreads();
    #pragma unroll
    for (int i = 0; i < 4; ++i) {
        int p = p0 + ty8 + i*8;
        out[((size_t)b*hw + p)*c + c0 + tx] = tile[tx][ty8+i*8];
    }
}

// GroupNorm on xbufT [(b*hw+p)*256 + ch], write transposed into src[b, sbase+p, ch]
__global__ __launch_bounds__(256) void gn_t_kernel(const float* __restrict__ xbufT,
                          const float* __restrict__ gg, const float* __restrict__ gb,
                          float* __restrict__ src, int hw, int sbase)
{
    int b = blockIdx.x >> 5;
    int g = blockIdx.x & 31;
    int n = 8 * hw;
    const float* base = xbufT + (size_t)b*hw*256 + g*8;
    float s = 0.f, s2 = 0.f;
    for (int e = threadIdx.x; e < n; e += 256) {
        float v = base[(size_t)(e>>3)*256 + (e&7)];
        s += v; s2 += v*v;
    }
    __shared__ float rs[256], rq[256];
    rs[threadIdx.x] = s; rq[threadIdx.x] = s2; __syncthreads();
    for (int off = 128; off; off >>= 1) {
        if (threadIdx.x < off) { rs[threadIdx.x] += rs[threadIdx.x+off]; rq[threadIdx.x] += rq[threadIdx.x+off]; }
        __syncthreads();
    }
    float mu  = rs[0] / n;
    float var = rq[0] / n - mu*mu;
    float inv = rsqrtf(var + 1e-5f);
    for (int e = threadIdx.x; e < n; e += 256) {
        int p = e>>3, chl = e&7;
        int ch = g*8 + chl;
        float v = (base[(size_t)p*256 + chl] - mu) * inv;
        src[((size_t)b*kS + sbase + p)*kH + ch] = v * gg[ch] + gb[ch];
    }
}

// sine position embedding + level embed, broadcast over batch
__global__ void pos_kernel(const float* __restrict__ lev, float* __restrict__ pos,
                           int h, int w, int sbase, int lvl, int n)
{
    int idx = blockIdx.x * blockDim.x + threadIdx.x;
    if (idx >= n) return;                 // n = h*w*256
    int ch = idx % kH;
    int p  = idx / kH;
    int py = p / w, px = p % w;
    int c2 = ch & 127;
    int i  = c2 >> 1;
    float dt = powf(10000.0f, (float)i / 64.0f);
    float t;
    if (ch < 128) t = (py + 1) / ((float)h + 1e-6f) * 6.2831853071795864f;
    else          t = (px + 1) / ((float)w + 1e-6f) * 6.2831853071795864f;
    float arg = t / dt;
    float val = (c2 & 1) ? cosf(arg) : sinf(arg);
    val += lev[lvl*kH + ch];
    for (int b = 0; b < kB; ++b)
        pos[((size_t)b*kS + sbase + p)*kH + ch] = val;
}

// concat off/aw weights: Wcat[i][384][256], bcat[i][384]
__global__ void concat_w_kernel(const float* __restrict__ off_w, const float* __restrict__ aw_w,
                                float* __restrict__ Wcat, int n)
{
    int idx = blockIdx.x * blockDim.x + threadIdx.x;
    if (idx >= n) return;                 // n = 6*384*256
    int col = idx & 255;
    int row = (idx >> 8) % 384;
    int i   = idx / (384*256);
    float v = (row < 256) ? off_w[((size_t)i*256 + row)*256 + col]
                          : aw_w[((size_t)i*128 + row-256)*256 + col];
    Wcat[idx] = v;
}
__global__ void concat_b_kernel(const float* __restrict__ off_b, const float* __restrict__ aw_b,
                                float* __restrict__ bcat, int n)
{
    int idx = blockIdx.x * blockDim.x + threadIdx.x;
    if (idx >= n) return;                 // n = 6*384
    int row = idx % 384;
    int i   = idx / 384;
    bcat[idx] = (row < 256) ? off_b[i*256 + row] : aw_b[i*128 + row-256];
}

// ---------------- MFMA bf16 GEMM ----------------
// C[m,n] = sum_k A[m,k]*W[n,k] + bias[n]
// AMODE: 0 = A fp32; 1 = A fp32 + A2 elementwise add (q = src+pos); 2 = A already bf16.
// 128x128 tile, BK=32, 256 threads (4 waves 2x2), 4x4 16x16x32 fragments/wave.
// LDS row stride 40 bf16 (80B) -> fragment reads 2 lanes/bank (free).
// M,K multiples of 128/32; N arbitrary (guarded).
template<int AMODE>
__global__ __launch_bounds__(256) void gemm_mfma(const void* __restrict__ Av,
        const float* __restrict__ A2, const float* __restrict__ W,
        const float* __restrict__ bias, float* __restrict__ C,
        int M, int N, int K, int relu)
{
    __shared__ short Asm[128 * 40];
    __shared__ short Bsm[128 * 40];
    const int t    = threadIdx.x;
    const int bm   = blockIdx.x * 128;
    const int bn   = blockIdx.y * 128;
    const int lane = t & 63;
    const int wid  = t >> 6;
    const int wr   = wid >> 1;
    const int wc   = wid & 1;
    const int frow = lane & 15;
    const int g    = lane >> 4;
    const int sr = t >> 1;             // staging row 0..127
    const int sc = (t & 1) * 16;       // staging col 0 or 16

    f32x4 acc[4][4];
    #pragma unroll
    for (int i = 0; i < 4; ++i)
        #pragma unroll
        for (int j = 0; j < 4; ++j)
            acc[i][j] = (f32x4){0.f, 0.f, 0.f, 0.f};

    const int wrow_ok = (bn + sr) < N;

    for (int k0 = 0; k0 < K; k0 += 32) {
        short8v av, av2, wv, wv2;
        if constexpr (AMODE == 2) {
            const short* Ab = (const short*)Av;
            const short8v* Ap = (const short8v*)(Ab + (size_t)(bm + sr)*K + k0 + sc);
            av = Ap[0]; av2 = Ap[1];
        } else {
            const float* Af = (const float*)Av;
            const float4* Ap = (const float4*)(Af + (size_t)(bm + sr)*K + k0 + sc);
            float4 a0 = Ap[0], a1 = Ap[1], a2 = Ap[2], a3 = Ap[3];
            if constexpr (AMODE == 1) {
                const float4* Pp = (const float4*)(A2 + (size_t)(bm + sr)*K + k0 + sc);
                float4 p0 = Pp[0], p1 = Pp[1], p2 = Pp[2], p3 = Pp[3];
                a0.x+=p0.x; a0.y+=p0.y; a0.z+=p0.z; a0.w+=p0.w;
                a1.x+=p1.x; a1.y+=p1.y; a1.z+=p1.z; a1.w+=p1.w;
                a2.x+=p2.x; a2.y+=p2.y; a2.z+=p2.z; a2.w+=p2.w;
                a3.x+=p3.x; a3.y+=p3.y; a3.z+=p3.z; a3.w+=p3.w;
            }
            av[0]=bf16rne(a0.x); av[1]=bf16rne(a0.y); av[2]=bf16rne(a0.z); av[3]=bf16rne(a0.w);
            av[4]=bf16rne(a1.x); av[5]=bf16rne(a1.y); av[6]=bf16rne(a1.z); av[7]=bf16rne(a1.w);
            av2[0]=bf16rne(a2.x); av2[1]=bf16rne(a2.y); av2[2]=bf16rne(a2.z); av2[3]=bf16rne(a2.w);
            av2[4]=bf16rne(a3.x); av2[5]=bf16rne(a3.y); av2[6]=bf16rne(a3.z); av2[7]=bf16rne(a3.w);
        }
        {
            float4 w0 = {0,0,0,0}, w1 = {0,0,0,0}, w2 = {0,0,0,0}, w3 = {0,0,0,0};
            if (wrow_ok) {
                const float4* Wp = (const float4*)(W + (size_t)(bn + sr)*K + k0 + sc);
                w0 = Wp[0]; w1 = Wp[1]; w2 = Wp[2]; w3 = Wp[3];
            }
            wv[0]=bf16rne(w0.x); wv[1]=bf16rne(w0.y); wv[2]=bf16rne(w0.z); wv[3]=bf16rne(w0.w);
            wv[4]=bf16rne(w1.x); wv[5]=bf16rne(w1.y); wv[6]=bf16rne(w1.z); wv[7]=bf16rne(w1.w);
            wv2[0]=bf16rne(w2.x); wv2[1]=bf16rne(w2.y); wv2[2]=bf16rne(w2.z); wv2[3]=bf16rne(w2.w);
            wv2[4]=bf16rne(w3.x); wv2[5]=bf16rne(w3.y); wv2[6]=bf16rne(w3.z); wv2[7]=bf16rne(w3.w);
        }
        __syncthreads();   // previous iteration's fragment reads done before overwrite
        *(short8v*)&Asm[sr*40 + sc]     = av;
        *(short8v*)&Asm[sr*40 + sc + 8] = av2;
        *(short8v*)&Bsm[sr*40 + sc]     = wv;
        *(short8v*)&Bsm[sr*40 + sc + 8] = wv2;
        __syncthreads();

        short8v af[4], bf[4];
        #pragma unroll
        for (int i = 0; i < 4; ++i)
            af[i] = *(const short8v*)&Asm[(wr*64 + i*16 + frow)*40 + g*8];
        #pragma unroll
        for (int j = 0; j < 4; ++j)
            bf[j] = *(const short8v*)&Bsm[(wc*64 + j*16 + frow)*40 + g*8];
        #pragma unroll
        for (int i = 0; i < 4; ++i)
            #pragma unroll
            for (int j = 0; j < 4; ++j)
                acc[i][j] = __builtin_amdgcn_mfma_f32_16x16x32_bf16(af[i], bf[j], acc[i][j], 0, 0, 0);
    }

    // epilogue: D row = (lane>>4)*4 + reg, col = lane&15  (m89-verified)
    #pragma unroll
    for (int j = 0; j < 4; ++j) {
        int col = bn + wc*64 + j*16 + frow;
        if (col >= N) continue;
        float bz = bias[col];
        #pragma unroll
        for (int i = 0; i < 4; ++i) {
            int row = bm + wr*64 + i*16 + g*4;
            #pragma unroll
            for (int rr = 0; rr < 4; ++rr) {
                float v = acc[i][j][rr] + bz;
                if (relu) v = fmaxf(v, 0.f);
                C[(size_t)(row + rr)*N + col] = v;
            }
        }
    }
}

// softmax over 16 per (b,s,head), in place on cat cols 256..383 (row stride 384)
__global__ void softmax16_kernel(float* __restrict__ cat, int n)
{
    int idx = blockIdx.x * blockDim.x + threadIdx.x;
    if (idx >= n) return;
    float* p = cat + (size_t)(idx >> 3)*384 + 256 + (idx & 7)*16;
    f32x4 v0 = ((f32x4*)p)[0], v1 = ((f32x4*)p)[1], v2 = ((f32x4*)p)[2], v3 = ((f32x4*)p)[3];
    float m = v0[0];
    #pragma unroll
    for (int k = 1; k < 4; ++k) m = fmaxf(m, v0[k]);
    #pragma unroll
    for (int k = 0; k < 4; ++k) { m = fmaxf(m, v1[k]); m = fmaxf(m, v2[k]); m = fmaxf(m, v3[k]); }
    float s = 0.f;
    #pragma unroll
    for (int k = 0; k < 4; ++k) { v0[k] = expf(v0[k]-m); s += v0[k]; }
    #pragma unroll
    for (int k = 0; k < 4; ++k) { v1[k] = expf(v1[k]-m); s += v1[k]; }
    #pragma unroll
    for (int k = 0; k < 4; ++k) { v2[k] = expf(v2[k]-m); s += v2[k]; }
    #pragma unroll
    for (int k = 0; k < 4; ++k) { v3[k] = expf(v3[k]-m); s += v3[k]; }
    float inv = 1.0f / s;
    ((f32x4*)p)[0] = v0*inv; ((f32x4*)p)[1] = v1*inv;
    ((f32x4*)p)[2] = v2*inv; ((f32x4*)p)[3] = v3*inv;
}

// ms_deform, float4 channels: thread = (s_local, head, d4); block = 4 (b,s) pairs
__global__ __launch_bounds__(256) void msdeform4_kernel(const float* __restrict__ val,
        const float* __restrict__ cat, float* __restrict__ msd)
{
    int tid  = threadIdx.x;
    int d4   = tid & 7;
    int head = (tid >> 3) & 7;
    int bs   = blockIdx.x*4 + (tid >> 6);
    int s  = bs % kS;
    int b  = bs / kS;
    float refx, refy;
    if (s < 4096)      { int loc = s;        refy = ((loc>>6)+0.5f)/64.f; refx = ((loc&63)+0.5f)/64.f; }
    else if (s < 5120) { int loc = s - 4096; refy = ((loc>>5)+0.5f)/32.f; refx = ((loc&31)+0.5f)/32.f; }
    else if (s < 5376) { int loc = s - 5120; refy = ((loc>>4)+0.5f)/16.f; refx = ((loc&15)+0.5f)/16.f; }
    else               { int loc = s - 5376; refy = ((loc>>3)+0.5f)/8.f;  refx = ((loc&7)+0.5f)/8.f; }
    const float* op = cat + (size_t)bs*384 + head*32;
    const float* ap = cat + (size_t)bs*384 + 256 + head*16;
    const float* vb = val + (size_t)b*kS*256 + head*32 + d4*4;
    const int WL[4] = {64,32,16,8};
    const int BASE[4] = {0,4096,5120,5376};
    f32x4 acc = {0.f,0.f,0.f,0.f};
    #pragma unroll
    for (int l = 0; l < 4; ++l) {
        int wl = WL[l], hl = WL[l], base = BASE[l];
        #pragma unroll
        for (int p = 0; p < 4; ++p) {
            float ox = op[l*8 + p*2 + 0];
            float oy = op[l*8 + p*2 + 1];
            float gx = (refx + ox/wl)*wl - 0.5f;
            float gy = (refy + oy/hl)*hl - 0.5f;
            float x0f = floorf(gx), y0f = floorf(gy);
            float wx1 = gx - x0f, wy1 = gy - y0f;
            int x0 = (int)x0f, y0 = (int)y0f;
            float a = ap[l*4 + p];
            #pragma unroll
            for (int dy = 0; dy < 2; ++dy) {
                int yi = y0 + dy;
                if (yi < 0 || yi >= hl) continue;
                float wy = dy ? wy1 : 1.f - wy1;
                #pragma unroll
                for (int dx = 0; dx < 2; ++dx) {
                    int xi = x0 + dx;
                    if (xi < 0 || xi >= wl) continue;
                    float wx = dx ? wx1 : 1.f - wx1;
                    f32x4 v = *(const f32x4*)&vb[(size_t)(base + yi*wl + xi)*256];
                    float wgt = wx*wy*a;
                    acc[0] += v[0]*wgt; acc[1] += v[1]*wgt;
                    acc[2] += v[2]*wgt; acc[3] += v[3]*wgt;
                }
            }
        }
    }
    *(f32x4*)&msd[(size_t)bs*256 + head*32 + d4*4] = acc;
}

// src = LayerNorm(src + delta) * g + b ; one wave per row, float4 + shfl reduce
__global__ __launch_bounds__(256) void add_ln_kernel(float* __restrict__ src,
        const float* __restrict__ delta, const float* __restrict__ g,
        const float* __restrict__ bta)
{
    int lane = threadIdx.x & 63;
    int row  = blockIdx.x*4 + (threadIdx.x >> 6);
    f32x4* s4 = (f32x4*)(src + (size_t)row*256);
    const f32x4* d4 = (const f32x4*)(delta + (size_t)row*256);
    f32x4 x = s4[lane];
    f32x4 dd = d4[lane];
    x[0]+=dd[0]; x[1]+=dd[1]; x[2]+=dd[2]; x[3]+=dd[3];
    float s = x[0]+x[1]+x[2]+x[3];
    #pragma unroll
    for (int o = 1; o < 64; o <<= 1) s += __shfl_xor(s, o);
    float mu = s * (1.f/256.f);
    f32x4 xc;
    xc[0]=x[0]-mu; xc[1]=x[1]-mu; xc[2]=x[2]-mu; xc[3]=x[3]-mu;
    float s2 = xc[0]*xc[0]+xc[1]*xc[1]+xc[2]*xc[2]+xc[3]*xc[3];
    #pragma unroll
    for (int o = 1; o < 64; o <<= 1) s2 += __shfl_xor(s2, o);
    float inv = rsqrtf(s2*(1.f/256.f) + 1e-5f);
    const f32x4 gv = ((const f32x4*)g)[lane];
    const f32x4 bv = ((const f32x4*)bta)[lane];
    f32x4 o4;
    o4[0]=xc[0]*inv*gv[0]+bv[0]; o4[1]=xc[1]*inv*gv[1]+bv[1];
    o4[2]=xc[2]*inv*gv[2]+bv[2]; o4[3]=xc[3]*inv*gv[3]+bv[3];
    s4[lane] = o4;
}

// im2col for conv1 in bf16: A[m][k], m = b*4096 + y*64 + x, k = c*9 + dy*3 + dx
__global__ void im2col_bf16_kernel(const float* __restrict__ src, short* __restrict__ A, int n)
{
    int idx = blockIdx.x * blockDim.x + threadIdx.x;
    if (idx >= n) return;
    int k = idx % 2304;
    int m = idx / 2304;
    int c  = k / 9;
    int r9 = k - c*9;
    int dy = r9 / 3;
    int dx = r9 - dy*3;
    int x = m & 63, y = (m >> 6) & 63, b = m >> 12;
    int yy = y + dy - 1, xx = x + dx - 1;
    float v = 0.f;
    if (yy >= 0 && yy < 64 && xx >= 0 && xx < 64)
        v = src[((size_t)b*kS + yy*64 + xx)*256 + c];
    A[idx] = bf16rne(v);
}

// conv2: 3x3, 64->2; input c1 is NHWC (b, 64x64, 64); output NCHW
__global__ void conv2_kernel(const float* __restrict__ c1, const float* __restrict__ w,
                             const float* __restrict__ bias, float* __restrict__ pred)
{
    int idx = blockIdx.x * blockDim.x + threadIdx.x;   // B*2*64*64
    int x = idx & 63;
    int y = (idx >> 6) & 63;
    int o = (idx >> 12) & 1;
    int b = idx >> 13;
    float acc = bias[o];
    for (int dy = 0; dy < 3; ++dy) {
        int yy = y + dy - 1;
        if (yy < 0 || yy >= 64) continue;
        for (int dx = 0; dx < 3; ++dx) {
            int xx = x + dx - 1;
            if (xx < 0 || xx >= 64) continue;
            const float* sp = c1 + ((size_t)(b*4096) + yy*64 + xx)*64;
            const float* wp = w + o*576 + dy*3 + dx;
            for (int c = 0; c < 64; ++c) acc += sp[c] * wp[c*9];
        }
    }
    pred[idx] = acc;
}

// bilinear resize 64x64 -> 256x256 (half-pixel, edge clamp)
__global__ void resize_kernel(const float* __restrict__ pred, float* __restrict__ out)
{
    int idx = blockIdx.x * blockDim.x + threadIdx.x;   // B*2*256*256
    int X = idx & 255;
    int Y = (idx >> 8) & 255;
    int c = (idx >> 16) & 1;
    int b = idx >> 17;
    float sx = (X + 0.5f)*0.25f - 0.5f;
    float sy = (Y + 0.5f)*0.25f - 0.5f;
    int x0 = (int)floorf(sx); float fx = sx - x0;
    int y0 = (int)floorf(sy); float fy = sy - y0;
    int x0c = min(max(x0, 0), 63), x1c = min(max(x0+1, 0), 63);
    int y0c = min(max(y0, 0), 63), y1c = min(max(y0+1, 0), 63);
    const float* p = pred + ((size_t)(b*2 + c))*4096;
    float v00 = p[y0c*64 + x0c], v01 = p[y0c*64 + x1c];
    float v10 = p[y1c*64 + x0c], v11 = p[y1c*64 + x1c];
    out[idx] = (1.f-fy)*((1.f-fx)*v00 + fx*v01) + fy*((1.f-fx)*v10 + fx*v11);
}

// ---------------- launch ----------------
extern "C" void kernel_launch(void* const* d_in, const int* in_sizes, int n_in,
                              void* d_out, int out_size, void* d_ws, size_t ws_size,
                              hipStream_t stream)
{
    const float* F[3][4];
    for (int t = 0; t < 3; ++t)
        for (int l = 0; l < 4; ++l)
            F[t][l] = (const float*)d_in[t*4 + l];
    const float* tfw = (const float*)d_in[12];
    const float *pw[4], *pb[4], *gg[4], *gb[4];
    for (int l = 0; l < 4; ++l) {
        pw[l] = (const float*)d_in[13 + 4*l];
        pb[l] = (const float*)d_in[14 + 4*l];
        gg[l] = (const float*)d_in[15 + 4*l];
        gb[l] = (const float*)d_in[16 + 4*l];
    }
    const float* lev   = (const float*)d_in[29];
    const float* off_w = (const float*)d_in[30];
    const float* off_b = (const float*)d_in[31];
    const float* aw_w  = (const float*)d_in[32];
    const float* aw_b  = (const float*)d_in[33];
    const float* val_w = (const float*)d_in[34];
    const float* val_b = (const float*)d_in[35];
    const float* out_w = (const float*)d_in[36];
    const float* out_b = (const float*)d_in[37];
    const float* ln1g  = (const float*)d_in[38];
    const float* ln1b  = (const float*)d_in[39];
    const float* ff1w  = (const float*)d_in[40];
    const float* ff1b  = (const float*)d_in[41];
    const float* ff2w  = (const float*)d_in[42];
    const float* ff2b  = (const float*)d_in[43];
    const float* ln2g  = (const float*)d_in[44];
    const float* ln2b  = (const float*)d_in[45];
    const float* c1w   = (const float*)d_in[46];
    const float* c1b   = (const float*)d_in[47];
    const float* c2w   = (const float*)d_in[48];
    const float* c2b   = (const float*)d_in[49];

    const size_t N256 = (size_t)kB * kS * 256;        // 5,570,560
    float* ws   = (float*)d_ws;
    float* src  = ws;                                 // 5.57M
    float* pos  = src + N256;                         // 5.57M
    float* cat  = pos + N256;                         // kM*384 = 8.36M
    float* val  = cat + (size_t)kM*384;               // 5.57M
    float* msd  = val + N256;                         // 5.57M
    float* tmp  = msd + N256;                         // 5.57M
    float* ffh  = tmp + N256;                         // kM*1024 = 22.28M
    float* Wcat = ffh + (size_t)kM*1024;              // 6*384*256
    float* bcat = Wcat + (size_t)6*384*256;           // 6*384
    // stage-1 aliases inside ffh (dead during encoder loop)
    float* fusedT = ffh;                              // ≤ 2.1M
    float* xbufT  = ffh + (size_t)5*1024*1024;        // ≤ 4.2M
    // head aliases (after encoder loop): Acol in ffh (bf16), c1o in tmp, pred in msd
    short* Acol  = (short*)ffh;                       // 16384*2304 shorts = 18.9M float-slots
    float* c1o   = tmp;                               // 16384*64
    float* pred  = msd;                               // 32768

    const int LVL_HWS[4]  = {4096, 1024, 256, 64};
    const int LVL_BASE[4] = {0, 4096, 5120, 5376};
    const int LVL_C[4]    = {128, 256, 512, 512};
    const int LVL_PRIOR[4]= {0, 128, 256, 512};       // reference's literal (non-cumulative) priors

    // ---- weight concat (off|aw) ----
    {
        int n = 6*384*256;
        concat_w_kernel<<<(n+255)/256, 256, 0, stream>>>(off_w, aw_w, Wcat, n);
        concat_b_kernel<<<(6*384+255)/256, 256, 0, stream>>>(off_b, aw_b, bcat, 6*384);
    }

    // ---- stage 1: fuse(T) + proj GEMM + GN(+transpose into src) + pos ----
    for (int l = 0; l < 4; ++l) {
        int hw = LVL_HWS[l], c = LVL_C[l];
        dim3 gf(hw/32, c/32, kB);
        fuseT_kernel<<<gf, 256, 0, stream>>>(F[0][l], F[1][l], F[2][l], tfw,
                                             fusedT, c, hw, LVL_PRIOR[l]);
        dim3 gp((kB*hw)/128, 2);
        gemm_mfma<0><<<gp, 256, 0, stream>>>(fusedT, nullptr, pw[l], pb[l], xbufT,
                                             kB*hw, 256, c, 0);
        gn_t_kernel<<<kB*32, 256, 0, stream>>>(xbufT, gg[l], gb[l], src, hw, LVL_BASE[l]);
        int dim = (l==0)?64:(l==1)?32:(l==2)?16:8;
        int n3 = hw * kH;
        pos_kernel<<<(n3+255)/256, 256, 0, stream>>>(lev, pos, dim, dim, LVL_BASE[l], l, n3);
    }

    // ---- stage 2: 6 encoder layers ----
    for (int i = 0; i < 6; ++i) {
        dim3 gcat(kM/128, 3);   // N=384 (off|aw), q=src+pos fused into staging
        gemm_mfma<1><<<gcat, 256, 0, stream>>>(src, pos, Wcat + (size_t)i*384*256,
                                               bcat + i*384, cat, kM, 384, 256, 0);
        int nsm = kM * kNH;
        softmax16_kernel<<<(nsm+255)/256, 256, 0, stream>>>(cat, nsm);

        dim3 g1(kM/128, 2);     // N=256
        gemm_mfma<0><<<g1, 256, 0, stream>>>(src, nullptr, val_w + (size_t)i*256*256,
                                             val_b + i*256, val, kM, 256, 256, 0);
        msdeform4_kernel<<<kM/4, 256, 0, stream>>>(val, cat, msd);
        gemm_mfma<0><<<g1, 256, 0, stream>>>(msd, nullptr, out_w + (size_t)i*256*256,
                                             out_b + i*256, tmp, kM, 256, 256, 0);
        add_ln_kernel<<<kM/4, 256, 0, stream>>>(src, tmp, ln1g + i*256, ln1b + i*256);

        dim3 g3(kM/128, 8);     // N=1024
        gemm_mfma<0><<<g3, 256, 0, stream>>>(src, nullptr, ff1w + (size_t)i*1024*256,
                                             ff1b + i*1024, ffh, kM, 1024, 256, 1);
        gemm_mfma<0><<<g1, 256, 0, stream>>>(ffh, nullptr, ff2w + (size_t)i*256*1024,
                                             ff2b + i*256, tmp, kM, 256, 1024, 0);
        add_ln_kernel<<<kM/4, 256, 0, stream>>>(src, tmp, ln2g + i*256, ln2b + i*256);
    }

    // ---- stage 3: head ----
    {
        int nim = 16384 * 2304;
        im2col_bf16_kernel<<<(nim+255)/256, 256, 0, stream>>>(src, Acol, nim);
        dim3 gc(16384/128, 1);
        gemm_mfma<2><<<gc, 256, 0, stream>>>(Acol, nullptr, c1w, c1b, c1o, 16384, 64, 2304, 1);
        conv2_kernel<<<(kB*2*64*64)/256, 256, 0, stream>>>(c1o, c2w, c2b, pred);
        resize_kernel<<<(kB*2*256*256)/256, 256, 0, stream>>>(pred, (float*)d_out);
    }
}

// Round 4
// 1635.245 us; speedup vs baseline: 5.5368x; 1.3530x over previous
//
#include <hip/hip_runtime.h>
#include <math.h>

// ---------------- problem constants ----------------
constexpr int kB = 4;
constexpr int kS = 5440;           // 64*64 + 32*32 + 16*16 + 8*8
constexpr int kH = 256;            // HIDDEN
constexpr int kNH = 8, kNL = 4, kNP = 4, kDH = 32;
constexpr int kM = kB * kS;        // 21760 rows
constexpr int kCHSUM = 1408;       // sum(CHS)

typedef __attribute__((ext_vector_type(8))) short short8v;   // 8 bf16 (4 VGPRs)
typedef __attribute__((ext_vector_type(4))) short short4v;   // 4 bf16 (8 B)
typedef __attribute__((ext_vector_type(4))) float f32x4;

__device__ inline short bf16rne(float f) {
    unsigned u = __float_as_uint(f);
    u += 0x7FFF + ((u >> 16) & 1);
    return (short)(u >> 16);
}
__device__ inline float bf2f(short s) {
    return __uint_as_float(((unsigned)(unsigned short)s) << 16);
}

// ---------------- prep kernels ----------------

// flat fp32 -> bf16 convert (n multiple of 4)
__global__ void f2bf_kernel(const float* __restrict__ in, short* __restrict__ out, int n)
{
    int idx = (blockIdx.x * blockDim.x + threadIdx.x) * 4;
    if (idx >= n) return;
    f32x4 v = *(const f32x4*)(in + idx);
    short4v o;
    o[0]=bf16rne(v[0]); o[1]=bf16rne(v[1]); o[2]=bf16rne(v[2]); o[3]=bf16rne(v[3]);
    *(short4v*)(out + idx) = o;
}

// concat off/aw weights into bf16: Wcat[i][384][256]
__global__ void concat_w_kernel(const float* __restrict__ off_w, const float* __restrict__ aw_w,
                                short* __restrict__ Wcat, int n)
{
    int idx = blockIdx.x * blockDim.x + threadIdx.x;
    if (idx >= n) return;                 // n = 6*384*256
    int col = idx & 255;
    int row = (idx >> 8) % 384;
    int i   = idx / (384*256);
    float v = (row < 256) ? off_w[((size_t)i*256 + row)*256 + col]
                          : aw_w[((size_t)i*128 + row-256)*256 + col];
    Wcat[idx] = bf16rne(v);
}
__global__ void concat_b_kernel(const float* __restrict__ off_b, const float* __restrict__ aw_b,
                                float* __restrict__ bcat, int n)
{
    int idx = blockIdx.x * blockDim.x + threadIdx.x;
    if (idx >= n) return;                 // n = 6*384
    int row = idx % 384;
    int i   = idx / 384;
    bcat[idx] = (row < 256) ? off_b[i*256 + row] : aw_b[i*128 + row-256];
}

// ---------------- stage-1 kernels ----------------

// fused (transposed, bf16 out): out[(b*hw+p)*c + ch] = sum_t f_t[b,ch,p]*softmax_t(tfw)
__global__ __launch_bounds__(256) void fuseT_kernel(const float* __restrict__ f0,
        const float* __restrict__ f1, const float* __restrict__ f2,
        const float* __restrict__ tfw, short* __restrict__ out,
        int c, int hw, int prior)
{
    __shared__ float tile[32][33];
    int p0 = blockIdx.x * 32;
    int c0 = blockIdx.y * 32;
    int b  = blockIdx.z;
    int tx  = threadIdx.x & 31;
    int ty8 = threadIdx.x >> 5;      // 0..7
    #pragma unroll
    for (int i = 0; i < 4; ++i) {
        int ch = c0 + ty8 + i*8;
        float t0 = tfw[0*kCHSUM + prior + ch];
        float t1 = tfw[1*kCHSUM + prior + ch];
        float t2 = tfw[2*kCHSUM + prior + ch];
        float m = fmaxf(t0, fmaxf(t1, t2));
        float e0 = expf(t0-m), e1 = expf(t1-m), e2 = expf(t2-m);
        float inv = 1.0f / (e0+e1+e2);
        size_t base = ((size_t)b*c + ch)*hw + p0 + tx;
        tile[ty8+i*8][tx] = f0[base]*(e0*inv) + f1[base]*(e1*inv) + f2[base]*(e2*inv);
    }
    __syncthreads();
    #pragma unroll
    for (int i = 0; i < 4; ++i) {
        int p = p0 + ty8 + i*8;
        out[((size_t)b*hw + p)*c + c0 + tx] = bf16rne(tile[tx][ty8+i*8]);
    }
}

// GroupNorm on xbufT [(b*hw+p)*256+ch]; writes src fp32, srcbf, qbf=bf16(src+pos)
__global__ __launch_bounds__(256) void gn_t_kernel(const float* __restrict__ xbufT,
                          const float* __restrict__ gg, const float* __restrict__ gb,
                          const float* __restrict__ pos,
                          float* __restrict__ src, short* __restrict__ srcbf,
                          short* __restrict__ qbf, int hw, int sbase)
{
    int b = blockIdx.x >> 5;
    int g = blockIdx.x & 31;
    int n = 8 * hw;
    const float* base = xbufT + (size_t)b*hw*256 + g*8;
    float s = 0.f, s2 = 0.f;
    for (int e = threadIdx.x; e < n; e += 256) {
        float v = base[(size_t)(e>>3)*256 + (e&7)];
        s += v; s2 += v*v;
    }
    __shared__ float rs[256], rq[256];
    rs[threadIdx.x] = s; rq[threadIdx.x] = s2; __syncthreads();
    for (int off = 128; off; off >>= 1) {
        if (threadIdx.x < off) { rs[threadIdx.x] += rs[threadIdx.x+off]; rq[threadIdx.x] += rq[threadIdx.x+off]; }
        __syncthreads();
    }
    float mu  = rs[0] / n;
    float var = rq[0] / n - mu*mu;
    float inv = rsqrtf(var + 1e-5f);
    for (int e = threadIdx.x; e < n; e += 256) {
        int p = e>>3, chl = e&7;
        int ch = g*8 + chl;
        float v = (base[(size_t)p*256 + chl] - mu) * inv * gg[ch] + gb[ch];
        size_t idx = ((size_t)b*kS + sbase + p)*kH + ch;
        src[idx] = v;
        srcbf[idx] = bf16rne(v);
        qbf[idx] = bf16rne(v + pos[idx]);
    }
}

// sine position embedding + level embed, broadcast over batch
__global__ void pos_kernel(const float* __restrict__ lev, float* __restrict__ pos,
                           int h, int w, int sbase, int lvl, int n)
{
    int idx = blockIdx.x * blockDim.x + threadIdx.x;
    if (idx >= n) return;                 // n = h*w*256
    int ch = idx % kH;
    int p  = idx / kH;
    int py = p / w, px = p % w;
    int c2 = ch & 127;
    int i  = c2 >> 1;
    float dt = powf(10000.0f, (float)i / 64.0f);
    float t;
    if (ch < 128) t = (py + 1) / ((float)h + 1e-6f) * 6.2831853071795864f;
    else          t = (px + 1) / ((float)w + 1e-6f) * 6.2831853071795864f;
    float arg = t / dt;
    float val = (c2 & 1) ? cosf(arg) : sinf(arg);
    val += lev[lvl*kH + ch];
    for (int b = 0; b < kB; ++b)
        pos[((size_t)b*kS + sbase + p)*kH + ch] = val;
}

// ---------------- MFMA bf16 GEMM (all-bf16 operands, reg-prefetch) ----------------
// C[m,n] = sum_k A[m,k]*W[n,k] + bias[n]; A,W bf16 row-major; OUTMODE 0=fp32 C, 1=bf16 Cb.
// 128x128 tile, BK=32, 256 threads (4 waves 2x2), 4x4 16x16x32 frags/wave.
// LDS stride 40 shorts (80B). M,K multiples of 128/32; N arbitrary (guarded).
template<int OUTMODE>
__global__ __launch_bounds__(256) void gemm_bf16(const short* __restrict__ A,
        const short* __restrict__ W, const float* __restrict__ bias,
        float* __restrict__ C, short* __restrict__ Cb,
        int M, int N, int K, int relu)
{
    __shared__ short Asm[128 * 40];
    __shared__ short Bsm[128 * 40];
    const int t    = threadIdx.x;
    const int bm   = blockIdx.x * 128;
    const int bn   = blockIdx.y * 128;
    const int lane = t & 63;
    const int wid  = t >> 6;
    const int wr   = wid >> 1;
    const int wc   = wid & 1;
    const int frow = lane & 15;
    const int g    = lane >> 4;
    const int sr = t >> 1;             // staging row 0..127
    const int sc = (t & 1) * 16;       // staging col 0 or 16

    f32x4 acc[4][4];
    #pragma unroll
    for (int i = 0; i < 4; ++i)
        #pragma unroll
        for (int j = 0; j < 4; ++j)
            acc[i][j] = (f32x4){0.f, 0.f, 0.f, 0.f};

    const bool wok = (bn + sr) < N;
    const short* Aptr = A + (size_t)(bm + sr)*K + sc;
    const short* Wptr = W + (size_t)(bn + sr)*K + sc;

    short8v a0, a1, w0 = {0,0,0,0,0,0,0,0}, w1 = {0,0,0,0,0,0,0,0};
    a0 = *(const short8v*)(Aptr);
    a1 = *(const short8v*)(Aptr + 8);
    if (wok) { w0 = *(const short8v*)(Wptr); w1 = *(const short8v*)(Wptr + 8); }

    for (int k0 = 0; k0 < K; k0 += 32) {
        __syncthreads();   // prev iteration's fragment reads done
        *(short8v*)&Asm[sr*40 + sc]     = a0;
        *(short8v*)&Asm[sr*40 + sc + 8] = a1;
        *(short8v*)&Bsm[sr*40 + sc]     = w0;
        *(short8v*)&Bsm[sr*40 + sc + 8] = w1;
        __syncthreads();
        if (k0 + 32 < K) {   // prefetch next tile while MFMAs run
            a0 = *(const short8v*)(Aptr + k0 + 32);
            a1 = *(const short8v*)(Aptr + k0 + 40);
            if (wok) {
                w0 = *(const short8v*)(Wptr + k0 + 32);
                w1 = *(const short8v*)(Wptr + k0 + 40);
            }
        }
        short8v af[4], bfv[4];
        #pragma unroll
        for (int i = 0; i < 4; ++i)
            af[i] = *(const short8v*)&Asm[(wr*64 + i*16 + frow)*40 + g*8];
        #pragma unroll
        for (int j = 0; j < 4; ++j)
            bfv[j] = *(const short8v*)&Bsm[(wc*64 + j*16 + frow)*40 + g*8];
        #pragma unroll
        for (int i = 0; i < 4; ++i)
            #pragma unroll
            for (int j = 0; j < 4; ++j)
                acc[i][j] = __builtin_amdgcn_mfma_f32_16x16x32_bf16(af[i], bfv[j], acc[i][j], 0, 0, 0);
    }

    // epilogue: D row = (lane>>4)*4 + reg, col = lane&15  (m89-verified)
    #pragma unroll
    for (int j = 0; j < 4; ++j) {
        int col = bn + wc*64 + j*16 + frow;
        if (col >= N) continue;
        float bz = bias[col];
        #pragma unroll
        for (int i = 0; i < 4; ++i) {
            int row = bm + wr*64 + i*16 + g*4;
            #pragma unroll
            for (int rr = 0; rr < 4; ++rr) {
                float v = acc[i][j][rr] + bz;
                if (relu) v = fmaxf(v, 0.f);
                if constexpr (OUTMODE == 0) C[(size_t)(row + rr)*N + col] = v;
                else                        Cb[(size_t)(row + rr)*N + col] = bf16rne(v);
            }
        }
    }
}

// softmax over 16 per (b,s,head), in place on cat cols 256..383 (row stride 384)
__global__ void softmax16_kernel(float* __restrict__ cat, int n)
{
    int idx = blockIdx.x * blockDim.x + threadIdx.x;
    if (idx >= n) return;
    float* p = cat + (size_t)(idx >> 3)*384 + 256 + (idx & 7)*16;
    f32x4 v0 = ((f32x4*)p)[0], v1 = ((f32x4*)p)[1], v2 = ((f32x4*)p)[2], v3 = ((f32x4*)p)[3];
    float m = v0[0];
    #pragma unroll
    for (int k = 1; k < 4; ++k) m = fmaxf(m, v0[k]);
    #pragma unroll
    for (int k = 0; k < 4; ++k) { m = fmaxf(m, v1[k]); m = fmaxf(m, v2[k]); m = fmaxf(m, v3[k]); }
    float s = 0.f;
    #pragma unroll
    for (int k = 0; k < 4; ++k) { v0[k] = expf(v0[k]-m); s += v0[k]; }
    #pragma unroll
    for (int k = 0; k < 4; ++k) { v1[k] = expf(v1[k]-m); s += v1[k]; }
    #pragma unroll
    for (int k = 0; k < 4; ++k) { v2[k] = expf(v2[k]-m); s += v2[k]; }
    #pragma unroll
    for (int k = 0; k < 4; ++k) { v3[k] = expf(v3[k]-m); s += v3[k]; }
    float inv = 1.0f / s;
    ((f32x4*)p)[0] = v0*inv; ((f32x4*)p)[1] = v1*inv;
    ((f32x4*)p)[2] = v2*inv; ((f32x4*)p)[3] = v3*inv;
}

// ms_deform: bf16 val gathers, bf16 msd out. thread = (s_local, head, d4)
__global__ __launch_bounds__(256) void msdeform4_kernel(const short* __restrict__ val,
        const float* __restrict__ cat, short* __restrict__ msd)
{
    int tid  = threadIdx.x;
    int d4   = tid & 7;
    int head = (tid >> 3) & 7;
    int bs   = blockIdx.x*4 + (tid >> 6);
    int s  = bs % kS;
    int b  = bs / kS;
    float refx, refy;
    if (s < 4096)      { int loc = s;        refy = ((loc>>6)+0.5f)/64.f; refx = ((loc&63)+0.5f)/64.f; }
    else if (s < 5120) { int loc = s - 4096; refy = ((loc>>5)+0.5f)/32.f; refx = ((loc&31)+0.5f)/32.f; }
    else if (s < 5376) { int loc = s - 5120; refy = ((loc>>4)+0.5f)/16.f; refx = ((loc&15)+0.5f)/16.f; }
    else               { int loc = s - 5376; refy = ((loc>>3)+0.5f)/8.f;  refx = ((loc&7)+0.5f)/8.f; }
    const float* op = cat + (size_t)bs*384 + head*32;
    const float* ap = cat + (size_t)bs*384 + 256 + head*16;
    const short* vb = val + (size_t)b*kS*256 + head*32 + d4*4;
    const int WL[4] = {64,32,16,8};
    const int BASE[4] = {0,4096,5120,5376};
    f32x4 acc = {0.f,0.f,0.f,0.f};
    #pragma unroll
    for (int l = 0; l < 4; ++l) {
        int wl = WL[l], hl = WL[l], base = BASE[l];
        #pragma unroll
        for (int p = 0; p < 4; ++p) {
            float ox = op[l*8 + p*2 + 0];
            float oy = op[l*8 + p*2 + 1];
            float gx = (refx + ox/wl)*wl - 0.5f;
            float gy = (refy + oy/hl)*hl - 0.5f;
            float x0f = floorf(gx), y0f = floorf(gy);
            float wx1 = gx - x0f, wy1 = gy - y0f;
            int x0 = (int)x0f, y0 = (int)y0f;
            float a = ap[l*4 + p];
            #pragma unroll
            for (int dy = 0; dy < 2; ++dy) {
                int yi = y0 + dy;
                if (yi < 0 || yi >= hl) continue;
                float wy = dy ? wy1 : 1.f - wy1;
                #pragma unroll
                for (int dx = 0; dx < 2; ++dx) {
                    int xi = x0 + dx;
                    if (xi < 0 || xi >= wl) continue;
                    float wx = dx ? wx1 : 1.f - wx1;
                    short4v v = *(const short4v*)&vb[(size_t)(base + yi*wl + xi)*256];
                    float wgt = wx*wy*a;
                    acc[0] += bf2f(v[0])*wgt; acc[1] += bf2f(v[1])*wgt;
                    acc[2] += bf2f(v[2])*wgt; acc[3] += bf2f(v[3])*wgt;
                }
            }
        }
    }
    short4v o;
    o[0]=bf16rne(acc[0]); o[1]=bf16rne(acc[1]); o[2]=bf16rne(acc[2]); o[3]=bf16rne(acc[3]);
    *(short4v*)&msd[(size_t)bs*256 + head*32 + d4*4] = o;
}

// src = LayerNorm(src + delta); writes src fp32, srcbf, optionally qbf=bf16(src+pos)
template<int WQ>
__global__ __launch_bounds__(256) void add_ln_kernel(float* __restrict__ src,
        const float* __restrict__ delta, const float* __restrict__ g,
        const float* __restrict__ bta, short* __restrict__ srcbf,
        short* __restrict__ qbf, const float* __restrict__ pos)
{
    int lane = threadIdx.x & 63;
    int row  = blockIdx.x*4 + (threadIdx.x >> 6);
    f32x4* s4 = (f32x4*)(src + (size_t)row*256);
    const f32x4* d4 = (const f32x4*)(delta + (size_t)row*256);
    f32x4 x = s4[lane];
    f32x4 dd = d4[lane];
    x[0]+=dd[0]; x[1]+=dd[1]; x[2]+=dd[2]; x[3]+=dd[3];
    float s = x[0]+x[1]+x[2]+x[3];
    #pragma unroll
    for (int o = 1; o < 64; o <<= 1) s += __shfl_xor(s, o);
    float mu = s * (1.f/256.f);
    f32x4 xc;
    xc[0]=x[0]-mu; xc[1]=x[1]-mu; xc[2]=x[2]-mu; xc[3]=x[3]-mu;
    float s2 = xc[0]*xc[0]+xc[1]*xc[1]+xc[2]*xc[2]+xc[3]*xc[3];
    #pragma unroll
    for (int o = 1; o < 64; o <<= 1) s2 += __shfl_xor(s2, o);
    float inv = rsqrtf(s2*(1.f/256.f) + 1e-5f);
    const f32x4 gv = ((const f32x4*)g)[lane];
    const f32x4 bv = ((const f32x4*)bta)[lane];
    f32x4 o4;
    o4[0]=xc[0]*inv*gv[0]+bv[0]; o4[1]=xc[1]*inv*gv[1]+bv[1];
    o4[2]=xc[2]*inv*gv[2]+bv[2]; o4[3]=xc[3]*inv*gv[3]+bv[3];
    s4[lane] = o4;
    short4v sb;
    sb[0]=bf16rne(o4[0]); sb[1]=bf16rne(o4[1]); sb[2]=bf16rne(o4[2]); sb[3]=bf16rne(o4[3]);
    *(short4v*)&srcbf[(size_t)row*256 + lane*4] = sb;
    if constexpr (WQ) {
        f32x4 pv = ((const f32x4*)(pos + (size_t)row*256))[lane];
        short4v qb;
        qb[0]=bf16rne(o4[0]+pv[0]); qb[1]=bf16rne(o4[1]+pv[1]);
        qb[2]=bf16rne(o4[2]+pv[2]); qb[3]=bf16rne(o4[3]+pv[3]);
        *(short4v*)&qbf[(size_t)row*256 + lane*4] = qb;
    }
}

// im2col for conv1 in bf16: A[m][k], m = b*4096 + y*64 + x, k = c*9 + dy*3 + dx
__global__ void im2col_bf16_kernel(const float* __restrict__ src, short* __restrict__ A, int n)
{
    int idx = blockIdx.x * blockDim.x + threadIdx.x;
    if (idx >= n) return;
    int k = idx % 2304;
    int m = idx / 2304;
    int c  = k / 9;
    int r9 = k - c*9;
    int dy = r9 / 3;
    int dx = r9 - dy*3;
    int x = m & 63, y = (m >> 6) & 63, b = m >> 12;
    int yy = y + dy - 1, xx = x + dx - 1;
    float v = 0.f;
    if (yy >= 0 && yy < 64 && xx >= 0 && xx < 64)
        v = src[((size_t)b*kS + yy*64 + xx)*256 + c];
    A[idx] = bf16rne(v);
}

// conv2: 3x3, 64->2; input c1 is NHWC (b, 64x64, 64); output NCHW
__global__ void conv2_kernel(const float* __restrict__ c1, const float* __restrict__ w,
                             const float* __restrict__ bias, float* __restrict__ pred)
{
    int idx = blockIdx.x * blockDim.x + threadIdx.x;   // B*2*64*64
    int x = idx & 63;
    int y = (idx >> 6) & 63;
    int o = (idx >> 12) & 1;
    int b = idx >> 13;
    float acc = bias[o];
    for (int dy = 0; dy < 3; ++dy) {
        int yy = y + dy - 1;
        if (yy < 0 || yy >= 64) continue;
        for (int dx = 0; dx < 3; ++dx) {
            int xx = x + dx - 1;
            if (xx < 0 || xx >= 64) continue;
            const float* sp = c1 + ((size_t)(b*4096) + yy*64 + xx)*64;
            const float* wp = w + o*576 + dy*3 + dx;
            for (int c = 0; c < 64; ++c) acc += sp[c] * wp[c*9];
        }
    }
    pred[idx] = acc;
}

// bilinear resize 64x64 -> 256x256 (half-pixel, edge clamp)
__global__ void resize_kernel(const float* __restrict__ pred, float* __restrict__ out)
{
    int idx = blockIdx.x * blockDim.x + threadIdx.x;   // B*2*256*256
    int X = idx & 255;
    int Y = (idx >> 8) & 255;
    int c = (idx >> 16) & 1;
    int b = idx >> 17;
    float sx = (X + 0.5f)*0.25f - 0.5f;
    float sy = (Y + 0.5f)*0.25f - 0.5f;
    int x0 = (int)floorf(sx); float fx = sx - x0;
    int y0 = (int)floorf(sy); float fy = sy - y0;
    int x0c = min(max(x0, 0), 63), x1c = min(max(x0+1, 0), 63);
    int y0c = min(max(y0, 0), 63), y1c = min(max(y0+1, 0), 63);
    const float* p = pred + ((size_t)(b*2 + c))*4096;
    float v00 = p[y0c*64 + x0c], v01 = p[y0c*64 + x1c];
    float v10 = p[y1c*64 + x0c], v11 = p[y1c*64 + x1c];
    out[idx] = (1.f-fy)*((1.f-fx)*v00 + fx*v01) + fy*((1.f-fx)*v10 + fx*v11);
}

// ---------------- launch ----------------
extern "C" void kernel_launch(void* const* d_in, const int* in_sizes, int n_in,
                              void* d_out, int out_size, void* d_ws, size_t ws_size,
                              hipStream_t stream)
{
    const float* F[3][4];
    for (int t = 0; t < 3; ++t)
        for (int l = 0; l < 4; ++l)
            F[t][l] = (const float*)d_in[t*4 + l];
    const float* tfw = (const float*)d_in[12];
    const float *pw[4], *pb[4], *gg[4], *gb[4];
    for (int l = 0; l < 4; ++l) {
        pw[l] = (const float*)d_in[13 + 4*l];
        pb[l] = (const float*)d_in[14 + 4*l];
        gg[l] = (const float*)d_in[15 + 4*l];
        gb[l] = (const float*)d_in[16 + 4*l];
    }
    const float* lev   = (const float*)d_in[29];
    const float* off_w = (const float*)d_in[30];
    const float* off_b = (const float*)d_in[31];
    const float* aw_w  = (const float*)d_in[32];
    const float* aw_b  = (const float*)d_in[33];
    const float* val_w = (const float*)d_in[34];
    const float* val_b = (const float*)d_in[35];
    const float* out_w = (const float*)d_in[36];
    const float* out_b = (const float*)d_in[37];
    const float* ln1g  = (const float*)d_in[38];
    const float* ln1b  = (const float*)d_in[39];
    const float* ff1w  = (const float*)d_in[40];
    const float* ff1b  = (const float*)d_in[41];
    const float* ff2w  = (const float*)d_in[42];
    const float* ff2b  = (const float*)d_in[43];
    const float* ln2g  = (const float*)d_in[44];
    const float* ln2b  = (const float*)d_in[45];
    const float* c1w   = (const float*)d_in[46];
    const float* c1b   = (const float*)d_in[47];
    const float* c2w   = (const float*)d_in[48];
    const float* c2b   = (const float*)d_in[49];

    const size_t N256 = (size_t)kB * kS * 256;        // 5,570,560
    float* ws    = (float*)d_ws;
    float* src   = ws;                                // 5.57M f
    short* srcbf = (short*)(src + N256);              // N256 shorts (2.79M f)
    short* qbf   = srcbf + N256;
    short* valbf = qbf + N256;
    short* msdbf = valbf + N256;
    short* warena= msdbf + N256;                      // bf16 weights, 5.03M shorts
    // weight arena offsets (shorts)
    short* Wcat_bf = warena;                              // 6*384*256 = 589824
    short* valw_bf = Wcat_bf + 589824;                    // 393216
    short* outw_bf = valw_bf + 393216;                    // 393216
    short* ff1w_bf = outw_bf + 393216;                    // 1572864
    short* ff2w_bf = ff1w_bf + 1572864;                   // 1572864
    short* pw_bf   = ff2w_bf + 1572864;                   // 360448
    short* c1w_bf  = pw_bf + 360448;                      // 147456
    float* bcat  = (float*)(c1w_bf + 147456 + 128);   // 2304 f (aligned)
    float* pos   = bcat + 4096;                       // 5.57M f
    float* cat   = pos + N256;                        // kM*384 = 8.36M f
    float* tmp   = cat + (size_t)kM*384;              // 5.57M f
    short* ffhbf = (short*)(tmp + N256);              // kM*1024 shorts = 11.14M f
    // stage-1 aliases (cat/tmp dead in stage 1)
    short* fusedT = (short*)cat;                      // ≤ 2.1M shorts
    float* xbufT  = tmp;                              // ≤ 4.19M f
    // head aliases (pos/cat/tmp/ffhbf dead after encoder)
    short* Acol  = (short*)pos;                       // 16384*2304 = 37.7M shorts (fits in 30.6M f region)
    float* c1o   = (float*)valbf;                     // 1.05M f (valbf+msdbf region = 2.79M f)
    float* pred  = (float*)msdbf;                     // 32K f

    const int LVL_HWS[4]  = {4096, 1024, 256, 64};
    const int LVL_BASE[4] = {0, 4096, 5120, 5376};
    const int LVL_C[4]    = {128, 256, 512, 512};
    const int LVL_PRIOR[4]= {0, 128, 256, 512};       // reference's literal (non-cumulative) priors
    const int PW_OFF[4]   = {0, 32768, 98304, 229376};

    // ---- weight prep (bf16) ----
    {
        int n = 6*384*256;
        concat_w_kernel<<<(n+255)/256, 256, 0, stream>>>(off_w, aw_w, Wcat_bf, n);
        concat_b_kernel<<<(6*384+255)/256, 256, 0, stream>>>(off_b, aw_b, bcat, 6*384);
        f2bf_kernel<<<(393216/4+255)/256, 256, 0, stream>>>(val_w, valw_bf, 393216);
        f2bf_kernel<<<(393216/4+255)/256, 256, 0, stream>>>(out_w, outw_bf, 393216);
        f2bf_kernel<<<(1572864/4+255)/256, 256, 0, stream>>>(ff1w, ff1w_bf, 1572864);
        f2bf_kernel<<<(1572864/4+255)/256, 256, 0, stream>>>(ff2w, ff2w_bf, 1572864);
        for (int l = 0; l < 4; ++l) {
            int n2 = 256 * LVL_C[l];
            f2bf_kernel<<<(n2/4+255)/256, 256, 0, stream>>>(pw[l], pw_bf + PW_OFF[l], n2);
        }
        f2bf_kernel<<<(147456/4+255)/256, 256, 0, stream>>>(c1w, c1w_bf, 147456);
    }

    // ---- stage 1: pos first (gn_t needs it), then fuse+proj+GN per level ----
    for (int l = 0; l < 4; ++l) {
        int hw = LVL_HWS[l];
        int dim = (l==0)?64:(l==1)?32:(l==2)?16:8;
        int n3 = hw * kH;
        pos_kernel<<<(n3+255)/256, 256, 0, stream>>>(lev, pos, dim, dim, LVL_BASE[l], l, n3);
    }
    for (int l = 0; l < 4; ++l) {
        int hw = LVL_HWS[l], c = LVL_C[l];
        dim3 gf(hw/32, c/32, kB);
        fuseT_kernel<<<gf, 256, 0, stream>>>(F[0][l], F[1][l], F[2][l], tfw,
                                             fusedT, c, hw, LVL_PRIOR[l]);
        dim3 gp((kB*hw)/128, 2);
        gemm_bf16<0><<<gp, 256, 0, stream>>>(fusedT, pw_bf + PW_OFF[l], pb[l],
                                             xbufT, nullptr, kB*hw, 256, c, 0);
        gn_t_kernel<<<kB*32, 256, 0, stream>>>(xbufT, gg[l], gb[l], pos,
                                               src, srcbf, qbf, hw, LVL_BASE[l]);
    }

    // ---- stage 2: 6 encoder layers ----
    for (int i = 0; i < 6; ++i) {
        dim3 gcat(kM/128, 3);   // N=384 (off|aw)
        gemm_bf16<0><<<gcat, 256, 0, stream>>>(qbf, Wcat_bf + (size_t)i*384*256,
                                               bcat + i*384, cat, nullptr, kM, 384, 256, 0);
        int nsm = kM * kNH;
        softmax16_kernel<<<(nsm+255)/256, 256, 0, stream>>>(cat, nsm);

        dim3 g1(kM/128, 2);     // N=256
        gemm_bf16<1><<<g1, 256, 0, stream>>>(srcbf, valw_bf + (size_t)i*65536,
                                             val_b + i*256, nullptr, valbf, kM, 256, 256, 0);
        msdeform4_kernel<<<kM/4, 256, 0, stream>>>(valbf, cat, msdbf);
        gemm_bf16<0><<<g1, 256, 0, stream>>>(msdbf, outw_bf + (size_t)i*65536,
                                             out_b + i*256, tmp, nullptr, kM, 256, 256, 0);
        add_ln_kernel<0><<<kM/4, 256, 0, stream>>>(src, tmp, ln1g + i*256, ln1b + i*256,
                                                   srcbf, nullptr, nullptr);

        dim3 g3(kM/128, 8);     // N=1024
        gemm_bf16<1><<<g3, 256, 0, stream>>>(srcbf, ff1w_bf + (size_t)i*262144,
                                             ff1b + i*1024, nullptr, ffhbf, kM, 1024, 256, 1);
        gemm_bf16<0><<<g1, 256, 0, stream>>>(ffhbf, ff2w_bf + (size_t)i*262144,
                                             ff2b + i*256, tmp, nullptr, kM, 256, 1024, 0);
        add_ln_kernel<1><<<kM/4, 256, 0, stream>>>(src, tmp, ln2g + i*256, ln2b + i*256,
                                                   srcbf, qbf, pos);
    }

    // ---- stage 3: head ----
    {
        int nim = 16384 * 2304;
        im2col_bf16_kernel<<<(nim+255)/256, 256, 0, stream>>>(src, Acol, nim);
        dim3 gc(16384/128, 1);
        gemm_bf16<0><<<gc, 256, 0, stream>>>(Acol, c1w_bf, c1b, c1o, nullptr, 16384, 64, 2304, 1);
        conv2_kernel<<<(kB*2*64*64)/256, 256, 0, stream>>>(c1o, c2w, c2b, pred);
        resize_kernel<<<(kB*2*256*256)/256, 256, 0, stream>>>(pred, (float*)d_out);
    }
}

// Round 5
// 1569.990 us; speedup vs baseline: 5.7670x; 1.0416x over previous
//
#include <hip/hip_runtime.h>
#include <math.h>

// ---------------- problem constants ----------------
constexpr int kB = 4;
constexpr int kS = 5440;           // 64*64 + 32*32 + 16*16 + 8*8
constexpr int kH = 256;            // HIDDEN
constexpr int kNH = 8, kNL = 4, kNP = 4, kDH = 32;
constexpr int kM = kB * kS;        // 21760 rows
constexpr int kCHSUM = 1408;       // sum(CHS)

typedef __attribute__((ext_vector_type(8))) short short8v;   // 8 bf16 (4 VGPRs)
typedef __attribute__((ext_vector_type(4))) short short4v;   // 4 bf16 (8 B)
typedef __attribute__((ext_vector_type(4))) float f32x4;

__device__ inline short bf16rne(float f) {
    unsigned u = __float_as_uint(f);
    u += 0x7FFF + ((u >> 16) & 1);
    return (short)(u >> 16);
}
__device__ inline float bf2f(short s) {
    return __uint_as_float(((unsigned)(unsigned short)s) << 16);
}

// ---------------- prep kernels ----------------

__global__ void f2bf_kernel(const float* __restrict__ in, short* __restrict__ out, int n)
{
    int idx = (blockIdx.x * blockDim.x + threadIdx.x) * 4;
    if (idx >= n) return;
    f32x4 v = *(const f32x4*)(in + idx);
    short4v o;
    o[0]=bf16rne(v[0]); o[1]=bf16rne(v[1]); o[2]=bf16rne(v[2]); o[3]=bf16rne(v[3]);
    *(short4v*)(out + idx) = o;
}

__global__ void concat_w_kernel(const float* __restrict__ off_w, const float* __restrict__ aw_w,
                                short* __restrict__ Wcat, int n)
{
    int idx = blockIdx.x * blockDim.x + threadIdx.x;
    if (idx >= n) return;                 // n = 6*384*256
    int col = idx & 255;
    int row = (idx >> 8) % 384;
    int i   = idx / (384*256);
    float v = (row < 256) ? off_w[((size_t)i*256 + row)*256 + col]
                          : aw_w[((size_t)i*128 + row-256)*256 + col];
    Wcat[idx] = bf16rne(v);
}
__global__ void concat_b_kernel(const float* __restrict__ off_b, const float* __restrict__ aw_b,
                                float* __restrict__ bcat, int n)
{
    int idx = blockIdx.x * blockDim.x + threadIdx.x;
    if (idx >= n) return;                 // n = 6*384
    int row = idx % 384;
    int i   = idx / 384;
    bcat[idx] = (row < 256) ? off_b[i*256 + row] : aw_b[i*128 + row-256];
}

// ---------------- stage-1 kernels ----------------

// fused (transposed, bf16 out)
__global__ __launch_bounds__(256) void fuseT_kernel(const float* __restrict__ f0,
        const float* __restrict__ f1, const float* __restrict__ f2,
        const float* __restrict__ tfw, short* __restrict__ out,
        int c, int hw, int prior)
{
    __shared__ float tile[32][33];
    int p0 = blockIdx.x * 32;
    int c0 = blockIdx.y * 32;
    int b  = blockIdx.z;
    int tx  = threadIdx.x & 31;
    int ty8 = threadIdx.x >> 5;
    #pragma unroll
    for (int i = 0; i < 4; ++i) {
        int ch = c0 + ty8 + i*8;
        float t0 = tfw[0*kCHSUM + prior + ch];
        float t1 = tfw[1*kCHSUM + prior + ch];
        float t2 = tfw[2*kCHSUM + prior + ch];
        float m = fmaxf(t0, fmaxf(t1, t2));
        float e0 = expf(t0-m), e1 = expf(t1-m), e2 = expf(t2-m);
        float inv = 1.0f / (e0+e1+e2);
        size_t base = ((size_t)b*c + ch)*hw + p0 + tx;
        tile[ty8+i*8][tx] = f0[base]*(e0*inv) + f1[base]*(e1*inv) + f2[base]*(e2*inv);
    }
    __syncthreads();
    #pragma unroll
    for (int i = 0; i < 4; ++i) {
        int p = p0 + ty8 + i*8;
        out[((size_t)b*hw + p)*c + c0 + tx] = bf16rne(tile[tx][ty8+i*8]);
    }
}

// GN pass 1: per (b, chunk of 16 rows) partial per-group sums. Fully coalesced.
__global__ __launch_bounds__(256) void gn_sum_kernel(const float* __restrict__ xbufT,
        float* __restrict__ gnstat, int nchunks)
{
    int chunk = blockIdx.x, b = blockIdx.y;
    int t = threadIdx.x;
    size_t base = ((size_t)b*nchunks + chunk) * 4096;   // 16 rows * 256
    float s = 0.f, q = 0.f;
    #pragma unroll
    for (int i = 0; i < 4; ++i) {
        f32x4 v = *(const f32x4*)(xbufT + base + i*1024 + t*4);
        s += v[0]+v[1]+v[2]+v[3];
        q += v[0]*v[0]+v[1]*v[1]+v[2]*v[2]+v[3]*v[3];
    }
    __shared__ float ls[256], lq[256];
    ls[t] = s; lq[t] = q; __syncthreads();
    if (t < 64) { ls[t] += ls[t+64]+ls[t+128]+ls[t+192];
                  lq[t] += lq[t+64]+lq[t+128]+lq[t+192]; }
    __syncthreads();
    if (t < 32) {
        float ss = ls[2*t] + ls[2*t+1];
        float qq = lq[2*t] + lq[2*t+1];
        size_t o = (((size_t)b*nchunks + chunk)*32 + t)*2;
        gnstat[o] = ss; gnstat[o+1] = qq;
    }
}

// GN pass 2: reduce chunks -> per-channel scale/shift
__global__ __launch_bounds__(256) void gn_fin_kernel(const float* __restrict__ gnstat,
        const float* __restrict__ gg, const float* __restrict__ gb,
        float* __restrict__ gnA, float* __restrict__ gnB, int nchunks, int hw)
{
    int b = blockIdx.x, t = threadIdx.x;
    int g = t >> 3, sub = t & 7;
    float s = 0.f, q = 0.f;
    for (int c = sub; c < nchunks; c += 8) {
        size_t o = (((size_t)b*nchunks + c)*32 + g)*2;
        s += gnstat[o]; q += gnstat[o+1];
    }
    __shared__ float ls[256], lq[256], gmu[32], ginv[32];
    ls[t] = s; lq[t] = q; __syncthreads();
    if (sub < 4) { ls[t] += ls[t+4]; lq[t] += lq[t+4]; } __syncthreads();
    if (sub < 2) { ls[t] += ls[t+2]; lq[t] += lq[t+2]; } __syncthreads();
    if (sub == 0) {
        float ss = ls[t] + ls[t+1], qq = lq[t] + lq[t+1];
        float n = 8.0f * hw;
        float mu = ss / n;
        float var = qq / n - mu*mu;
        gmu[g] = mu; ginv[g] = rsqrtf(var + 1e-5f);
    }
    __syncthreads();
    int ch = t;
    float A = ginv[ch>>3] * gg[ch];
    float B = gb[ch] - gmu[ch>>3] * A;
    gnA[b*256 + ch] = A;
    gnB[b*256 + ch] = B;
}

// GN pass 3: apply, fully coalesced; writes src fp32, srcbf, qbf=bf16(src+pos)
__global__ __launch_bounds__(256) void gn_apply_kernel(const float* __restrict__ xbufT,
        const float* __restrict__ gnA, const float* __restrict__ gnB,
        const float* __restrict__ pos, float* __restrict__ src,
        short* __restrict__ srcbf, short* __restrict__ qbf, int hw, int sbase)
{
    int E = hw * 256;
    size_t fl = (size_t)blockIdx.x*1024 + threadIdx.x*4;
    int b = (int)(fl / E);
    int off = (int)(fl - (size_t)b*E);
    int p = off >> 8, col = off & 255;
    f32x4 v = *(const f32x4*)(xbufT + fl);
    f32x4 A = *(const f32x4*)(gnA + b*256 + col);
    f32x4 Bv = *(const f32x4*)(gnB + b*256 + col);
    size_t si = ((size_t)b*kS + sbase + p)*256 + col;
    f32x4 pv = *(const f32x4*)(pos + si);
    f32x4 o;
    o[0]=v[0]*A[0]+Bv[0]; o[1]=v[1]*A[1]+Bv[1];
    o[2]=v[2]*A[2]+Bv[2]; o[3]=v[3]*A[3]+Bv[3];
    *(f32x4*)(src + si) = o;
    short4v sb, qb;
    sb[0]=bf16rne(o[0]); sb[1]=bf16rne(o[1]); sb[2]=bf16rne(o[2]); sb[3]=bf16rne(o[3]);
    qb[0]=bf16rne(o[0]+pv[0]); qb[1]=bf16rne(o[1]+pv[1]);
    qb[2]=bf16rne(o[2]+pv[2]); qb[3]=bf16rne(o[3]+pv[3]);
    *(short4v*)(srcbf + si) = sb;
    *(short4v*)(qbf + si) = qb;
}

// sine position embedding + level embed, broadcast over batch
__global__ void pos_kernel(const float* __restrict__ lev, float* __restrict__ pos,
                           int h, int w, int sbase, int lvl, int n)
{
    int idx = blockIdx.x * blockDim.x + threadIdx.x;
    if (idx >= n) return;                 // n = h*w*256
    int ch = idx % kH;
    int p  = idx / kH;
    int py = p / w, px = p % w;
    int c2 = ch & 127;
    int i  = c2 >> 1;
    float dt = powf(10000.0f, (float)i / 64.0f);
    float t;
    if (ch < 128) t = (py + 1) / ((float)h + 1e-6f) * 6.2831853071795864f;
    else          t = (px + 1) / ((float)w + 1e-6f) * 6.2831853071795864f;
    float arg = t / dt;
    float val = (c2 & 1) ? cosf(arg) : sinf(arg);
    val += lev[lvl*kH + ch];
    for (int b = 0; b < kB; ++b)
        pos[((size_t)b*kS + sbase + p)*kH + ch] = val;
}

// ---------------- 64x64 MFMA bf16 GEMM ----------------
// grid (N/64, M/64); 256 threads = 4 waves 2x2; per-wave 32x32 (2x2 16x16x32 frags).
// LDS stride 40 shorts. OUTMODE 0=fp32 C, 1=bf16 Cb. M,N mult of 64, K mult of 32.
template<int OUTMODE>
__global__ __launch_bounds__(256) void gemm64(const short* __restrict__ A,
        const short* __restrict__ W, const float* __restrict__ bias,
        float* __restrict__ C, short* __restrict__ Cb, int N, int K, int relu)
{
    __shared__ short Asm[64 * 40];
    __shared__ short Bsm[64 * 40];
    const int t    = threadIdx.x;
    const int bn   = blockIdx.x * 64;
    const int bm   = blockIdx.y * 64;
    const int lane = t & 63;
    const int wid  = t >> 6;
    const int wr   = wid >> 1;
    const int wc   = wid & 1;
    const int frow = lane & 15;
    const int g    = lane >> 4;
    const int sr   = t >> 2;           // 0..63
    const int sc   = (t & 3) * 8;      // 0,8,16,24

    f32x4 acc[2][2];
    #pragma unroll
    for (int i = 0; i < 2; ++i)
        #pragma unroll
        for (int j = 0; j < 2; ++j)
            acc[i][j] = (f32x4){0.f,0.f,0.f,0.f};

    const short* Aptr = A + (size_t)(bm + sr)*K + sc;
    const short* Wptr = W + (size_t)(bn + sr)*K + sc;
    short8v a0 = *(const short8v*)Aptr;
    short8v w0 = *(const short8v*)Wptr;

    for (int k0 = 0; k0 < K; k0 += 32) {
        __syncthreads();
        *(short8v*)&Asm[sr*40 + sc] = a0;
        *(short8v*)&Bsm[sr*40 + sc] = w0;
        __syncthreads();
        if (k0 + 32 < K) {
            a0 = *(const short8v*)(Aptr + k0 + 32);
            w0 = *(const short8v*)(Wptr + k0 + 32);
        }
        short8v af[2], bfv[2];
        #pragma unroll
        for (int i = 0; i < 2; ++i)
            af[i] = *(const short8v*)&Asm[(wr*32 + i*16 + frow)*40 + g*8];
        #pragma unroll
        for (int j = 0; j < 2; ++j)
            bfv[j] = *(const short8v*)&Bsm[(wc*32 + j*16 + frow)*40 + g*8];
        #pragma unroll
        for (int i = 0; i < 2; ++i)
            #pragma unroll
            for (int j = 0; j < 2; ++j)
                acc[i][j] = __builtin_amdgcn_mfma_f32_16x16x32_bf16(af[i], bfv[j], acc[i][j], 0, 0, 0);
    }

    #pragma unroll
    for (int j = 0; j < 2; ++j) {
        int col = bn + wc*32 + j*16 + frow;
        float bz = bias[col];
        #pragma unroll
        for (int i = 0; i < 2; ++i) {
            int row = bm + wr*32 + i*16 + g*4;
            #pragma unroll
            for (int rr = 0; rr < 4; ++rr) {
                float v = acc[i][j][rr] + bz;
                if (relu) v = fmaxf(v, 0.f);
                if constexpr (OUTMODE == 0) C[(size_t)(row + rr)*N + col] = v;
                else                        Cb[(size_t)(row + rr)*N + col] = bf16rne(v);
            }
        }
    }
}

// merged (off|aw | val) GEMM: N=640; bn<384: A=qbf,W=Wcat -> cat fp32 (ld 384);
// bn>=384: A=srcbf,W=valw -> valbf bf16 (ld 256). K=256.
__global__ __launch_bounds__(256) void gemm_qv(const short* __restrict__ Aq,
        const short* __restrict__ As, const short* __restrict__ W1,
        const short* __restrict__ W2, const float* __restrict__ b1,
        const float* __restrict__ b2, float* __restrict__ C1,
        short* __restrict__ Cb2)
{
    __shared__ short Asm[64 * 40];
    __shared__ short Bsm[64 * 40];
    const int t    = threadIdx.x;
    const int bn   = blockIdx.x * 64;
    const int bm   = blockIdx.y * 64;
    const bool qreg = bn < 384;
    const int K = 256;
    const int lane = t & 63;
    const int wid  = t >> 6;
    const int wr   = wid >> 1;
    const int wc   = wid & 1;
    const int frow = lane & 15;
    const int g    = lane >> 4;
    const int sr   = t >> 2;
    const int sc   = (t & 3) * 8;

    f32x4 acc[2][2];
    #pragma unroll
    for (int i = 0; i < 2; ++i)
        #pragma unroll
        for (int j = 0; j < 2; ++j)
            acc[i][j] = (f32x4){0.f,0.f,0.f,0.f};

    const short* Aptr = (qreg ? Aq : As) + (size_t)(bm + sr)*K + sc;
    const short* Wptr = (qreg ? (W1 + (size_t)(bn + sr)*K)
                              : (W2 + (size_t)(bn - 384 + sr)*K)) + sc;
    short8v a0 = *(const short8v*)Aptr;
    short8v w0 = *(const short8v*)Wptr;

    for (int k0 = 0; k0 < K; k0 += 32) {
        __syncthreads();
        *(short8v*)&Asm[sr*40 + sc] = a0;
        *(short8v*)&Bsm[sr*40 + sc] = w0;
        __syncthreads();
        if (k0 + 32 < K) {
            a0 = *(const short8v*)(Aptr + k0 + 32);
            w0 = *(const short8v*)(Wptr + k0 + 32);
        }
        short8v af[2], bfv[2];
        #pragma unroll
        for (int i = 0; i < 2; ++i)
            af[i] = *(const short8v*)&Asm[(wr*32 + i*16 + frow)*40 + g*8];
        #pragma unroll
        for (int j = 0; j < 2; ++j)
            bfv[j] = *(const short8v*)&Bsm[(wc*32 + j*16 + frow)*40 + g*8];
        #pragma unroll
        for (int i = 0; i < 2; ++i)
            #pragma unroll
            for (int j = 0; j < 2; ++j)
                acc[i][j] = __builtin_amdgcn_mfma_f32_16x16x32_bf16(af[i], bfv[j], acc[i][j], 0, 0, 0);
    }

    #pragma unroll
    for (int j = 0; j < 2; ++j) {
        int col = bn + wc*32 + j*16 + frow;
        float bz = qreg ? b1[col] : b2[col - 384];
        #pragma unroll
        for (int i = 0; i < 2; ++i) {
            int row = bm + wr*32 + i*16 + g*4;
            #pragma unroll
            for (int rr = 0; rr < 4; ++rr) {
                float v = acc[i][j][rr] + bz;
                if (qreg) C1[(size_t)(row + rr)*384 + col] = v;
                else      Cb2[(size_t)(row + rr)*256 + col - 384] = bf16rne(v);
            }
        }
    }
}

// softmax over 16 per (b,s,head), in place on cat cols 256..383 (row stride 384)
__global__ void softmax16_kernel(float* __restrict__ cat, int n)
{
    int idx = blockIdx.x * blockDim.x + threadIdx.x;
    if (idx >= n) return;
    float* p = cat + (size_t)(idx >> 3)*384 + 256 + (idx & 7)*16;
    f32x4 v0 = ((f32x4*)p)[0], v1 = ((f32x4*)p)[1], v2 = ((f32x4*)p)[2], v3 = ((f32x4*)p)[3];
    float m = v0[0];
    #pragma unroll
    for (int k = 1; k < 4; ++k) m = fmaxf(m, v0[k]);
    #pragma unroll
    for (int k = 0; k < 4; ++k) { m = fmaxf(m, v1[k]); m = fmaxf(m, v2[k]); m = fmaxf(m, v3[k]); }
    float s = 0.f;
    #pragma unroll
    for (int k = 0; k < 4; ++k) { v0[k] = expf(v0[k]-m); s += v0[k]; }
    #pragma unroll
    for (int k = 0; k < 4; ++k) { v1[k] = expf(v1[k]-m); s += v1[k]; }
    #pragma unroll
    for (int k = 0; k < 4; ++k) { v2[k] = expf(v2[k]-m); s += v2[k]; }
    #pragma unroll
    for (int k = 0; k < 4; ++k) { v3[k] = expf(v3[k]-m); s += v3[k]; }
    float inv = 1.0f / s;
    ((f32x4*)p)[0] = v0*inv; ((f32x4*)p)[1] = v1*inv;
    ((f32x4*)p)[2] = v2*inv; ((f32x4*)p)[3] = v3*inv;
}

// ms_deform: bf16 val gathers, bf16 msd out. thread = (s_local, head, d4)
__global__ __launch_bounds__(256) void msdeform4_kernel(const short* __restrict__ val,
        const float* __restrict__ cat, short* __restrict__ msd)
{
    int tid  = threadIdx.x;
    int d4   = tid & 7;
    int head = (tid >> 3) & 7;
    int bs   = blockIdx.x*4 + (tid >> 6);
    int s  = bs % kS;
    int b  = bs / kS;
    float refx, refy;
    if (s < 4096)      { int loc = s;        refy = ((loc>>6)+0.5f)/64.f; refx = ((loc&63)+0.5f)/64.f; }
    else if (s < 5120) { int loc = s - 4096; refy = ((loc>>5)+0.5f)/32.f; refx = ((loc&31)+0.5f)/32.f; }
    else if (s < 5376) { int loc = s - 5120; refy = ((loc>>4)+0.5f)/16.f; refx = ((loc&15)+0.5f)/16.f; }
    else               { int loc = s - 5376; refy = ((loc>>3)+0.5f)/8.f;  refx = ((loc&7)+0.5f)/8.f; }
    const float* op = cat + (size_t)bs*384 + head*32;
    const float* ap = cat + (size_t)bs*384 + 256 + head*16;
    const short* vb = val + (size_t)b*kS*256 + head*32 + d4*4;
    const int WL[4] = {64,32,16,8};
    const int BASE[4] = {0,4096,5120,5376};
    f32x4 acc = {0.f,0.f,0.f,0.f};
    #pragma unroll
    for (int l = 0; l < 4; ++l) {
        int wl = WL[l], hl = WL[l], base = BASE[l];
        #pragma unroll
        for (int p = 0; p < 4; ++p) {
            float ox = op[l*8 + p*2 + 0];
            float oy = op[l*8 + p*2 + 1];
            float gx = (refx + ox/wl)*wl - 0.5f;
            float gy = (refy + oy/hl)*hl - 0.5f;
            float x0f = floorf(gx), y0f = floorf(gy);
            float wx1 = gx - x0f, wy1 = gy - y0f;
            int x0 = (int)x0f, y0 = (int)y0f;
            float a = ap[l*4 + p];
            #pragma unroll
            for (int dy = 0; dy < 2; ++dy) {
                int yi = y0 + dy;
                if (yi < 0 || yi >= hl) continue;
                float wy = dy ? wy1 : 1.f - wy1;
                #pragma unroll
                for (int dx = 0; dx < 2; ++dx) {
                    int xi = x0 + dx;
                    if (xi < 0 || xi >= wl) continue;
                    float wx = dx ? wx1 : 1.f - wx1;
                    short4v v = *(const short4v*)&vb[(size_t)(base + yi*wl + xi)*256];
                    float wgt = wx*wy*a;
                    acc[0] += bf2f(v[0])*wgt; acc[1] += bf2f(v[1])*wgt;
                    acc[2] += bf2f(v[2])*wgt; acc[3] += bf2f(v[3])*wgt;
                }
            }
        }
    }
    short4v o;
    o[0]=bf16rne(acc[0]); o[1]=bf16rne(acc[1]); o[2]=bf16rne(acc[2]); o[3]=bf16rne(acc[3]);
    *(short4v*)&msd[(size_t)bs*256 + head*32 + d4*4] = o;
}

// src = LayerNorm(src + delta); writes src fp32, srcbf, optionally qbf=bf16(src+pos)
template<int WQ>
__global__ __launch_bounds__(256) void add_ln_kernel(float* __restrict__ src,
        const float* __restrict__ delta, const float* __restrict__ g,
        const float* __restrict__ bta, short* __restrict__ srcbf,
        short* __restrict__ qbf, const float* __restrict__ pos)
{
    int lane = threadIdx.x & 63;
    int row  = blockIdx.x*4 + (threadIdx.x >> 6);
    f32x4* s4 = (f32x4*)(src + (size_t)row*256);
    const f32x4* d4 = (const f32x4*)(delta + (size_t)row*256);
    f32x4 x = s4[lane];
    f32x4 dd = d4[lane];
    x[0]+=dd[0]; x[1]+=dd[1]; x[2]+=dd[2]; x[3]+=dd[3];
    float s = x[0]+x[1]+x[2]+x[3];
    #pragma unroll
    for (int o = 1; o < 64; o <<= 1) s += __shfl_xor(s, o);
    float mu = s * (1.f/256.f);
    f32x4 xc;
    xc[0]=x[0]-mu; xc[1]=x[1]-mu; xc[2]=x[2]-mu; xc[3]=x[3]-mu;
    float s2 = xc[0]*xc[0]+xc[1]*xc[1]+xc[2]*xc[2]+xc[3]*xc[3];
    #pragma unroll
    for (int o = 1; o < 64; o <<= 1) s2 += __shfl_xor(s2, o);
    float inv = rsqrtf(s2*(1.f/256.f) + 1e-5f);
    const f32x4 gv = ((const f32x4*)g)[lane];
    const f32x4 bv = ((const f32x4*)bta)[lane];
    f32x4 o4;
    o4[0]=xc[0]*inv*gv[0]+bv[0]; o4[1]=xc[1]*inv*gv[1]+bv[1];
    o4[2]=xc[2]*inv*gv[2]+bv[2]; o4[3]=xc[3]*inv*gv[3]+bv[3];
    s4[lane] = o4;
    short4v sb;
    sb[0]=bf16rne(o4[0]); sb[1]=bf16rne(o4[1]); sb[2]=bf16rne(o4[2]); sb[3]=bf16rne(o4[3]);
    *(short4v*)&srcbf[(size_t)row*256 + lane*4] = sb;
    if constexpr (WQ) {
        f32x4 pv = ((const f32x4*)(pos + (size_t)row*256))[lane];
        short4v qb;
        qb[0]=bf16rne(o4[0]+pv[0]); qb[1]=bf16rne(o4[1]+pv[1]);
        qb[2]=bf16rne(o4[2]+pv[2]); qb[3]=bf16rne(o4[3]+pv[3]);
        *(short4v*)&qbf[(size_t)row*256 + lane*4] = qb;
    }
}

// im2col for conv1 in bf16
__global__ void im2col_bf16_kernel(const float* __restrict__ src, short* __restrict__ A, int n)
{
    int idx = blockIdx.x * blockDim.x + threadIdx.x;
    if (idx >= n) return;
    int k = idx % 2304;
    int m = idx / 2304;
    int c  = k / 9;
    int r9 = k - c*9;
    int dy = r9 / 3;
    int dx = r9 - dy*3;
    int x = m & 63, y = (m >> 6) & 63, b = m >> 12;
    int yy = y + dy - 1, xx = x + dx - 1;
    float v = 0.f;
    if (yy >= 0 && yy < 64 && xx >= 0 && xx < 64)
        v = src[((size_t)b*kS + yy*64 + xx)*256 + c];
    A[idx] = bf16rne(v);
}

// conv2: 3x3, 64->2; input c1 NHWC; output NCHW
__global__ void conv2_kernel(const float* __restrict__ c1, const float* __restrict__ w,
                             const float* __restrict__ bias, float* __restrict__ pred)
{
    int idx = blockIdx.x * blockDim.x + threadIdx.x;   // B*2*64*64
    int x = idx & 63;
    int y = (idx >> 6) & 63;
    int o = (idx >> 12) & 1;
    int b = idx >> 13;
    float acc = bias[o];
    for (int dy = 0; dy < 3; ++dy) {
        int yy = y + dy - 1;
        if (yy < 0 || yy >= 64) continue;
        for (int dx = 0; dx < 3; ++dx) {
            int xx = x + dx - 1;
            if (xx < 0 || xx >= 64) continue;
            const float* sp = c1 + ((size_t)(b*4096) + yy*64 + xx)*64;
            const float* wp = w + o*576 + dy*3 + dx;
            for (int c = 0; c < 64; ++c) acc += sp[c] * wp[c*9];
        }
    }
    pred[idx] = acc;
}

// bilinear resize 64x64 -> 256x256 (half-pixel, edge clamp)
__global__ void resize_kernel(const float* __restrict__ pred, float* __restrict__ out)
{
    int idx = blockIdx.x * blockDim.x + threadIdx.x;   // B*2*256*256
    int X = idx & 255;
    int Y = (idx >> 8) & 255;
    int c = (idx >> 16) & 1;
    int b = idx >> 17;
    float sx = (X + 0.5f)*0.25f - 0.5f;
    float sy = (Y + 0.5f)*0.25f - 0.5f;
    int x0 = (int)floorf(sx); float fx = sx - x0;
    int y0 = (int)floorf(sy); float fy = sy - y0;
    int x0c = min(max(x0, 0), 63), x1c = min(max(x0+1, 0), 63);
    int y0c = min(max(y0, 0), 63), y1c = min(max(y0+1, 0), 63);
    const float* p = pred + ((size_t)(b*2 + c))*4096;
    float v00 = p[y0c*64 + x0c], v01 = p[y0c*64 + x1c];
    float v10 = p[y1c*64 + x0c], v11 = p[y1c*64 + x1c];
    out[idx] = (1.f-fy)*((1.f-fx)*v00 + fx*v01) + fy*((1.f-fx)*v10 + fx*v11);
}

// ---------------- launch ----------------
extern "C" void kernel_launch(void* const* d_in, const int* in_sizes, int n_in,
                              void* d_out, int out_size, void* d_ws, size_t ws_size,
                              hipStream_t stream)
{
    const float* F[3][4];
    for (int t = 0; t < 3; ++t)
        for (int l = 0; l < 4; ++l)
            F[t][l] = (const float*)d_in[t*4 + l];
    const float* tfw = (const float*)d_in[12];
    const float *pw[4], *pb[4], *gg[4], *gb[4];
    for (int l = 0; l < 4; ++l) {
        pw[l] = (const float*)d_in[13 + 4*l];
        pb[l] = (const float*)d_in[14 + 4*l];
        gg[l] = (const float*)d_in[15 + 4*l];
        gb[l] = (const float*)d_in[16 + 4*l];
    }
    const float* lev   = (const float*)d_in[29];
    const float* off_w = (const float*)d_in[30];
    const float* off_b = (const float*)d_in[31];
    const float* aw_w  = (const float*)d_in[32];
    const float* aw_b  = (const float*)d_in[33];
    const float* val_w = (const float*)d_in[34];
    const float* val_b = (const float*)d_in[35];
    const float* out_w = (const float*)d_in[36];
    const float* out_b = (const float*)d_in[37];
    const float* ln1g  = (const float*)d_in[38];
    const float* ln1b  = (const float*)d_in[39];
    const float* ff1w  = (const float*)d_in[40];
    const float* ff1b  = (const float*)d_in[41];
    const float* ff2w  = (const float*)d_in[42];
    const float* ff2b  = (const float*)d_in[43];
    const float* ln2g  = (const float*)d_in[44];
    const float* ln2b  = (const float*)d_in[45];
    const float* c1w   = (const float*)d_in[46];
    const float* c1b   = (const float*)d_in[47];
    const float* c2w   = (const float*)d_in[48];
    const float* c2b   = (const float*)d_in[49];

    const size_t N256 = (size_t)kB * kS * 256;        // 5,570,560
    float* ws    = (float*)d_ws;
    float* src   = ws;                                // 5.57M f
    short* srcbf = (short*)(src + N256);
    short* qbf   = srcbf + N256;
    short* valbf = qbf + N256;
    short* msdbf = valbf + N256;
    short* warena= msdbf + N256;                      // bf16 weights
    short* Wcat_bf = warena;                              // 589824
    short* valw_bf = Wcat_bf + 589824;                    // 393216
    short* outw_bf = valw_bf + 393216;                    // 393216
    short* ff1w_bf = outw_bf + 393216;                    // 1572864
    short* ff2w_bf = ff1w_bf + 1572864;                   // 1572864
    short* pw_bf   = ff2w_bf + 1572864;                   // 360448
    short* c1w_bf  = pw_bf + 360448;                      // 147456
    float* bcat  = (float*)(c1w_bf + 147456 + 128);   // 2304 f
    float* gnstat= bcat + 4096;                       // 65536 f
    float* gnA   = gnstat + 65536;                    // 1024 f
    float* gnB   = gnA + 1024;                        // 1024 f
    float* pos   = gnB + 1024;                        // 5.57M f
    float* cat   = pos + N256;                        // kM*384
    float* tmp   = cat + (size_t)kM*384;              // 5.57M f
    short* ffhbf = (short*)(tmp + N256);              // kM*1024 shorts
    // stage-1 aliases (cat/tmp dead in stage 1)
    short* fusedT = (short*)cat;
    float* xbufT  = tmp;
    // head aliases (pos..ffhbf dead after encoder)
    short* Acol  = (short*)pos;                       // 37.7M shorts < pos..ffhbf region
    float* c1o   = (float*)valbf;
    float* pred  = (float*)msdbf;

    const int LVL_HWS[4]  = {4096, 1024, 256, 64};
    const int LVL_BASE[4] = {0, 4096, 5120, 5376};
    const int LVL_C[4]    = {128, 256, 512, 512};
    const int LVL_PRIOR[4]= {0, 128, 256, 512};       // reference's literal (non-cumulative) priors
    const int PW_OFF[4]   = {0, 32768, 98304, 229376};

    // ---- weight prep (bf16) ----
    {
        int n = 6*384*256;
        concat_w_kernel<<<(n+255)/256, 256, 0, stream>>>(off_w, aw_w, Wcat_bf, n);
        concat_b_kernel<<<(6*384+255)/256, 256, 0, stream>>>(off_b, aw_b, bcat, 6*384);
        f2bf_kernel<<<(393216/4+255)/256, 256, 0, stream>>>(val_w, valw_bf, 393216);
        f2bf_kernel<<<(393216/4+255)/256, 256, 0, stream>>>(out_w, outw_bf, 393216);
        f2bf_kernel<<<(1572864/4+255)/256, 256, 0, stream>>>(ff1w, ff1w_bf, 1572864);
        f2bf_kernel<<<(1572864/4+255)/256, 256, 0, stream>>>(ff2w, ff2w_bf, 1572864);
        for (int l = 0; l < 4; ++l) {
            int n2 = 256 * LVL_C[l];
            f2bf_kernel<<<(n2/4+255)/256, 256, 0, stream>>>(pw[l], pw_bf + PW_OFF[l], n2);
        }
        f2bf_kernel<<<(147456/4+255)/256, 256, 0, stream>>>(c1w, c1w_bf, 147456);
    }

    // ---- stage 1 ----
    for (int l = 0; l < 4; ++l) {
        int hw = LVL_HWS[l];
        int dim = (l==0)?64:(l==1)?32:(l==2)?16:8;
        int n3 = hw * kH;
        pos_kernel<<<(n3+255)/256, 256, 0, stream>>>(lev, pos, dim, dim, LVL_BASE[l], l, n3);
    }
    for (int l = 0; l < 4; ++l) {
        int hw = LVL_HWS[l], c = LVL_C[l];
        dim3 gf(hw/32, c/32, kB);
        fuseT_kernel<<<gf, 256, 0, stream>>>(F[0][l], F[1][l], F[2][l], tfw,
                                             fusedT, c, hw, LVL_PRIOR[l]);
        dim3 gp(4, (kB*hw)/64);
        gemm64<0><<<gp, 256, 0, stream>>>(fusedT, pw_bf + PW_OFF[l], pb[l],
                                          xbufT, nullptr, 256, c, 0);
        int nchunks = hw / 16;
        gn_sum_kernel<<<dim3(nchunks, kB), 256, 0, stream>>>(xbufT, gnstat, nchunks);
        gn_fin_kernel<<<kB, 256, 0, stream>>>(gnstat, gg[l], gb[l], gnA, gnB, nchunks, hw);
        gn_apply_kernel<<<(kB*hw*256)/1024, 256, 0, stream>>>(xbufT, gnA, gnB, pos,
                                                              src, srcbf, qbf, hw, LVL_BASE[l]);
    }

    // ---- stage 2: 6 encoder layers ----
    for (int i = 0; i < 6; ++i) {
        gemm_qv<<<dim3(10, kM/64), 256, 0, stream>>>(qbf, srcbf,
                Wcat_bf + (size_t)i*384*256, valw_bf + (size_t)i*65536,
                bcat + i*384, val_b + i*256, cat, valbf);
        int nsm = kM * kNH;
        softmax16_kernel<<<(nsm+255)/256, 256, 0, stream>>>(cat, nsm);
        msdeform4_kernel<<<kM/4, 256, 0, stream>>>(valbf, cat, msdbf);
        gemm64<0><<<dim3(4, kM/64), 256, 0, stream>>>(msdbf, outw_bf + (size_t)i*65536,
                                                      out_b + i*256, tmp, nullptr, 256, 256, 0);
        add_ln_kernel<0><<<kM/4, 256, 0, stream>>>(src, tmp, ln1g + i*256, ln1b + i*256,
                                                   srcbf, nullptr, nullptr);
        gemm64<1><<<dim3(16, kM/64), 256, 0, stream>>>(srcbf, ff1w_bf + (size_t)i*262144,
                                                       ff1b + i*1024, nullptr, ffhbf, 1024, 256, 1);
        gemm64<0><<<dim3(4, kM/64), 256, 0, stream>>>(ffhbf, ff2w_bf + (size_t)i*262144,
                                                      ff2b + i*256, tmp, nullptr, 256, 1024, 0);
        add_ln_kernel<1><<<kM/4, 256, 0, stream>>>(src, tmp, ln2g + i*256, ln2b + i*256,
                                                   srcbf, qbf, pos);
    }

    // ---- stage 3: head ----
    {
        int nim = 16384 * 2304;
        im2col_bf16_kernel<<<(nim+255)/256, 256, 0, stream>>>(src, Acol, nim);
        gemm64<0><<<dim3(1, 256), 256, 0, stream>>>(Acol, c1w_bf, c1b, c1o, nullptr, 64, 2304, 1);
        conv2_kernel<<<(kB*2*64*64)/256, 256, 0, stream>>>(c1o, c2w, c2b, pred);
        resize_kernel<<<(kB*2*256*256)/256, 256, 0, stream>>>(pred, (float*)d_out);
    }
}

// Round 6
// 1437.120 us; speedup vs baseline: 6.3001x; 1.0925x over previous
//
#include <hip/hip_runtime.h>
#include <math.h>

// ---------------- problem constants ----------------
constexpr int kB = 4;
constexpr int kS = 5440;           // 64*64 + 32*32 + 16*16 + 8*8
constexpr int kH = 256;            // HIDDEN
constexpr int kNH = 8, kNL = 4, kNP = 4, kDH = 32;
constexpr int kM = kB * kS;        // 21760 rows
constexpr int kCHSUM = 1408;       // sum(CHS)

typedef __attribute__((ext_vector_type(8))) short short8v;   // 8 bf16 (4 VGPRs)
typedef __attribute__((ext_vector_type(4))) short short4v;   // 4 bf16 (8 B)
typedef __attribute__((ext_vector_type(4))) float f32x4;

__device__ inline short bf16rne(float f) {
    unsigned u = __float_as_uint(f);
    u += 0x7FFF + ((u >> 16) & 1);
    return (short)(u >> 16);
}
__device__ inline float bf2f(short s) {
    return __uint_as_float(((unsigned)(unsigned short)s) << 16);
}

// ---------------- prep kernels ----------------

__global__ void f2bf_kernel(const float* __restrict__ in, short* __restrict__ out, int n)
{
    int idx = (blockIdx.x * blockDim.x + threadIdx.x) * 4;
    if (idx >= n) return;
    f32x4 v = *(const f32x4*)(in + idx);
    short4v o;
    o[0]=bf16rne(v[0]); o[1]=bf16rne(v[1]); o[2]=bf16rne(v[2]); o[3]=bf16rne(v[3]);
    *(short4v*)(out + idx) = o;
}

__global__ void concat_w_kernel(const float* __restrict__ off_w, const float* __restrict__ aw_w,
                                short* __restrict__ Wcat, int n)
{
    int idx = blockIdx.x * blockDim.x + threadIdx.x;
    if (idx >= n) return;                 // n = 6*384*256
    int col = idx & 255;
    int row = (idx >> 8) % 384;
    int i   = idx / (384*256);
    float v = (row < 256) ? off_w[((size_t)i*256 + row)*256 + col]
                          : aw_w[((size_t)i*128 + row-256)*256 + col];
    Wcat[idx] = bf16rne(v);
}
__global__ void concat_b_kernel(const float* __restrict__ off_b, const float* __restrict__ aw_b,
                                float* __restrict__ bcat, int n)
{
    int idx = blockIdx.x * blockDim.x + threadIdx.x;
    if (idx >= n) return;                 // n = 6*384
    int row = idx % 384;
    int i   = idx / 384;
    bcat[idx] = (row < 256) ? off_b[i*256 + row] : aw_b[i*128 + row-256];
}

// ---------------- stage-1 kernels ----------------

// fused (transposed, bf16 out)
__global__ __launch_bounds__(256) void fuseT_kernel(const float* __restrict__ f0,
        const float* __restrict__ f1, const float* __restrict__ f2,
        const float* __restrict__ tfw, short* __restrict__ out,
        int c, int hw, int prior)
{
    __shared__ float tile[32][33];
    int p0 = blockIdx.x * 32;
    int c0 = blockIdx.y * 32;
    int b  = blockIdx.z;
    int tx  = threadIdx.x & 31;
    int ty8 = threadIdx.x >> 5;
    #pragma unroll
    for (int i = 0; i < 4; ++i) {
        int ch = c0 + ty8 + i*8;
        float t0 = tfw[0*kCHSUM + prior + ch];
        float t1 = tfw[1*kCHSUM + prior + ch];
        float t2 = tfw[2*kCHSUM + prior + ch];
        float m = fmaxf(t0, fmaxf(t1, t2));
        float e0 = expf(t0-m), e1 = expf(t1-m), e2 = expf(t2-m);
        float inv = 1.0f / (e0+e1+e2);
        size_t base = ((size_t)b*c + ch)*hw + p0 + tx;
        tile[ty8+i*8][tx] = f0[base]*(e0*inv) + f1[base]*(e1*inv) + f2[base]*(e2*inv);
    }
    __syncthreads();
    #pragma unroll
    for (int i = 0; i < 4; ++i) {
        int p = p0 + ty8 + i*8;
        out[((size_t)b*hw + p)*c + c0 + tx] = bf16rne(tile[tx][ty8+i*8]);
    }
}

// GN pass 1: per (b, chunk of 16 rows) partial per-group sums. Fully coalesced.
__global__ __launch_bounds__(256) void gn_sum_kernel(const float* __restrict__ xbufT,
        float* __restrict__ gnstat, int nchunks)
{
    int chunk = blockIdx.x, b = blockIdx.y;
    int t = threadIdx.x;
    size_t base = ((size_t)b*nchunks + chunk) * 4096;   // 16 rows * 256
    float s = 0.f, q = 0.f;
    #pragma unroll
    for (int i = 0; i < 4; ++i) {
        f32x4 v = *(const f32x4*)(xbufT + base + i*1024 + t*4);
        s += v[0]+v[1]+v[2]+v[3];
        q += v[0]*v[0]+v[1]*v[1]+v[2]*v[2]+v[3]*v[3];
    }
    __shared__ float ls[256], lq[256];
    ls[t] = s; lq[t] = q; __syncthreads();
    if (t < 64) { ls[t] += ls[t+64]+ls[t+128]+ls[t+192];
                  lq[t] += lq[t+64]+lq[t+128]+lq[t+192]; }
    __syncthreads();
    if (t < 32) {
        float ss = ls[2*t] + ls[2*t+1];
        float qq = lq[2*t] + lq[2*t+1];
        size_t o = (((size_t)b*nchunks + chunk)*32 + t)*2;
        gnstat[o] = ss; gnstat[o+1] = qq;
    }
}

// GN pass 2: reduce chunks -> per-channel scale/shift
__global__ __launch_bounds__(256) void gn_fin_kernel(const float* __restrict__ gnstat,
        const float* __restrict__ gg, const float* __restrict__ gb,
        float* __restrict__ gnA, float* __restrict__ gnB, int nchunks, int hw)
{
    int b = blockIdx.x, t = threadIdx.x;
    int g = t >> 3, sub = t & 7;
    float s = 0.f, q = 0.f;
    for (int c = sub; c < nchunks; c += 8) {
        size_t o = (((size_t)b*nchunks + c)*32 + g)*2;
        s += gnstat[o]; q += gnstat[o+1];
    }
    __shared__ float ls[256], lq[256], gmu[32], ginv[32];
    ls[t] = s; lq[t] = q; __syncthreads();
    if (sub < 4) { ls[t] += ls[t+4]; lq[t] += lq[t+4]; } __syncthreads();
    if (sub < 2) { ls[t] += ls[t+2]; lq[t] += lq[t+2]; } __syncthreads();
    if (sub == 0) {
        float ss = ls[t] + ls[t+1], qq = lq[t] + lq[t+1];
        float n = 8.0f * hw;
        float mu = ss / n;
        float var = qq / n - mu*mu;
        gmu[g] = mu; ginv[g] = rsqrtf(var + 1e-5f);
    }
    __syncthreads();
    int ch = t;
    float A = ginv[ch>>3] * gg[ch];
    float B = gb[ch] - gmu[ch>>3] * A;
    gnA[b*256 + ch] = A;
    gnB[b*256 + ch] = B;
}

// GN pass 3: apply, fully coalesced; writes src fp32, srcbf, qbf=bf16(src+pos)
__global__ __launch_bounds__(256) void gn_apply_kernel(const float* __restrict__ xbufT,
        const float* __restrict__ gnA, const float* __restrict__ gnB,
        const float* __restrict__ pos, float* __restrict__ src,
        short* __restrict__ srcbf, short* __restrict__ qbf, int hw, int sbase)
{
    int E = hw * 256;
    size_t fl = (size_t)blockIdx.x*1024 + threadIdx.x*4;
    int b = (int)(fl / E);
    int off = (int)(fl - (size_t)b*E);
    int p = off >> 8, col = off & 255;
    f32x4 v = *(const f32x4*)(xbufT + fl);
    f32x4 A = *(const f32x4*)(gnA + b*256 + col);
    f32x4 Bv = *(const f32x4*)(gnB + b*256 + col);
    size_t si = ((size_t)b*kS + sbase + p)*256 + col;
    f32x4 pv = *(const f32x4*)(pos + si);
    f32x4 o;
    o[0]=v[0]*A[0]+Bv[0]; o[1]=v[1]*A[1]+Bv[1];
    o[2]=v[2]*A[2]+Bv[2]; o[3]=v[3]*A[3]+Bv[3];
    *(f32x4*)(src + si) = o;
    short4v sb, qb;
    sb[0]=bf16rne(o[0]); sb[1]=bf16rne(o[1]); sb[2]=bf16rne(o[2]); sb[3]=bf16rne(o[3]);
    qb[0]=bf16rne(o[0]+pv[0]); qb[1]=bf16rne(o[1]+pv[1]);
    qb[2]=bf16rne(o[2]+pv[2]); qb[3]=bf16rne(o[3]+pv[3]);
    *(short4v*)(srcbf + si) = sb;
    *(short4v*)(qbf + si) = qb;
}

// sine position embedding + level embed, broadcast over batch
__global__ void pos_kernel(const float* __restrict__ lev, float* __restrict__ pos,
                           int h, int w, int sbase, int lvl, int n)
{
    int idx = blockIdx.x * blockDim.x + threadIdx.x;
    if (idx >= n) return;                 // n = h*w*256
    int ch = idx % kH;
    int p  = idx / kH;
    int py = p / w, px = p % w;
    int c2 = ch & 127;
    int i  = c2 >> 1;
    float dt = powf(10000.0f, (float)i / 64.0f);
    float t;
    if (ch < 128) t = (py + 1) / ((float)h + 1e-6f) * 6.2831853071795864f;
    else          t = (px + 1) / ((float)w + 1e-6f) * 6.2831853071795864f;
    float arg = t / dt;
    float val = (c2 & 1) ? cosf(arg) : sinf(arg);
    val += lev[lvl*kH + ch];
    for (int b = 0; b < kB; ++b)
        pos[((size_t)b*kS + sbase + p)*kH + ch] = val;
}

// ---------------- 64x64 MFMA bf16 GEMM, BK=64 (2 k-panels) ----------------
// grid (N/64, M/64); 256 threads = 4 waves 2x2; per-wave 32x32 (2x2 16x16x32 frags).
// LDS: 2 panels of [64][40] shorts per matrix. OUTMODE 0=fp32 C, 1=bf16 Cb.
// M,N multiples of 64; K multiple of 64.
template<int OUTMODE>
__global__ __launch_bounds__(256) void gemm64(const short* __restrict__ A,
        const short* __restrict__ W, const float* __restrict__ bias,
        float* __restrict__ C, short* __restrict__ Cb, int N, int K, int relu)
{
    __shared__ short Asm[2][64 * 40];
    __shared__ short Bsm[2][64 * 40];
    const int t    = threadIdx.x;
    const int bn   = blockIdx.x * 64;
    const int bm   = blockIdx.y * 64;
    const int lane = t & 63;
    const int wid  = t >> 6;
    const int wr   = wid >> 1;
    const int wc   = wid & 1;
    const int frow = lane & 15;
    const int g    = lane >> 4;
    const int sr   = t >> 2;           // 0..63
    const int q    = t & 3;            // 16-short chunk id
    const int kh   = q >> 1;           // panel
    const int ko   = (q & 1) * 16;     // offset in panel

    f32x4 acc[2][2];
    #pragma unroll
    for (int i = 0; i < 2; ++i)
        #pragma unroll
        for (int j = 0; j < 2; ++j)
            acc[i][j] = (f32x4){0.f,0.f,0.f,0.f};

    const short* Aptr = A + (size_t)(bm + sr)*K + q*16;
    const short* Wptr = W + (size_t)(bn + sr)*K + q*16;
    short8v a0 = *(const short8v*)Aptr;
    short8v a1 = *(const short8v*)(Aptr + 8);
    short8v w0 = *(const short8v*)Wptr;
    short8v w1 = *(const short8v*)(Wptr + 8);

    for (int k0 = 0; k0 < K; k0 += 64) {
        __syncthreads();
        *(short8v*)&Asm[kh][sr*40 + ko]     = a0;
        *(short8v*)&Asm[kh][sr*40 + ko + 8] = a1;
        *(short8v*)&Bsm[kh][sr*40 + ko]     = w0;
        *(short8v*)&Bsm[kh][sr*40 + ko + 8] = w1;
        __syncthreads();
        if (k0 + 64 < K) {
            a0 = *(const short8v*)(Aptr + k0 + 64);
            a1 = *(const short8v*)(Aptr + k0 + 72);
            w0 = *(const short8v*)(Wptr + k0 + 64);
            w1 = *(const short8v*)(Wptr + k0 + 72);
        }
        #pragma unroll
        for (int p = 0; p < 2; ++p) {
            short8v af[2], bfv[2];
            #pragma unroll
            for (int i = 0; i < 2; ++i)
                af[i] = *(const short8v*)&Asm[p][(wr*32 + i*16 + frow)*40 + g*8];
            #pragma unroll
            for (int j = 0; j < 2; ++j)
                bfv[j] = *(const short8v*)&Bsm[p][(wc*32 + j*16 + frow)*40 + g*8];
            #pragma unroll
            for (int i = 0; i < 2; ++i)
                #pragma unroll
                for (int j = 0; j < 2; ++j)
                    acc[i][j] = __builtin_amdgcn_mfma_f32_16x16x32_bf16(af[i], bfv[j], acc[i][j], 0, 0, 0);
        }
    }

    #pragma unroll
    for (int j = 0; j < 2; ++j) {
        int col = bn + wc*32 + j*16 + frow;
        float bz = bias[col];
        #pragma unroll
        for (int i = 0; i < 2; ++i) {
            int row = bm + wr*32 + i*16 + g*4;
            #pragma unroll
            for (int rr = 0; rr < 4; ++rr) {
                float v = acc[i][j][rr] + bz;
                if (relu) v = fmaxf(v, 0.f);
                if constexpr (OUTMODE == 0) C[(size_t)(row + rr)*N + col] = v;
                else                        Cb[(size_t)(row + rr)*N + col] = bf16rne(v);
            }
        }
    }
}

// merged (off|aw|val) GEMM, BK=64, fused aw-softmax.
// N=640; bn<256: off -> cat fp32 (ld 384); bn in {256,320}: aw -> softmax16 -> cat;
// bn>=384: val -> valbf bf16 (ld 256). K=256.
__global__ __launch_bounds__(256) void gemm_qv(const short* __restrict__ Aq,
        const short* __restrict__ As, const short* __restrict__ W1,
        const short* __restrict__ W2, const float* __restrict__ b1,
        const float* __restrict__ b2, float* __restrict__ C1,
        short* __restrict__ Cb2)
{
    __shared__ short Asm[2][64 * 40];
    __shared__ short Bsm[2][64 * 40];
    const int t    = threadIdx.x;
    const int bn   = blockIdx.x * 64;
    const int bm   = blockIdx.y * 64;
    const bool qreg = bn < 384;
    const int K = 256;
    const int lane = t & 63;
    const int wid  = t >> 6;
    const int wr   = wid >> 1;
    const int wc   = wid & 1;
    const int frow = lane & 15;
    const int g    = lane >> 4;
    const int sr   = t >> 2;
    const int q    = t & 3;
    const int kh   = q >> 1;
    const int ko   = (q & 1) * 16;

    f32x4 acc[2][2];
    #pragma unroll
    for (int i = 0; i < 2; ++i)
        #pragma unroll
        for (int j = 0; j < 2; ++j)
            acc[i][j] = (f32x4){0.f,0.f,0.f,0.f};

    const short* Aptr = (qreg ? Aq : As) + (size_t)(bm + sr)*K + q*16;
    const short* Wptr = (qreg ? (W1 + (size_t)(bn + sr)*K)
                              : (W2 + (size_t)(bn - 384 + sr)*K)) + q*16;
    short8v a0 = *(const short8v*)Aptr;
    short8v a1 = *(const short8v*)(Aptr + 8);
    short8v w0 = *(const short8v*)Wptr;
    short8v w1 = *(const short8v*)(Wptr + 8);

    for (int k0 = 0; k0 < K; k0 += 64) {
        __syncthreads();
        *(short8v*)&Asm[kh][sr*40 + ko]     = a0;
        *(short8v*)&Asm[kh][sr*40 + ko + 8] = a1;
        *(short8v*)&Bsm[kh][sr*40 + ko]     = w0;
        *(short8v*)&Bsm[kh][sr*40 + ko + 8] = w1;
        __syncthreads();
        if (k0 + 64 < K) {
            a0 = *(const short8v*)(Aptr + k0 + 64);
            a1 = *(const short8v*)(Aptr + k0 + 72);
            w0 = *(const short8v*)(Wptr + k0 + 64);
            w1 = *(const short8v*)(Wptr + k0 + 72);
        }
        #pragma unroll
        for (int p = 0; p < 2; ++p) {
            short8v af[2], bfv[2];
            #pragma unroll
            for (int i = 0; i < 2; ++i)
                af[i] = *(const short8v*)&Asm[p][(wr*32 + i*16 + frow)*40 + g*8];
            #pragma unroll
            for (int j = 0; j < 2; ++j)
                bfv[j] = *(const short8v*)&Bsm[p][(wc*32 + j*16 + frow)*40 + g*8];
            #pragma unroll
            for (int i = 0; i < 2; ++i)
                #pragma unroll
                for (int j = 0; j < 2; ++j)
                    acc[i][j] = __builtin_amdgcn_mfma_f32_16x16x32_bf16(af[i], bfv[j], acc[i][j], 0, 0, 0);
        }
    }

    if (bn == 256 || bn == 320) {
        // aw region: fused softmax over each 16-col head (16 frow lanes per (row, head))
        #pragma unroll
        for (int j = 0; j < 2; ++j) {
            int col = bn + wc*32 + j*16 + frow;
            float bz = b1[col];
            #pragma unroll
            for (int i = 0; i < 2; ++i) {
                int row = bm + wr*32 + i*16 + g*4;
                #pragma unroll
                for (int rr = 0; rr < 4; ++rr) {
                    float v = acc[i][j][rr] + bz;
                    float m = v;
                    m = fmaxf(m, __shfl_xor(m, 1));
                    m = fmaxf(m, __shfl_xor(m, 2));
                    m = fmaxf(m, __shfl_xor(m, 4));
                    m = fmaxf(m, __shfl_xor(m, 8));
                    float e = expf(v - m);
                    float s = e;
                    s += __shfl_xor(s, 1);
                    s += __shfl_xor(s, 2);
                    s += __shfl_xor(s, 4);
                    s += __shfl_xor(s, 8);
                    C1[(size_t)(row + rr)*384 + col] = e / s;
                }
            }
        }
    } else {
        #pragma unroll
        for (int j = 0; j < 2; ++j) {
            int col = bn + wc*32 + j*16 + frow;
            float bz = qreg ? b1[col] : b2[col - 384];
            #pragma unroll
            for (int i = 0; i < 2; ++i) {
                int row = bm + wr*32 + i*16 + g*4;
                #pragma unroll
                for (int rr = 0; rr < 4; ++rr) {
                    float v = acc[i][j][rr] + bz;
                    if (qreg) C1[(size_t)(row + rr)*384 + col] = v;
                    else      Cb2[(size_t)(row + rr)*256 + col - 384] = bf16rne(v);
                }
            }
        }
    }
}

// ms_deform: 16B bf16 gathers; thread = (s_local in 8, head, d8 in 4), 8 ch each
__global__ __launch_bounds__(256) void msdeform8_kernel(const short* __restrict__ val,
        const float* __restrict__ cat, short* __restrict__ msd)
{
    int tid  = threadIdx.x;
    int d8   = tid & 3;
    int head = (tid >> 2) & 7;
    int bs   = blockIdx.x*8 + (tid >> 5);
    int s  = bs % kS;
    int b  = bs / kS;
    float refx, refy;
    if (s < 4096)      { int loc = s;        refy = ((loc>>6)+0.5f)/64.f; refx = ((loc&63)+0.5f)/64.f; }
    else if (s < 5120) { int loc = s - 4096; refy = ((loc>>5)+0.5f)/32.f; refx = ((loc&31)+0.5f)/32.f; }
    else if (s < 5376) { int loc = s - 5120; refy = ((loc>>4)+0.5f)/16.f; refx = ((loc&15)+0.5f)/16.f; }
    else               { int loc = s - 5376; refy = ((loc>>3)+0.5f)/8.f;  refx = ((loc&7)+0.5f)/8.f; }
    const float* op = cat + (size_t)bs*384 + head*32;
    const float* ap = cat + (size_t)bs*384 + 256 + head*16;
    const short* vb = val + (size_t)b*kS*256 + head*32 + d8*8;
    const int WL[4] = {64,32,16,8};
    const int BASE[4] = {0,4096,5120,5376};
    float acc[8] = {0.f,0.f,0.f,0.f,0.f,0.f,0.f,0.f};
    #pragma unroll
    for (int l = 0; l < 4; ++l) {
        int wl = WL[l], hl = WL[l], base = BASE[l];
        #pragma unroll
        for (int p = 0; p < 4; ++p) {
            float ox = op[l*8 + p*2 + 0];
            float oy = op[l*8 + p*2 + 1];
            float gx = (refx + ox/wl)*wl - 0.5f;
            float gy = (refy + oy/hl)*hl - 0.5f;
            float x0f = floorf(gx), y0f = floorf(gy);
            float wx1 = gx - x0f, wy1 = gy - y0f;
            int x0 = (int)x0f, y0 = (int)y0f;
            float a = ap[l*4 + p];
            #pragma unroll
            for (int dy = 0; dy < 2; ++dy) {
                int yi = y0 + dy;
                if (yi < 0 || yi >= hl) continue;
                float wy = dy ? wy1 : 1.f - wy1;
                #pragma unroll
                for (int dx = 0; dx < 2; ++dx) {
                    int xi = x0 + dx;
                    if (xi < 0 || xi >= wl) continue;
                    float wx = dx ? wx1 : 1.f - wx1;
                    float wgt = wx*wy*a;
                    uint4 v = *(const uint4*)&vb[(size_t)(base + yi*wl + xi)*256];
                    acc[0] = fmaf(__uint_as_float(v.x << 16),          wgt, acc[0]);
                    acc[1] = fmaf(__uint_as_float(v.x & 0xffff0000u), wgt, acc[1]);
                    acc[2] = fmaf(__uint_as_float(v.y << 16),          wgt, acc[2]);
                    acc[3] = fmaf(__uint_as_float(v.y & 0xffff0000u), wgt, acc[3]);
                    acc[4] = fmaf(__uint_as_float(v.z << 16),          wgt, acc[4]);
                    acc[5] = fmaf(__uint_as_float(v.z & 0xffff0000u), wgt, acc[5]);
                    acc[6] = fmaf(__uint_as_float(v.w << 16),          wgt, acc[6]);
                    acc[7] = fmaf(__uint_as_float(v.w & 0xffff0000u), wgt, acc[7]);
                }
            }
        }
    }
    short8v o;
    #pragma unroll
    for (int k = 0; k < 8; ++k) o[k] = bf16rne(acc[k]);
    *(short8v*)&msd[(size_t)bs*256 + head*32 + d8*8] = o;
}

// src = LayerNorm(src + delta[bf16]); writes src fp32, srcbf, optionally qbf
template<int WQ>
__global__ __launch_bounds__(256) void add_ln_kernel(float* __restrict__ src,
        const short* __restrict__ delta, const float* __restrict__ g,
        const float* __restrict__ bta, short* __restrict__ srcbf,
        short* __restrict__ qbf, const float* __restrict__ pos)
{
    int lane = threadIdx.x & 63;
    int row  = blockIdx.x*4 + (threadIdx.x >> 6);
    f32x4* s4 = (f32x4*)(src + (size_t)row*256);
    f32x4 x = s4[lane];
    short4v dd = *(const short4v*)&delta[(size_t)row*256 + lane*4];
    x[0]+=bf2f(dd[0]); x[1]+=bf2f(dd[1]); x[2]+=bf2f(dd[2]); x[3]+=bf2f(dd[3]);
    float s = x[0]+x[1]+x[2]+x[3];
    #pragma unroll
    for (int o = 1; o < 64; o <<= 1) s += __shfl_xor(s, o);
    float mu = s * (1.f/256.f);
    f32x4 xc;
    xc[0]=x[0]-mu; xc[1]=x[1]-mu; xc[2]=x[2]-mu; xc[3]=x[3]-mu;
    float s2 = xc[0]*xc[0]+xc[1]*xc[1]+xc[2]*xc[2]+xc[3]*xc[3];
    #pragma unroll
    for (int o = 1; o < 64; o <<= 1) s2 += __shfl_xor(s2, o);
    float inv = rsqrtf(s2*(1.f/256.f) + 1e-5f);
    const f32x4 gv = ((const f32x4*)g)[lane];
    const f32x4 bv = ((const f32x4*)bta)[lane];
    f32x4 o4;
    o4[0]=xc[0]*inv*gv[0]+bv[0]; o4[1]=xc[1]*inv*gv[1]+bv[1];
    o4[2]=xc[2]*inv*gv[2]+bv[2]; o4[3]=xc[3]*inv*gv[3]+bv[3];
    s4[lane] = o4;
    short4v sb;
    sb[0]=bf16rne(o4[0]); sb[1]=bf16rne(o4[1]); sb[2]=bf16rne(o4[2]); sb[3]=bf16rne(o4[3]);
    *(short4v*)&srcbf[(size_t)row*256 + lane*4] = sb;
    if constexpr (WQ) {
        f32x4 pv = ((const f32x4*)(pos + (size_t)row*256))[lane];
        short4v qb;
        qb[0]=bf16rne(o4[0]+pv[0]); qb[1]=bf16rne(o4[1]+pv[1]);
        qb[2]=bf16rne(o4[2]+pv[2]); qb[3]=bf16rne(o4[3]+pv[3]);
        *(short4v*)&qbf[(size_t)row*256 + lane*4] = qb;
    }
}

// im2col for conv1 in bf16
__global__ void im2col_bf16_kernel(const float* __restrict__ src, short* __restrict__ A, int n)
{
    int idx = blockIdx.x * blockDim.x + threadIdx.x;
    if (idx >= n) return;
    int k = idx % 2304;
    int m = idx / 2304;
    int c  = k / 9;
    int r9 = k - c*9;
    int dy = r9 / 3;
    int dx = r9 - dy*3;
    int x = m & 63, y = (m >> 6) & 63, b = m >> 12;
    int yy = y + dy - 1, xx = x + dx - 1;
    float v = 0.f;
    if (yy >= 0 && yy < 64 && xx >= 0 && xx < 64)
        v = src[((size_t)b*kS + yy*64 + xx)*256 + c];
    A[idx] = bf16rne(v);
}

// conv2: 3x3, 64->2; input c1 NHWC; output NCHW
__global__ void conv2_kernel(const float* __restrict__ c1, const float* __restrict__ w,
                             const float* __restrict__ bias, float* __restrict__ pred)
{
    int idx = blockIdx.x * blockDim.x + threadIdx.x;   // B*2*64*64
    int x = idx & 63;
    int y = (idx >> 6) & 63;
    int o = (idx >> 12) & 1;
    int b = idx >> 13;
    float acc = bias[o];
    for (int dy = 0; dy < 3; ++dy) {
        int yy = y + dy - 1;
        if (yy < 0 || yy >= 64) continue;
        for (int dx = 0; dx < 3; ++dx) {
            int xx = x + dx - 1;
            if (xx < 0 || xx >= 64) continue;
            const float* sp = c1 + ((size_t)(b*4096) + yy*64 + xx)*64;
            const float* wp = w + o*576 + dy*3 + dx;
            for (int c = 0; c < 64; ++c) acc += sp[c] * wp[c*9];
        }
    }
    pred[idx] = acc;
}

// bilinear resize 64x64 -> 256x256 (half-pixel, edge clamp)
__global__ void resize_kernel(const float* __restrict__ pred, float* __restrict__ out)
{
    int idx = blockIdx.x * blockDim.x + threadIdx.x;   // B*2*256*256
    int X = idx & 255;
    int Y = (idx >> 8) & 255;
    int c = (idx >> 16) & 1;
    int b = idx >> 17;
    float sx = (X + 0.5f)*0.25f - 0.5f;
    float sy = (Y + 0.5f)*0.25f - 0.5f;
    int x0 = (int)floorf(sx); float fx = sx - x0;
    int y0 = (int)floorf(sy); float fy = sy - y0;
    int x0c = min(max(x0, 0), 63), x1c = min(max(x0+1, 0), 63);
    int y0c = min(max(y0, 0), 63), y1c = min(max(y0+1, 0), 63);
    const float* p = pred + ((size_t)(b*2 + c))*4096;
    float v00 = p[y0c*64 + x0c], v01 = p[y0c*64 + x1c];
    float v10 = p[y1c*64 + x0c], v11 = p[y1c*64 + x1c];
    out[idx] = (1.f-fy)*((1.f-fx)*v00 + fx*v01) + fy*((1.f-fx)*v10 + fx*v11);
}

// ---------------- launch ----------------
extern "C" void kernel_launch(void* const* d_in, const int* in_sizes, int n_in,
                              void* d_out, int out_size, void* d_ws, size_t ws_size,
                              hipStream_t stream)
{
    const float* F[3][4];
    for (int t = 0; t < 3; ++t)
        for (int l = 0; l < 4; ++l)
            F[t][l] = (const float*)d_in[t*4 + l];
    const float* tfw = (const float*)d_in[12];
    const float *pw[4], *pb[4], *gg[4], *gb[4];
    for (int l = 0; l < 4; ++l) {
        pw[l] = (const float*)d_in[13 + 4*l];
        pb[l] = (const float*)d_in[14 + 4*l];
        gg[l] = (const float*)d_in[15 + 4*l];
        gb[l] = (const float*)d_in[16 + 4*l];
    }
    const float* lev   = (const float*)d_in[29];
    const float* off_w = (const float*)d_in[30];
    const float* off_b = (const float*)d_in[31];
    const float* aw_w  = (const float*)d_in[32];
    const float* aw_b  = (const float*)d_in[33];
    const float* val_w = (const float*)d_in[34];
    const float* val_b = (const float*)d_in[35];
    const float* out_w = (const float*)d_in[36];
    const float* out_b = (const float*)d_in[37];
    const float* ln1g  = (const float*)d_in[38];
    const float* ln1b  = (const float*)d_in[39];
    const float* ff1w  = (const float*)d_in[40];
    const float* ff1b  = (const float*)d_in[41];
    const float* ff2w  = (const float*)d_in[42];
    const float* ff2b  = (const float*)d_in[43];
    const float* ln2g  = (const float*)d_in[44];
    const float* ln2b  = (const float*)d_in[45];
    const float* c1w   = (const float*)d_in[46];
    const float* c1b   = (const float*)d_in[47];
    const float* c2w   = (const float*)d_in[48];
    const float* c2b   = (const float*)d_in[49];

    const size_t N256 = (size_t)kB * kS * 256;        // 5,570,560
    float* ws    = (float*)d_ws;
    float* src   = ws;                                // 5.57M f
    short* srcbf = (short*)(src + N256);
    short* qbf   = srcbf + N256;
    short* valbf = qbf + N256;
    short* msdbf = valbf + N256;
    short* warena= msdbf + N256;                      // bf16 weights
    short* Wcat_bf = warena;                              // 589824
    short* valw_bf = Wcat_bf + 589824;                    // 393216
    short* outw_bf = valw_bf + 393216;                    // 393216
    short* ff1w_bf = outw_bf + 393216;                    // 1572864
    short* ff2w_bf = ff1w_bf + 1572864;                   // 1572864
    short* pw_bf   = ff2w_bf + 1572864;                   // 360448
    short* c1w_bf  = pw_bf + 360448;                      // 147456
    float* bcat  = (float*)(c1w_bf + 147456 + 128);   // 2304 f
    float* gnstat= bcat + 4096;                       // 65536 f
    float* gnA   = gnstat + 65536;                    // 1024 f
    float* gnB   = gnA + 1024;                        // 1024 f
    float* pos   = gnB + 1024;                        // 5.57M f
    float* cat   = pos + N256;                        // kM*384
    float* tmp   = cat + (size_t)kM*384;              // 5.57M f
    short* tmpbf = (short*)tmp;                       // bf16 view of tmp
    short* ffhbf = (short*)(tmp + N256);              // kM*1024 shorts
    // stage-1 aliases (cat/tmp dead in stage 1)
    short* fusedT = (short*)cat;
    float* xbufT  = tmp;
    // head aliases (pos..ffhbf dead after encoder)
    short* Acol  = (short*)pos;                       // 37.7M shorts < pos..ffhbf region
    float* c1o   = (float*)valbf;
    float* pred  = (float*)msdbf;

    const int LVL_HWS[4]  = {4096, 1024, 256, 64};
    const int LVL_BASE[4] = {0, 4096, 5120, 5376};
    const int LVL_C[4]    = {128, 256, 512, 512};
    const int LVL_PRIOR[4]= {0, 128, 256, 512};       // reference's literal (non-cumulative) priors
    const int PW_OFF[4]   = {0, 32768, 98304, 229376};

    // ---- weight prep (bf16) ----
    {
        int n = 6*384*256;
        concat_w_kernel<<<(n+255)/256, 256, 0, stream>>>(off_w, aw_w, Wcat_bf, n);
        concat_b_kernel<<<(6*384+255)/256, 256, 0, stream>>>(off_b, aw_b, bcat, 6*384);
        f2bf_kernel<<<(393216/4+255)/256, 256, 0, stream>>>(val_w, valw_bf, 393216);
        f2bf_kernel<<<(393216/4+255)/256, 256, 0, stream>>>(out_w, outw_bf, 393216);
        f2bf_kernel<<<(1572864/4+255)/256, 256, 0, stream>>>(ff1w, ff1w_bf, 1572864);
        f2bf_kernel<<<(1572864/4+255)/256, 256, 0, stream>>>(ff2w, ff2w_bf, 1572864);
        for (int l = 0; l < 4; ++l) {
            int n2 = 256 * LVL_C[l];
            f2bf_kernel<<<(n2/4+255)/256, 256, 0, stream>>>(pw[l], pw_bf + PW_OFF[l], n2);
        }
        f2bf_kernel<<<(147456/4+255)/256, 256, 0, stream>>>(c1w, c1w_bf, 147456);
    }

    // ---- stage 1 ----
    for (int l = 0; l < 4; ++l) {
        int hw = LVL_HWS[l];
        int dim = (l==0)?64:(l==1)?32:(l==2)?16:8;
        int n3 = hw * kH;
        pos_kernel<<<(n3+255)/256, 256, 0, stream>>>(lev, pos, dim, dim, LVL_BASE[l], l, n3);
    }
    for (int l = 0; l < 4; ++l) {
        int hw = LVL_HWS[l], c = LVL_C[l];
        dim3 gf(hw/32, c/32, kB);
        fuseT_kernel<<<gf, 256, 0, stream>>>(F[0][l], F[1][l], F[2][l], tfw,
                                             fusedT, c, hw, LVL_PRIOR[l]);
        dim3 gp(4, (kB*hw)/64);
        gemm64<0><<<gp, 256, 0, stream>>>(fusedT, pw_bf + PW_OFF[l], pb[l],
                                          xbufT, nullptr, 256, c, 0);
        int nchunks = hw / 16;
        gn_sum_kernel<<<dim3(nchunks, kB), 256, 0, stream>>>(xbufT, gnstat, nchunks);
        gn_fin_kernel<<<kB, 256, 0, stream>>>(gnstat, gg[l], gb[l], gnA, gnB, nchunks, hw);
        gn_apply_kernel<<<(kB*hw*256)/1024, 256, 0, stream>>>(xbufT, gnA, gnB, pos,
                                                              src, srcbf, qbf, hw, LVL_BASE[l]);
    }

    // ---- stage 2: 6 encoder layers ----
    for (int i = 0; i < 6; ++i) {
        gemm_qv<<<dim3(10, kM/64), 256, 0, stream>>>(qbf, srcbf,
                Wcat_bf + (size_t)i*384*256, valw_bf + (size_t)i*65536,
                bcat + i*384, val_b + i*256, cat, valbf);
        msdeform8_kernel<<<kM/8, 256, 0, stream>>>(valbf, cat, msdbf);
        gemm64<1><<<dim3(4, kM/64), 256, 0, stream>>>(msdbf, outw_bf + (size_t)i*65536,
                                                      out_b + i*256, nullptr, tmpbf, 256, 256, 0);
        add_ln_kernel<0><<<kM/4, 256, 0, stream>>>(src, tmpbf, ln1g + i*256, ln1b + i*256,
                                                   srcbf, nullptr, nullptr);
        gemm64<1><<<dim3(16, kM/64), 256, 0, stream>>>(srcbf, ff1w_bf + (size_t)i*262144,
                                                       ff1b + i*1024, nullptr, ffhbf, 1024, 256, 1);
        gemm64<1><<<dim3(4, kM/64), 256, 0, stream>>>(ffhbf, ff2w_bf + (size_t)i*262144,
                                                      ff2b + i*256, nullptr, tmpbf, 256, 1024, 0);
        add_ln_kernel<1><<<kM/4, 256, 0, stream>>>(src, tmpbf, ln2g + i*256, ln2b + i*256,
                                                   srcbf, qbf, pos);
    }

    // ---- stage 3: head ----
    {
        int nim = 16384 * 2304;
        im2col_bf16_kernel<<<(nim+255)/256, 256, 0, stream>>>(src, Acol, nim);
        gemm64<0><<<dim3(1, 256), 256, 0, stream>>>(Acol, c1w_bf, c1b, c1o, nullptr, 64, 2304, 1);
        conv2_kernel<<<(kB*2*64*64)/256, 256, 0, stream>>>(c1o, c2w, c2b, pred);
        resize_kernel<<<(kB*2*256*256)/256, 256, 0, stream>>>(pred, (float*)d_out);
    }
}

// Round 7
// 1163.976 us; speedup vs baseline: 7.7786x; 1.2347x over previous
//
#include <hip/hip_runtime.h>
#include <math.h>

// ---------------- problem constants ----------------
constexpr int kB = 4;
constexpr int kS = 5440;           // 64*64 + 32*32 + 16*16 + 8*8
constexpr int kH = 256;            // HIDDEN
constexpr int kNH = 8, kNL = 4, kNP = 4, kDH = 32;
constexpr int kM = kB * kS;        // 21760 rows
constexpr int kCHSUM = 1408;       // sum(CHS)

typedef __attribute__((ext_vector_type(8))) short short8v;   // 8 bf16 (4 VGPRs)
typedef __attribute__((ext_vector_type(4))) short short4v;   // 4 bf16 (8 B)
typedef __attribute__((ext_vector_type(4))) float f32x4;

__device__ inline short bf16rne(float f) {
    unsigned u = __float_as_uint(f);
    u += 0x7FFF + ((u >> 16) & 1);
    return (short)(u >> 16);
}
__device__ inline float bf2f(short s) {
    return __uint_as_float(((unsigned)(unsigned short)s) << 16);
}

// ---------------- prep kernels ----------------

__global__ void f2bf_kernel(const float* __restrict__ in, short* __restrict__ out, int n)
{
    int idx = (blockIdx.x * blockDim.x + threadIdx.x) * 4;
    if (idx >= n) return;
    f32x4 v = *(const f32x4*)(in + idx);
    short4v o;
    o[0]=bf16rne(v[0]); o[1]=bf16rne(v[1]); o[2]=bf16rne(v[2]); o[3]=bf16rne(v[3]);
    *(short4v*)(out + idx) = o;
}

__global__ void concat_w_kernel(const float* __restrict__ off_w, const float* __restrict__ aw_w,
                                short* __restrict__ Wcat, int n)
{
    int idx = blockIdx.x * blockDim.x + threadIdx.x;
    if (idx >= n) return;                 // n = 6*384*256
    int col = idx & 255;
    int row = (idx >> 8) % 384;
    int i   = idx / (384*256);
    float v = (row < 256) ? off_w[((size_t)i*256 + row)*256 + col]
                          : aw_w[((size_t)i*128 + row-256)*256 + col];
    Wcat[idx] = bf16rne(v);
}
__global__ void concat_b_kernel(const float* __restrict__ off_b, const float* __restrict__ aw_b,
                                float* __restrict__ bcat, int n)
{
    int idx = blockIdx.x * blockDim.x + threadIdx.x;
    if (idx >= n) return;                 // n = 6*384
    int row = idx % 384;
    int i   = idx / 384;
    bcat[idx] = (row < 256) ? off_b[i*256 + row] : aw_b[i*128 + row-256];
}

// conv1 weights [64][256][3][3] -> [64][(dy*3+dx)*256 + c] bf16
__global__ void reorder_c1w_kernel(const float* __restrict__ w, short* __restrict__ out, int n)
{
    int idx = blockIdx.x * blockDim.x + threadIdx.x;
    if (idx >= n) return;                 // n = 64*2304
    int k = idx % 2304, o = idx / 2304;
    int kblk = k >> 8, c = k & 255;
    out[idx] = bf16rne(w[(size_t)o*2304 + c*9 + kblk]);
}
// conv2 weights [2][64][3][3] -> [2][9][64] fp32
__global__ void reorder_c2w_kernel(const float* __restrict__ w, float* __restrict__ out)
{
    int idx = blockIdx.x * blockDim.x + threadIdx.x;
    if (idx >= 1152) return;
    int c = idx & 63, r = idx >> 6;       // r = o*9 + kblk
    int o = r / 9, kblk = r % 9;
    out[idx] = w[((size_t)o*64 + c)*9 + kblk];
}

// ---------------- stage-1 kernels ----------------

// fused (transposed, bf16 out)
__global__ __launch_bounds__(256) void fuseT_kernel(const float* __restrict__ f0,
        const float* __restrict__ f1, const float* __restrict__ f2,
        const float* __restrict__ tfw, short* __restrict__ out,
        int c, int hw, int prior)
{
    __shared__ float tile[32][33];
    int p0 = blockIdx.x * 32;
    int c0 = blockIdx.y * 32;
    int b  = blockIdx.z;
    int tx  = threadIdx.x & 31;
    int ty8 = threadIdx.x >> 5;
    #pragma unroll
    for (int i = 0; i < 4; ++i) {
        int ch = c0 + ty8 + i*8;
        float t0 = tfw[0*kCHSUM + prior + ch];
        float t1 = tfw[1*kCHSUM + prior + ch];
        float t2 = tfw[2*kCHSUM + prior + ch];
        float m = fmaxf(t0, fmaxf(t1, t2));
        float e0 = expf(t0-m), e1 = expf(t1-m), e2 = expf(t2-m);
        float inv = 1.0f / (e0+e1+e2);
        size_t base = ((size_t)b*c + ch)*hw + p0 + tx;
        tile[ty8+i*8][tx] = f0[base]*(e0*inv) + f1[base]*(e1*inv) + f2[base]*(e2*inv);
    }
    __syncthreads();
    #pragma unroll
    for (int i = 0; i < 4; ++i) {
        int p = p0 + ty8 + i*8;
        out[((size_t)b*hw + p)*c + c0 + tx] = bf16rne(tile[tx][ty8+i*8]);
    }
}

// GN pass 1: per (b, chunk of 16 rows) partial per-group sums. Fully coalesced.
__global__ __launch_bounds__(256) void gn_sum_kernel(const float* __restrict__ xbufT,
        float* __restrict__ gnstat, int nchunks)
{
    int chunk = blockIdx.x, b = blockIdx.y;
    int t = threadIdx.x;
    size_t base = ((size_t)b*nchunks + chunk) * 4096;   // 16 rows * 256
    float s = 0.f, q = 0.f;
    #pragma unroll
    for (int i = 0; i < 4; ++i) {
        f32x4 v = *(const f32x4*)(xbufT + base + i*1024 + t*4);
        s += v[0]+v[1]+v[2]+v[3];
        q += v[0]*v[0]+v[1]*v[1]+v[2]*v[2]+v[3]*v[3];
    }
    __shared__ float ls[256], lq[256];
    ls[t] = s; lq[t] = q; __syncthreads();
    if (t < 64) { ls[t] += ls[t+64]+ls[t+128]+ls[t+192];
                  lq[t] += lq[t+64]+lq[t+128]+lq[t+192]; }
    __syncthreads();
    if (t < 32) {
        float ss = ls[2*t] + ls[2*t+1];
        float qq = lq[2*t] + lq[2*t+1];
        size_t o = (((size_t)b*nchunks + chunk)*32 + t)*2;
        gnstat[o] = ss; gnstat[o+1] = qq;
    }
}

// GN pass 2: reduce chunks -> per-channel scale/shift
__global__ __launch_bounds__(256) void gn_fin_kernel(const float* __restrict__ gnstat,
        const float* __restrict__ gg, const float* __restrict__ gb,
        float* __restrict__ gnA, float* __restrict__ gnB, int nchunks, int hw)
{
    int b = blockIdx.x, t = threadIdx.x;
    int g = t >> 3, sub = t & 7;
    float s = 0.f, q = 0.f;
    for (int c = sub; c < nchunks; c += 8) {
        size_t o = (((size_t)b*nchunks + c)*32 + g)*2;
        s += gnstat[o]; q += gnstat[o+1];
    }
    __shared__ float ls[256], lq[256], gmu[32], ginv[32];
    ls[t] = s; lq[t] = q; __syncthreads();
    if (sub < 4) { ls[t] += ls[t+4]; lq[t] += lq[t+4]; } __syncthreads();
    if (sub < 2) { ls[t] += ls[t+2]; lq[t] += lq[t+2]; } __syncthreads();
    if (sub == 0) {
        float ss = ls[t] + ls[t+1], qq = lq[t] + lq[t+1];
        float n = 8.0f * hw;
        float mu = ss / n;
        float var = qq / n - mu*mu;
        gmu[g] = mu; ginv[g] = rsqrtf(var + 1e-5f);
    }
    __syncthreads();
    int ch = t;
    float A = ginv[ch>>3] * gg[ch];
    float B = gb[ch] - gmu[ch>>3] * A;
    gnA[b*256 + ch] = A;
    gnB[b*256 + ch] = B;
}

// GN pass 3: apply, fully coalesced; writes src fp32, srcbf, qbf=bf16(src+pos)
__global__ __launch_bounds__(256) void gn_apply_kernel(const float* __restrict__ xbufT,
        const float* __restrict__ gnA, const float* __restrict__ gnB,
        const float* __restrict__ pos, float* __restrict__ src,
        short* __restrict__ srcbf, short* __restrict__ qbf, int hw, int sbase)
{
    int E = hw * 256;
    size_t fl = (size_t)blockIdx.x*1024 + threadIdx.x*4;
    int b = (int)(fl / E);
    int off = (int)(fl - (size_t)b*E);
    int p = off >> 8, col = off & 255;
    f32x4 v = *(const f32x4*)(xbufT + fl);
    f32x4 A = *(const f32x4*)(gnA + b*256 + col);
    f32x4 Bv = *(const f32x4*)(gnB + b*256 + col);
    size_t si = ((size_t)b*kS + sbase + p)*256 + col;
    f32x4 pv = *(const f32x4*)(pos + si);
    f32x4 o;
    o[0]=v[0]*A[0]+Bv[0]; o[1]=v[1]*A[1]+Bv[1];
    o[2]=v[2]*A[2]+Bv[2]; o[3]=v[3]*A[3]+Bv[3];
    *(f32x4*)(src + si) = o;
    short4v sb, qb;
    sb[0]=bf16rne(o[0]); sb[1]=bf16rne(o[1]); sb[2]=bf16rne(o[2]); sb[3]=bf16rne(o[3]);
    qb[0]=bf16rne(o[0]+pv[0]); qb[1]=bf16rne(o[1]+pv[1]);
    qb[2]=bf16rne(o[2]+pv[2]); qb[3]=bf16rne(o[3]+pv[3]);
    *(short4v*)(srcbf + si) = sb;
    *(short4v*)(qbf + si) = qb;
}

// sine position embedding + level embed, broadcast over batch (exp2f for dim_t)
__global__ void pos_kernel(const float* __restrict__ lev, float* __restrict__ pos,
                           int h, int w, int sbase, int lvl, int n)
{
    int idx = blockIdx.x * blockDim.x + threadIdx.x;
    if (idx >= n) return;                 // n = h*w*256
    int ch = idx % kH;
    int p  = idx / kH;
    int py = p / w, px = p % w;
    int c2 = ch & 127;
    int i  = c2 >> 1;
    // 1/dt = 10000^(-i/64) = exp2(-i * log2(1e4)/64)
    float invdt = exp2f((float)i * -0.20762050593046015f);
    float t;
    if (ch < 128) t = (py + 1) / ((float)h + 1e-6f) * 6.2831853071795864f;
    else          t = (px + 1) / ((float)w + 1e-6f) * 6.2831853071795864f;
    float arg = t * invdt;
    float val = (c2 & 1) ? cosf(arg) : sinf(arg);
    val += lev[lvl*kH + ch];
    for (int b = 0; b < kB; ++b)
        pos[((size_t)b*kS + sbase + p)*kH + ch] = val;
}

// ---------------- 64x64 MFMA bf16 GEMM, BK=64 (2 k-panels) ----------------
template<int OUTMODE>
__global__ __launch_bounds__(256) void gemm64(const short* __restrict__ A,
        const short* __restrict__ W, const float* __restrict__ bias,
        float* __restrict__ C, short* __restrict__ Cb, int N, int K, int relu)
{
    __shared__ short Asm[2][64 * 40];
    __shared__ short Bsm[2][64 * 40];
    const int t    = threadIdx.x;
    const int bn   = blockIdx.x * 64;
    const int bm   = blockIdx.y * 64;
    const int lane = t & 63;
    const int wid  = t >> 6;
    const int wr   = wid >> 1;
    const int wc   = wid & 1;
    const int frow = lane & 15;
    const int g    = lane >> 4;
    const int sr   = t >> 2;           // 0..63
    const int q    = t & 3;            // 16-short chunk id
    const int kh   = q >> 1;           // panel
    const int ko   = (q & 1) * 16;     // offset in panel

    f32x4 acc[2][2];
    #pragma unroll
    for (int i = 0; i < 2; ++i)
        #pragma unroll
        for (int j = 0; j < 2; ++j)
            acc[i][j] = (f32x4){0.f,0.f,0.f,0.f};

    const short* Aptr = A + (size_t)(bm + sr)*K + q*16;
    const short* Wptr = W + (size_t)(bn + sr)*K + q*16;
    short8v a0 = *(const short8v*)Aptr;
    short8v a1 = *(const short8v*)(Aptr + 8);
    short8v w0 = *(const short8v*)Wptr;
    short8v w1 = *(const short8v*)(Wptr + 8);

    for (int k0 = 0; k0 < K; k0 += 64) {
        __syncthreads();
        *(short8v*)&Asm[kh][sr*40 + ko]     = a0;
        *(short8v*)&Asm[kh][sr*40 + ko + 8] = a1;
        *(short8v*)&Bsm[kh][sr*40 + ko]     = w0;
        *(short8v*)&Bsm[kh][sr*40 + ko + 8] = w1;
        __syncthreads();
        if (k0 + 64 < K) {
            a0 = *(const short8v*)(Aptr + k0 + 64);
            a1 = *(const short8v*)(Aptr + k0 + 72);
            w0 = *(const short8v*)(Wptr + k0 + 64);
            w1 = *(const short8v*)(Wptr + k0 + 72);
        }
        #pragma unroll
        for (int p = 0; p < 2; ++p) {
            short8v af[2], bfv[2];
            #pragma unroll
            for (int i = 0; i < 2; ++i)
                af[i] = *(const short8v*)&Asm[p][(wr*32 + i*16 + frow)*40 + g*8];
            #pragma unroll
            for (int j = 0; j < 2; ++j)
                bfv[j] = *(const short8v*)&Bsm[p][(wc*32 + j*16 + frow)*40 + g*8];
            #pragma unroll
            for (int i = 0; i < 2; ++i)
                #pragma unroll
                for (int j = 0; j < 2; ++j)
                    acc[i][j] = __builtin_amdgcn_mfma_f32_16x16x32_bf16(af[i], bfv[j], acc[i][j], 0, 0, 0);
        }
    }

    #pragma unroll
    for (int j = 0; j < 2; ++j) {
        int col = bn + wc*32 + j*16 + frow;
        float bz = bias[col];
        #pragma unroll
        for (int i = 0; i < 2; ++i) {
            int row = bm + wr*32 + i*16 + g*4;
            #pragma unroll
            for (int rr = 0; rr < 4; ++rr) {
                float v = acc[i][j][rr] + bz;
                if (relu) v = fmaxf(v, 0.f);
                if constexpr (OUTMODE == 0) C[(size_t)(row + rr)*N + col] = v;
                else                        Cb[(size_t)(row + rr)*N + col] = bf16rne(v);
            }
        }
    }
}

// implicit-GEMM conv1: A generated from srcbf with (dy,dx) shifts; W reordered
// [64][(dy*3+dx)*256+c]. Out NHWC fp32 16384x64, relu. grid = 256 row-tiles.
__global__ __launch_bounds__(256) void conv1_gemm_kernel(const short* __restrict__ srcbf,
        const short* __restrict__ Wr, const float* __restrict__ bias,
        float* __restrict__ C)
{
    __shared__ short Asm[2][64 * 40];
    __shared__ short Bsm[2][64 * 40];
    const int t    = threadIdx.x;
    const int bm   = blockIdx.x * 64;
    const int K    = 2304;
    const int lane = t & 63;
    const int wid  = t >> 6;
    const int wr   = wid >> 1;
    const int wc   = wid & 1;
    const int frow = lane & 15;
    const int g    = lane >> 4;
    const int sr   = t >> 2;
    const int q    = t & 3;
    const int kh   = q >> 1;
    const int ko   = (q & 1) * 16;

    const int m  = bm + sr;
    const int bb = m >> 12, ys = (m >> 6) & 63, xs = m & 63;

    f32x4 acc[2][2];
    #pragma unroll
    for (int i = 0; i < 2; ++i)
        #pragma unroll
        for (int j = 0; j < 2; ++j)
            acc[i][j] = (f32x4){0.f,0.f,0.f,0.f};

    auto loadA = [&](int k0, short8v& r0, short8v& r1) {
        int kk = k0 + q*16;
        int kblk = kk >> 8;                  // 0..8, uniform per k0
        int dyy = kblk / 3, dxx = kblk - dyy*3;
        int yy = ys + dyy - 1, xx = xs + dxx - 1;
        if (yy >= 0 && yy < 64 && xx >= 0 && xx < 64) {
            const short* p = srcbf + ((size_t)(bb*kS + yy*64 + xx))*256 + (kk & 255);
            r0 = *(const short8v*)p;
            r1 = *(const short8v*)(p + 8);
        } else {
            r0 = (short8v){0,0,0,0,0,0,0,0};
            r1 = (short8v){0,0,0,0,0,0,0,0};
        }
    };

    const short* Wptr = Wr + (size_t)sr*K + q*16;
    short8v a0, a1;
    loadA(0, a0, a1);
    short8v w0 = *(const short8v*)Wptr;
    short8v w1 = *(const short8v*)(Wptr + 8);

    for (int k0 = 0; k0 < K; k0 += 64) {
        __syncthreads();
        *(short8v*)&Asm[kh][sr*40 + ko]     = a0;
        *(short8v*)&Asm[kh][sr*40 + ko + 8] = a1;
        *(short8v*)&Bsm[kh][sr*40 + ko]     = w0;
        *(short8v*)&Bsm[kh][sr*40 + ko + 8] = w1;
        __syncthreads();
        if (k0 + 64 < K) {
            loadA(k0 + 64, a0, a1);
            w0 = *(const short8v*)(Wptr + k0 + 64);
            w1 = *(const short8v*)(Wptr + k0 + 72);
        }
        #pragma unroll
        for (int p = 0; p < 2; ++p) {
            short8v af[2], bfv[2];
            #pragma unroll
            for (int i = 0; i < 2; ++i)
                af[i] = *(const short8v*)&Asm[p][(wr*32 + i*16 + frow)*40 + g*8];
            #pragma unroll
            for (int j = 0; j < 2; ++j)
                bfv[j] = *(const short8v*)&Bsm[p][(wc*32 + j*16 + frow)*40 + g*8];
            #pragma unroll
            for (int i = 0; i < 2; ++i)
                #pragma unroll
                for (int j = 0; j < 2; ++j)
                    acc[i][j] = __builtin_amdgcn_mfma_f32_16x16x32_bf16(af[i], bfv[j], acc[i][j], 0, 0, 0);
        }
    }

    #pragma unroll
    for (int j = 0; j < 2; ++j) {
        int col = wc*32 + j*16 + frow;       // N = 64
        float bz = bias[col];
        #pragma unroll
        for (int i = 0; i < 2; ++i) {
            int row = bm + wr*32 + i*16 + g*4;
            #pragma unroll
            for (int rr = 0; rr < 4; ++rr) {
                float v = fmaxf(acc[i][j][rr] + bz, 0.f);
                C[(size_t)(row + rr)*64 + col] = v;
            }
        }
    }
}

// merged (off|aw|val) GEMM, BK=64, fused aw-softmax.
__global__ __launch_bounds__(256) void gemm_qv(const short* __restrict__ Aq,
        const short* __restrict__ As, const short* __restrict__ W1,
        const short* __restrict__ W2, const float* __restrict__ b1,
        const float* __restrict__ b2, float* __restrict__ C1,
        short* __restrict__ Cb2)
{
    __shared__ short Asm[2][64 * 40];
    __shared__ short Bsm[2][64 * 40];
    const int t    = threadIdx.x;
    const int bn   = blockIdx.x * 64;
    const int bm   = blockIdx.y * 64;
    const bool qreg = bn < 384;
    const int K = 256;
    const int lane = t & 63;
    const int wid  = t >> 6;
    const int wr   = wid >> 1;
    const int wc   = wid & 1;
    const int frow = lane & 15;
    const int g    = lane >> 4;
    const int sr   = t >> 2;
    const int q    = t & 3;
    const int kh   = q >> 1;
    const int ko   = (q & 1) * 16;

    f32x4 acc[2][2];
    #pragma unroll
    for (int i = 0; i < 2; ++i)
        #pragma unroll
        for (int j = 0; j < 2; ++j)
            acc[i][j] = (f32x4){0.f,0.f,0.f,0.f};

    const short* Aptr = (qreg ? Aq : As) + (size_t)(bm + sr)*K + q*16;
    const short* Wptr = (qreg ? (W1 + (size_t)(bn + sr)*K)
                              : (W2 + (size_t)(bn - 384 + sr)*K)) + q*16;
    short8v a0 = *(const short8v*)Aptr;
    short8v a1 = *(const short8v*)(Aptr + 8);
    short8v w0 = *(const short8v*)Wptr;
    short8v w1 = *(const short8v*)(Wptr + 8);

    for (int k0 = 0; k0 < K; k0 += 64) {
        __syncthreads();
        *(short8v*)&Asm[kh][sr*40 + ko]     = a0;
        *(short8v*)&Asm[kh][sr*40 + ko + 8] = a1;
        *(short8v*)&Bsm[kh][sr*40 + ko]     = w0;
        *(short8v*)&Bsm[kh][sr*40 + ko + 8] = w1;
        __syncthreads();
        if (k0 + 64 < K) {
            a0 = *(const short8v*)(Aptr + k0 + 64);
            a1 = *(const short8v*)(Aptr + k0 + 72);
            w0 = *(const short8v*)(Wptr + k0 + 64);
            w1 = *(const short8v*)(Wptr + k0 + 72);
        }
        #pragma unroll
        for (int p = 0; p < 2; ++p) {
            short8v af[2], bfv[2];
            #pragma unroll
            for (int i = 0; i < 2; ++i)
                af[i] = *(const short8v*)&Asm[p][(wr*32 + i*16 + frow)*40 + g*8];
            #pragma unroll
            for (int j = 0; j < 2; ++j)
                bfv[j] = *(const short8v*)&Bsm[p][(wc*32 + j*16 + frow)*40 + g*8];
            #pragma unroll
            for (int i = 0; i < 2; ++i)
                #pragma unroll
                for (int j = 0; j < 2; ++j)
                    acc[i][j] = __builtin_amdgcn_mfma_f32_16x16x32_bf16(af[i], bfv[j], acc[i][j], 0, 0, 0);
        }
    }

    if (bn == 256 || bn == 320) {
        #pragma unroll
        for (int j = 0; j < 2; ++j) {
            int col = bn + wc*32 + j*16 + frow;
            float bz = b1[col];
            #pragma unroll
            for (int i = 0; i < 2; ++i) {
                int row = bm + wr*32 + i*16 + g*4;
                #pragma unroll
                for (int rr = 0; rr < 4; ++rr) {
                    float v = acc[i][j][rr] + bz;
                    float m = v;
                    m = fmaxf(m, __shfl_xor(m, 1));
                    m = fmaxf(m, __shfl_xor(m, 2));
                    m = fmaxf(m, __shfl_xor(m, 4));
                    m = fmaxf(m, __shfl_xor(m, 8));
                    float e = expf(v - m);
                    float s = e;
                    s += __shfl_xor(s, 1);
                    s += __shfl_xor(s, 2);
                    s += __shfl_xor(s, 4);
                    s += __shfl_xor(s, 8);
                    C1[(size_t)(row + rr)*384 + col] = e / s;
                }
            }
        }
    } else {
        #pragma unroll
        for (int j = 0; j < 2; ++j) {
            int col = bn + wc*32 + j*16 + frow;
            float bz = qreg ? b1[col] : b2[col - 384];
            #pragma unroll
            for (int i = 0; i < 2; ++i) {
                int row = bm + wr*32 + i*16 + g*4;
                #pragma unroll
                for (int rr = 0; rr < 4; ++rr) {
                    float v = acc[i][j][rr] + bz;
                    if (qreg) C1[(size_t)(row + rr)*384 + col] = v;
                    else      Cb2[(size_t)(row + rr)*256 + col - 384] = bf16rne(v);
                }
            }
        }
    }
}

// ms_deform: branchless clamped taps, vectorized cat loads.
__global__ __launch_bounds__(256) void msdeform8_kernel(const short* __restrict__ val,
        const float* __restrict__ cat, short* __restrict__ msd)
{
    int tid  = threadIdx.x;
    int d8   = tid & 3;
    int head = (tid >> 2) & 7;
    int bs   = blockIdx.x*8 + (tid >> 5);
    int s  = bs % kS;
    int b  = bs / kS;
    float refx, refy;
    if (s < 4096)      { int loc = s;        refy = ((loc>>6)+0.5f)/64.f; refx = ((loc&63)+0.5f)/64.f; }
    else if (s < 5120) { int loc = s - 4096; refy = ((loc>>5)+0.5f)/32.f; refx = ((loc&31)+0.5f)/32.f; }
    else if (s < 5376) { int loc = s - 5120; refy = ((loc>>4)+0.5f)/16.f; refx = ((loc&15)+0.5f)/16.f; }
    else               { int loc = s - 5376; refy = ((loc>>3)+0.5f)/8.f;  refx = ((loc&7)+0.5f)/8.f; }
    const float* op = cat + (size_t)bs*384 + head*32;
    const float* ap = cat + (size_t)bs*384 + 256 + head*16;
    const short* vb = val + (size_t)b*kS*256 + head*32 + d8*8;
    const int WL[4] = {64,32,16,8};
    const int BASE[4] = {0,4096,5120,5376};
    float acc[8] = {0.f,0.f,0.f,0.f,0.f,0.f,0.f,0.f};
    #pragma unroll
    for (int l = 0; l < 4; ++l) {
        int wl = WL[l], base = BASE[l];
        f32x4 o0 = *(const f32x4*)(op + l*8);
        f32x4 o1 = *(const f32x4*)(op + l*8 + 4);
        f32x4 av = *(const f32x4*)(ap + l*4);
        float oxs[4] = {o0[0], o0[2], o1[0], o1[2]};
        float oys[4] = {o0[1], o0[3], o1[1], o1[3]};
        #pragma unroll
        for (int p = 0; p < 4; ++p) {
            float gx = (refx + oxs[p]/wl)*wl - 0.5f;
            float gy = (refy + oys[p]/wl)*wl - 0.5f;
            float x0f = floorf(gx), y0f = floorf(gy);
            float wx1 = gx - x0f, wy1 = gy - y0f;
            int x0 = (int)x0f, y0 = (int)y0f;
            float a = av[p];
            #pragma unroll
            for (int dy = 0; dy < 2; ++dy) {
                int yi = y0 + dy;
                float wy = dy ? wy1 : 1.f - wy1;
                int vyok = (yi >= 0) & (yi < wl);
                int yc = min(max(yi, 0), wl - 1);
                #pragma unroll
                for (int dx = 0; dx < 2; ++dx) {
                    int xi = x0 + dx;
                    float wx = dx ? wx1 : 1.f - wx1;
                    int vok = vyok & (xi >= 0) & (xi < wl);
                    int xc = min(max(xi, 0), wl - 1);
                    float wgt = vok ? wx*wy*a : 0.f;
                    uint4 v = *(const uint4*)&vb[(size_t)(base + yc*wl + xc)*256];
                    acc[0] = fmaf(__uint_as_float(v.x << 16),          wgt, acc[0]);
                    acc[1] = fmaf(__uint_as_float(v.x & 0xffff0000u), wgt, acc[1]);
                    acc[2] = fmaf(__uint_as_float(v.y << 16),          wgt, acc[2]);
                    acc[3] = fmaf(__uint_as_float(v.y & 0xffff0000u), wgt, acc[3]);
                    acc[4] = fmaf(__uint_as_float(v.z << 16),          wgt, acc[4]);
                    acc[5] = fmaf(__uint_as_float(v.z & 0xffff0000u), wgt, acc[5]);
                    acc[6] = fmaf(__uint_as_float(v.w << 16),          wgt, acc[6]);
                    acc[7] = fmaf(__uint_as_float(v.w & 0xffff0000u), wgt, acc[7]);
                }
            }
        }
    }
    short8v o;
    #pragma unroll
    for (int k = 0; k < 8; ++k) o[k] = bf16rne(acc[k]);
    *(short8v*)&msd[(size_t)bs*256 + head*32 + d8*8] = o;
}

// src = LayerNorm(src + delta[bf16]); writes src fp32, srcbf, optionally qbf
template<int WQ>
__global__ __launch_bounds__(256) void add_ln_kernel(float* __restrict__ src,
        const short* __restrict__ delta, const float* __restrict__ g,
        const float* __restrict__ bta, short* __restrict__ srcbf,
        short* __restrict__ qbf, const float* __restrict__ pos)
{
    int lane = threadIdx.x & 63;
    int row  = blockIdx.x*4 + (threadIdx.x >> 6);
    f32x4* s4 = (f32x4*)(src + (size_t)row*256);
    f32x4 x = s4[lane];
    short4v dd = *(const short4v*)&delta[(size_t)row*256 + lane*4];
    x[0]+=bf2f(dd[0]); x[1]+=bf2f(dd[1]); x[2]+=bf2f(dd[2]); x[3]+=bf2f(dd[3]);
    float s = x[0]+x[1]+x[2]+x[3];
    #pragma unroll
    for (int o = 1; o < 64; o <<= 1) s += __shfl_xor(s, o);
    float mu = s * (1.f/256.f);
    f32x4 xc;
    xc[0]=x[0]-mu; xc[1]=x[1]-mu; xc[2]=x[2]-mu; xc[3]=x[3]-mu;
    float s2 = xc[0]*xc[0]+xc[1]*xc[1]+xc[2]*xc[2]+xc[3]*xc[3];
    #pragma unroll
    for (int o = 1; o < 64; o <<= 1) s2 += __shfl_xor(s2, o);
    float inv = rsqrtf(s2*(1.f/256.f) + 1e-5f);
    const f32x4 gv = ((const f32x4*)g)[lane];
    const f32x4 bv = ((const f32x4*)bta)[lane];
    f32x4 o4;
    o4[0]=xc[0]*inv*gv[0]+bv[0]; o4[1]=xc[1]*inv*gv[1]+bv[1];
    o4[2]=xc[2]*inv*gv[2]+bv[2]; o4[3]=xc[3]*inv*gv[3]+bv[3];
    s4[lane] = o4;
    short4v sb;
    sb[0]=bf16rne(o4[0]); sb[1]=bf16rne(o4[1]); sb[2]=bf16rne(o4[2]); sb[3]=bf16rne(o4[3]);
    *(short4v*)&srcbf[(size_t)row*256 + lane*4] = sb;
    if constexpr (WQ) {
        f32x4 pv = ((const f32x4*)(pos + (size_t)row*256))[lane];
        short4v qb;
        qb[0]=bf16rne(o4[0]+pv[0]); qb[1]=bf16rne(o4[1]+pv[1]);
        qb[2]=bf16rne(o4[2]+pv[2]); qb[3]=bf16rne(o4[3]+pv[3]);
        *(short4v*)&qbf[(size_t)row*256 + lane*4] = qb;
    }
}

// conv2: 3x3, 64->2; input c1 NHWC fp32; weights reordered [o][9][64]; output NCHW
__global__ void conv2_kernel(const float* __restrict__ c1, const float* __restrict__ w,
                             const float* __restrict__ bias, float* __restrict__ pred)
{
    int idx = blockIdx.x * blockDim.x + threadIdx.x;   // B*2*64*64
    int x = idx & 63;
    int y = (idx >> 6) & 63;
    int o = (idx >> 12) & 1;
    int b = idx >> 13;
    float acc = bias[o];
    #pragma unroll
    for (int dy = 0; dy < 3; ++dy) {
        int yy = y + dy - 1;
        if (yy < 0 || yy >= 64) continue;
        #pragma unroll
        for (int dx = 0; dx < 3; ++dx) {
            int xx = x + dx - 1;
            if (xx < 0 || xx >= 64) continue;
            const f32x4* sp = (const f32x4*)(c1 + ((size_t)(b*4096) + yy*64 + xx)*64);
            const f32x4* wp = (const f32x4*)(w + (o*9 + dy*3 + dx)*64);
            #pragma unroll
            for (int c = 0; c < 16; ++c) {
                f32x4 sv = sp[c], wv = wp[c];
                acc += sv[0]*wv[0] + sv[1]*wv[1] + sv[2]*wv[2] + sv[3]*wv[3];
            }
        }
    }
    pred[idx] = acc;
}

// bilinear resize 64x64 -> 256x256 (half-pixel, edge clamp)
__global__ void resize_kernel(const float* __restrict__ pred, float* __restrict__ out)
{
    int idx = blockIdx.x * blockDim.x + threadIdx.x;   // B*2*256*256
    int X = idx & 255;
    int Y = (idx >> 8) & 255;
    int c = (idx >> 16) & 1;
    int b = idx >> 17;
    float sx = (X + 0.5f)*0.25f - 0.5f;
    float sy = (Y + 0.5f)*0.25f - 0.5f;
    int x0 = (int)floorf(sx); float fx = sx - x0;
    int y0 = (int)floorf(sy); float fy = sy - y0;
    int x0c = min(max(x0, 0), 63), x1c = min(max(x0+1, 0), 63);
    int y0c = min(max(y0, 0), 63), y1c = min(max(y0+1, 0), 63);
    const float* p = pred + ((size_t)(b*2 + c))*4096;
    float v00 = p[y0c*64 + x0c], v01 = p[y0c*64 + x1c];
    float v10 = p[y1c*64 + x0c], v11 = p[y1c*64 + x1c];
    out[idx] = (1.f-fy)*((1.f-fx)*v00 + fx*v01) + fy*((1.f-fx)*v10 + fx*v11);
}

// ---------------- launch ----------------
extern "C" void kernel_launch(void* const* d_in, const int* in_sizes, int n_in,
                              void* d_out, int out_size, void* d_ws, size_t ws_size,
                              hipStream_t stream)
{
    const float* F[3][4];
    for (int t = 0; t < 3; ++t)
        for (int l = 0; l < 4; ++l)
            F[t][l] = (const float*)d_in[t*4 + l];
    const float* tfw = (const float*)d_in[12];
    const float *pw[4], *pb[4], *gg[4], *gb[4];
    for (int l = 0; l < 4; ++l) {
        pw[l] = (const float*)d_in[13 + 4*l];
        pb[l] = (const float*)d_in[14 + 4*l];
        gg[l] = (const float*)d_in[15 + 4*l];
        gb[l] = (const float*)d_in[16 + 4*l];
    }
    const float* lev   = (const float*)d_in[29];
    const float* off_w = (const float*)d_in[30];
    const float* off_b = (const float*)d_in[31];
    const float* aw_w  = (const float*)d_in[32];
    const float* aw_b  = (const float*)d_in[33];
    const float* val_w = (const float*)d_in[34];
    const float* val_b = (const float*)d_in[35];
    const float* out_w = (const float*)d_in[36];
    const float* out_b = (const float*)d_in[37];
    const float* ln1g  = (const float*)d_in[38];
    const float* ln1b  = (const float*)d_in[39];
    const float* ff1w  = (const float*)d_in[40];
    const float* ff1b  = (const float*)d_in[41];
    const float* ff2w  = (const float*)d_in[42];
    const float* ff2b  = (const float*)d_in[43];
    const float* ln2g  = (const float*)d_in[44];
    const float* ln2b  = (const float*)d_in[45];
    const float* c1w   = (const float*)d_in[46];
    const float* c1b   = (const float*)d_in[47];
    const float* c2w   = (const float*)d_in[48];
    const float* c2b   = (const float*)d_in[49];

    const size_t N256 = (size_t)kB * kS * 256;        // 5,570,560
    float* ws    = (float*)d_ws;
    float* src   = ws;                                // 5.57M f
    short* srcbf = (short*)(src + N256);
    short* qbf   = srcbf + N256;
    short* valbf = qbf + N256;
    short* msdbf = valbf + N256;
    short* warena= msdbf + N256;                      // bf16 weights
    short* Wcat_bf = warena;                              // 589824
    short* valw_bf = Wcat_bf + 589824;                    // 393216
    short* outw_bf = valw_bf + 393216;                    // 393216
    short* ff1w_bf = outw_bf + 393216;                    // 1572864
    short* ff2w_bf = ff1w_bf + 1572864;                   // 1572864
    short* pw_bf   = ff2w_bf + 1572864;                   // 360448
    short* c1w_bf  = pw_bf + 360448;                      // 147456 (reordered)
    float* bcat  = (float*)(c1w_bf + 147456 + 128);   // 2304 f
    float* gnstat= bcat + 4096;                       // 65536 f
    float* gnA   = gnstat + 65536;                    // 1024 f
    float* gnB   = gnA + 1024;                        // 1024 f
    float* c2wr  = gnB + 1024;                        // 1152 f
    float* pos   = c2wr + 1280;                       // 5.57M f
    float* cat   = pos + N256;                        // kM*384
    float* tmp   = cat + (size_t)kM*384;              // 5.57M f
    short* tmpbf = (short*)tmp;                       // bf16 view of tmp
    short* ffhbf = (short*)(tmp + N256);              // kM*1024 shorts
    // stage-1 aliases (cat/tmp dead in stage 1)
    short* fusedT = (short*)cat;
    float* xbufT  = tmp;
    // head aliases
    float* c1o   = (float*)valbf;                     // 16384*64 f (valbf+msdbf region)
    float* pred  = (float*)msdbf;

    const int LVL_HWS[4]  = {4096, 1024, 256, 64};
    const int LVL_BASE[4] = {0, 4096, 5120, 5376};
    const int LVL_C[4]    = {128, 256, 512, 512};
    const int LVL_PRIOR[4]= {0, 128, 256, 512};       // reference's literal (non-cumulative) priors
    const int PW_OFF[4]   = {0, 32768, 98304, 229376};

    // ---- weight prep (bf16) ----
    {
        int n = 6*384*256;
        concat_w_kernel<<<(n+255)/256, 256, 0, stream>>>(off_w, aw_w, Wcat_bf, n);
        concat_b_kernel<<<(6*384+255)/256, 256, 0, stream>>>(off_b, aw_b, bcat, 6*384);
        f2bf_kernel<<<(393216/4+255)/256, 256, 0, stream>>>(val_w, valw_bf, 393216);
        f2bf_kernel<<<(393216/4+255)/256, 256, 0, stream>>>(out_w, outw_bf, 393216);
        f2bf_kernel<<<(1572864/4+255)/256, 256, 0, stream>>>(ff1w, ff1w_bf, 1572864);
        f2bf_kernel<<<(1572864/4+255)/256, 256, 0, stream>>>(ff2w, ff2w_bf, 1572864);
        for (int l = 0; l < 4; ++l) {
            int n2 = 256 * LVL_C[l];
            f2bf_kernel<<<(n2/4+255)/256, 256, 0, stream>>>(pw[l], pw_bf + PW_OFF[l], n2);
        }
        reorder_c1w_kernel<<<(147456+255)/256, 256, 0, stream>>>(c1w, c1w_bf, 147456);
        reorder_c2w_kernel<<<(1152+255)/256, 256, 0, stream>>>(c2w, c2wr);
    }

    // ---- stage 1 ----
    for (int l = 0; l < 4; ++l) {
        int hw = LVL_HWS[l];
        int dim = (l==0)?64:(l==1)?32:(l==2)?16:8;
        int n3 = hw * kH;
        pos_kernel<<<(n3+255)/256, 256, 0, stream>>>(lev, pos, dim, dim, LVL_BASE[l], l, n3);
    }
    for (int l = 0; l < 4; ++l) {
        int hw = LVL_HWS[l], c = LVL_C[l];
        dim3 gf(hw/32, c/32, kB);
        fuseT_kernel<<<gf, 256, 0, stream>>>(F[0][l], F[1][l], F[2][l], tfw,
                                             fusedT, c, hw, LVL_PRIOR[l]);
        dim3 gp(4, (kB*hw)/64);
        gemm64<0><<<gp, 256, 0, stream>>>(fusedT, pw_bf + PW_OFF[l], pb[l],
                                          xbufT, nullptr, 256, c, 0);
        int nchunks = hw / 16;
        gn_sum_kernel<<<dim3(nchunks, kB), 256, 0, stream>>>(xbufT, gnstat, nchunks);
        gn_fin_kernel<<<kB, 256, 0, stream>>>(gnstat, gg[l], gb[l], gnA, gnB, nchunks, hw);
        gn_apply_kernel<<<(kB*hw*256)/1024, 256, 0, stream>>>(xbufT, gnA, gnB, pos,
                                                              src, srcbf, qbf, hw, LVL_BASE[l]);
    }

    // ---- stage 2: 6 encoder layers ----
    for (int i = 0; i < 6; ++i) {
        gemm_qv<<<dim3(10, kM/64), 256, 0, stream>>>(qbf, srcbf,
                Wcat_bf + (size_t)i*384*256, valw_bf + (size_t)i*65536,
                bcat + i*384, val_b + i*256, cat, valbf);
        msdeform8_kernel<<<kM/8, 256, 0, stream>>>(valbf, cat, msdbf);
        gemm64<1><<<dim3(4, kM/64), 256, 0, stream>>>(msdbf, outw_bf + (size_t)i*65536,
                                                      out_b + i*256, nullptr, tmpbf, 256, 256, 0);
        add_ln_kernel<0><<<kM/4, 256, 0, stream>>>(src, tmpbf, ln1g + i*256, ln1b + i*256,
                                                   srcbf, nullptr, nullptr);
        gemm64<1><<<dim3(16, kM/64), 256, 0, stream>>>(srcbf, ff1w_bf + (size_t)i*262144,
                                                       ff1b + i*1024, nullptr, ffhbf, 1024, 256, 1);
        gemm64<1><<<dim3(4, kM/64), 256, 0, stream>>>(ffhbf, ff2w_bf + (size_t)i*262144,
                                                      ff2b + i*256, nullptr, tmpbf, 256, 1024, 0);
        add_ln_kernel<1><<<kM/4, 256, 0, stream>>>(src, tmpbf, ln2g + i*256, ln2b + i*256,
                                                   srcbf, qbf, pos);
    }

    // ---- stage 3: head ----
    {
        conv1_gemm_kernel<<<256, 256, 0, stream>>>(srcbf, c1w_bf, c1b, c1o);
        conv2_kernel<<<(kB*2*64*64)/256, 256, 0, stream>>>(c1o, c2wr, c2b, pred);
        resize_kernel<<<(kB*2*256*256)/256, 256, 0, stream>>>(pred, (float*)d_out);
    }
}